// Round 10
// baseline (959.345 us; speedup 1.0000x reference)
//
#include <hip/hip_runtime.h>
#include <cstddef>

#define BB 4
#define CC 384
#define NPT 2048
#define KNN 20
#define NCAND 32
#define NCH 21
#define NKT (NPT*KNN)
#define TOT (BB*NKT)
#define EPSD 1e-6
#define BNEPSD 1e-5
#define EPSF 1e-6f
#define BNEPS 1e-5f
#define NEGS 0.2f

// ---------------- zero ----------------
__global__ __launch_bounds__(256) void k_zero(float* p, int n) {
    int t = blockIdx.x*256 + threadIdx.x;
    if (t < n) p[t] = 0.f;
}

// ---------------- xx = sum_c x^2 (f64) ----------------
__global__ __launch_bounds__(256) void k_xx(const float* __restrict__ x, float* __restrict__ xx,
                                            double* __restrict__ xxd) {
    int t = blockIdx.x*256 + threadIdx.x;       // B*N
    int n = t & (NPT-1); int b = t >> 11;
    const float* xp = x + (size_t)b*CC*NPT + n;
    double acc = 0.0;
    #pragma unroll 8
    for (int c = 0; c < CC; c++) { double v = (double)xp[(size_t)c*NPT]; acc += v*v; }
    xx[t] = (float)acc;
    xxd[t] = acc;
}

// ---------------- transpose x -> xT (B,N,C) ----------------
__global__ __launch_bounds__(256) void k_xt(const float* __restrict__ x, float* __restrict__ xT) {
    __shared__ float tile[64][65];
    int n0 = blockIdx.x*64, c0 = blockIdx.y*64, b = blockIdx.z;
    int tx = threadIdx.x & 63, ty = threadIdx.x >> 6;
    const float* xb = x + (size_t)b*CC*NPT;
    #pragma unroll
    for (int r = 0; r < 64; r += 4)
        tile[r+ty][tx] = xb[(size_t)(c0+r+ty)*NPT + n0 + tx];
    __syncthreads();
    float* xtb = xT + (size_t)b*NPT*CC;
    #pragma unroll
    for (int r = 0; r < 64; r += 4)
        xtb[(size_t)(n0+r+ty)*CC + c0 + tx] = tile[tx][r+ty];
}

// ---------------- f32 Gram, 128x128 tiles, 8x8/thread, triangular grid ----------------
__global__ __launch_bounds__(256) void k_gram(const float* __restrict__ x, const float* __restrict__ xx,
                                              float* __restrict__ scores4) {
    __shared__ float As[16][128];
    __shared__ float Bs[16][128];
    int tid = blockIdx.x;               // 0..135 triangular tile
    int b = blockIdx.y;
    int by = 0, rem = tid;
    while (rem >= 16 - by) { rem -= 16 - by; by++; }
    int bx = by + rem;
    int n0 = by*128, m0 = bx*128;
    int t = threadIdx.x;
    int tx = t & 15, ty = t >> 4;
    const float* xb = x + (size_t)b*CC*NPT;
    float* scores = scores4 + (size_t)b*NPT*NPT;
    float acc[8][8] = {};
    for (int c0 = 0; c0 < CC; c0 += 16) {
        #pragma unroll
        for (int i = 0; i < 8; i++) {
            int e = t + i*256;
            int cc = e >> 7, col = e & 127;
            As[cc][col] = xb[(size_t)(c0+cc)*NPT + n0 + col];
            Bs[cc][col] = xb[(size_t)(c0+cc)*NPT + m0 + col];
        }
        __syncthreads();
        #pragma unroll
        for (int kk = 0; kk < 16; kk++) {
            float4 a0 = *(const float4*)&As[kk][ty*8];
            float4 a1 = *(const float4*)&As[kk][ty*8+4];
            float4 b0 = *(const float4*)&Bs[kk][tx*8];
            float4 b1 = *(const float4*)&Bs[kk][tx*8+4];
            float av[8] = {a0.x,a0.y,a0.z,a0.w,a1.x,a1.y,a1.z,a1.w};
            float bv[8] = {b0.x,b0.y,b0.z,b0.w,b1.x,b1.y,b1.z,b1.w};
            #pragma unroll
            for (int i = 0; i < 8; i++)
                #pragma unroll
                for (int j = 0; j < 8; j++)
                    acc[i][j] += av[i]*bv[j];
        }
        __syncthreads();
    }
    int nb = n0 + ty*8, mb = m0 + tx*8;
    float xn[8], xm[8];
    #pragma unroll
    for (int i = 0; i < 8; i++) { xn[i] = xx[b*NPT + nb + i]; xm[i] = xx[b*NPT + mb + i]; }
    float val[8][8];
    #pragma unroll
    for (int i = 0; i < 8; i++)
        #pragma unroll
        for (int j = 0; j < 8; j++) {
            val[i][j] = 2.f*acc[i][j] - xn[i] - xm[j];
            scores[(size_t)(nb+i)*NPT + mb + j] = val[i][j];
        }
    if (bx != by) {
        #pragma unroll
        for (int j = 0; j < 8; j++)
            #pragma unroll
            for (int i = 0; i < 8; i++)
                scores[(size_t)(mb+j)*NPT + nb + i] = val[i][j];
    }
}

// ---------------- top-NCAND per row: radix select (set-identical to f32 top-32) ----------------
__global__ __launch_bounds__(256) void k_topk(const float* __restrict__ scores4, int* __restrict__ candout) {
    int n = blockIdx.x, b = blockIdx.y;
    const float* row = scores4 + ((size_t)b*NPT + n)*NPT;
    unsigned key[8];
    #pragma unroll
    for (int w = 0; w < 8; w++) {
        unsigned u = __float_as_uint(row[threadIdx.x + w*256]);
        key[w] = (u & 0x80000000u) ? ~u : (u | 0x80000000u);   // monotone float->uint
    }
    __shared__ int hist[4][257];
    __shared__ int histsum[256];
    __shared__ unsigned s_pfx;
    __shared__ int s_need, s_slot, s_tie;
    __shared__ unsigned long long tiel[256];
    int wv = threadIdx.x >> 6;
    if (threadIdx.x == 0) { s_pfx = 0u; s_need = NCAND; s_slot = 0; s_tie = 0; }
    #pragma unroll
    for (int pass = 0; pass < 3; pass++) {
        int sh = (pass == 0) ? 24 : (pass == 1 ? 16 : 8);
        unsigned maskhi = (pass == 0) ? 0u : (pass == 1 ? 0xFF000000u : 0xFFFF0000u);
        hist[0][threadIdx.x] = 0; hist[1][threadIdx.x] = 0;
        hist[2][threadIdx.x] = 0; hist[3][threadIdx.x] = 0;
        __syncthreads();
        unsigned pfx = s_pfx;
        #pragma unroll
        for (int w = 0; w < 8; w++) {
            unsigned v = key[w];
            if ((v & maskhi) == (pfx & maskhi))
                atomicAdd(&hist[wv][(v >> sh) & 0xFF], 1);
        }
        __syncthreads();
        histsum[threadIdx.x] = hist[0][threadIdx.x] + hist[1][threadIdx.x]
                             + hist[2][threadIdx.x] + hist[3][threadIdx.x];
        __syncthreads();
        if (threadIdx.x < 64) {
            int l = threadIdx.x, base = l*4;
            int c0 = histsum[base], c1 = histsum[base+1], c2 = histsum[base+2], c3 = histsum[base+3];
            int mysum = c0 + c1 + c2 + c3;
            int suf = mysum;
            #pragma unroll
            for (int st = 1; st < 64; st <<= 1) {
                int u2 = __shfl_down(suf, st);
                if (l + st >= 64) u2 = 0;
                suf += u2;
            }
            int need = s_need;
            int sufNext = suf - mysum;
            if (suf >= need && sufNext < need) {        // exactly one lane
                int s3 = sufNext + c3, s2p = s3 + c2, s1p = s2p + c1;
                int B, Sb1;
                if (s3 >= need)       { B = base+3; Sb1 = sufNext; }
                else if (s2p >= need) { B = base+2; Sb1 = s3; }
                else if (s1p >= need) { B = base+1; Sb1 = s2p; }
                else                  { B = base;   Sb1 = s1p; }
                s_pfx = s_pfx | ((unsigned)B << sh);
                s_need = need - Sb1;
            }
        }
        __syncthreads();
    }
    unsigned pfx24 = s_pfx & 0xFFFFFF00u;
    int* outp = candout + ((size_t)b*NPT + n)*NCAND;
    #pragma unroll
    for (int w = 0; w < 8; w++) {
        unsigned v = key[w];
        unsigned hi = v & 0xFFFFFF00u;
        int i = threadIdx.x + w*256;
        if (hi > pfx24) {
            int s = atomicAdd(&s_slot, 1);
            outp[s] = i;
        } else if (hi == pfx24) {
            int ti = atomicAdd(&s_tie, 1);
            if (ti < 256) tiel[ti] = ((unsigned long long)v << 32) | (unsigned)(NPT-1-i);
        }
    }
    __syncthreads();
    if (threadIdx.x == 0) {
        int A = s_slot, r = s_need, T = s_tie < 256 ? s_tie : 256;
        for (int kk = 0; kk < r; kk++) {
            unsigned long long best = 0ull; int bj = 0;
            for (int j2 = 0; j2 < T; j2++) if (tiel[j2] > best) { best = tiel[j2]; bj = j2; }
            tiel[bj] = 0ull;
            outp[A + kk] = NPT-1-(int)(best & 0xFFFFFFFFu);
        }
    }
}

// ---------------- exact f64 rescore -> final top-20 (wave-parallel selection) ----------------
__global__ __launch_bounds__(256) void k_rescore(const float* __restrict__ xT, const double* __restrict__ xxd,
                                                 const int* __restrict__ cand, int* __restrict__ idxout) {
    __shared__ float xn[CC];
    __shared__ double sc[NCAND];
    __shared__ int ci[NCAND];
    int t = blockIdx.x;             // b*N + n
    int b = t >> 11;
    const float* xrow = xT + (size_t)t*CC;
    for (int i = threadIdx.x; i < CC; i += 256) xn[i] = xrow[i];
    if (threadIdx.x < NCAND) ci[threadIdx.x] = cand[(size_t)t*NCAND + threadIdx.x];
    __syncthreads();
    int j = threadIdx.x >> 3, l = threadIdx.x & 7;
    int m = ci[j];
    const float* xm = xT + ((size_t)b*NPT + m)*CC;
    double acc = 0.0;
    int cbase = l*48;
    #pragma unroll 8
    for (int c = 0; c < 48; c++) acc += (double)xn[cbase+c] * (double)xm[cbase+c];
    acc += __shfl_down(acc, 4, 8);
    acc += __shfl_down(acc, 2, 8);
    acc += __shfl_down(acc, 1, 8);
    if (l == 0) sc[j] = 2.0*acc - xxd[t] - xxd[(size_t)b*NPT + m];
    __syncthreads();
    if (threadIdx.x < 64) {
        double v = (threadIdx.x < NCAND) ? sc[threadIdx.x] : -1e300;
        int oi = (threadIdx.x < NCAND) ? ci[threadIdx.x] : NPT;
        for (int kk = 0; kk < KNN; kk++) {
            double bv = v; int bo = oi;
            #pragma unroll
            for (int st = 16; st > 0; st >>= 1) {
                double ov = __shfl_xor(bv, st, 32);
                int    oo = __shfl_xor(bo, st, 32);
                if (ov > bv || (ov == bv && oo < bo)) { bv = ov; bo = oo; }
            }
            if (threadIdx.x == 0) idxout[(size_t)t*KNN + kk] = bo;
            if (oi == bo) v = -1e300;   // unique owner eliminates winner
        }
    }
}

// ---------------- P/Q precompute (f64), point-major [b*N+n][64] layout ----------------
__global__ __launch_bounds__(256) void k_pq_d(const float* __restrict__ x,
                                              const float* __restrict__ wf, const float* __restrict__ wd,
                                              double* __restrict__ Pf, double* __restrict__ Qf,
                                              double* __restrict__ Pd, double* __restrict__ Qd) {
    int t = blockIdx.x*256 + threadIdx.x;       // (b*N+n)*64 + ov
    int ov = t & 63;
    int row = t >> 6;                           // b*N+n
    if (ov >= 63) return;
    int n = row & (NPT-1); int b = row >> 11;
    int o = ov / 3, v = ov % 3;
    const float* xb = x + (size_t)b*CC*NPT + (size_t)v*NPT + n;
    const float* wfo = wf + o*256;
    const float* wdo = wd + o*256;
    double pf = 0.0, qf = 0.0, pd = 0.0, qd = 0.0;
    #pragma unroll 4
    for (int c3 = 0; c3 < 128; c3++) {
        double xv = (double)xb[(size_t)(c3*3)*NPT];
        double waf = (double)wfo[c3], wbf = (double)wfo[128+c3];
        double wad = (double)wdo[c3], wbd = (double)wdo[128+c3];
        pf += waf*xv; qf += (wbf-waf)*xv;
        pd += wad*xv; qd += (wbd-wad)*xv;
    }
    size_t off = (size_t)row*64 + ov;
    Pf[off] = pf; Qf[off] = qf; Pd[off] = pd; Qd[off] = qd;
}

// ---------------- BN1 partial sums (f64, deterministic) ----------------
__global__ __launch_bounds__(256) void k_bn1_part(const double* __restrict__ Pf, const double* __restrict__ Qf,
                                                  const int* __restrict__ idx, double* __restrict__ part) {
    __shared__ double red[4][42];
    int t = blockIdx.x*256 + threadIdx.x;       // (b*N+n)*K+k
    int bn = t / KNN;
    int n = bn & (NPT-1); int b = bn >> 11;
    int m = idx[t];
    const double* PF = Pf + ((size_t)b*NPT + m)*64;
    const double* QF = Qf + ((size_t)b*NPT + n)*64;
    int wave = threadIdx.x >> 6;
    #pragma unroll
    for (int o = 0; o < NCH; o++) {
        double p0 = PF[o*3+0] + QF[o*3+0];
        double p1 = PF[o*3+1] + QF[o*3+1];
        double p2 = PF[o*3+2] + QF[o*3+2];
        double nr = sqrt(p0*p0 + p1*p1 + p2*p2) + EPSD;
        double a = nr, c2 = nr*nr;
        #pragma unroll
        for (int st = 32; st > 0; st >>= 1) { a += __shfl_down(a, st); c2 += __shfl_down(c2, st); }
        if ((threadIdx.x & 63) == 0) { red[wave][o] = a; red[wave][NCH+o] = c2; }
    }
    __syncthreads();
    if (threadIdx.x < 42)
        part[(size_t)blockIdx.x*42 + threadIdx.x] =
            red[0][threadIdx.x] + red[1][threadIdx.x] + red[2][threadIdx.x] + red[3][threadIdx.x];
}

// ---------------- finalize f64 stats (parallel: 21 blocks x 256 thr) ----------------
__global__ __launch_bounds__(256) void k_fin_d(const double* __restrict__ part, double* __restrict__ st,
                                               int nblk, double cnt) {
    __shared__ double r0[4], r1[4];
    int o = blockIdx.x;             // 0..NCH-1
    double s0 = 0.0, s1 = 0.0;
    for (int i = threadIdx.x; i < nblk; i += 256) {
        s0 += part[(size_t)i*42 + o];
        s1 += part[(size_t)i*42 + NCH + o];
    }
    #pragma unroll
    for (int stp = 32; stp > 0; stp >>= 1) { s0 += __shfl_down(s0, stp); s1 += __shfl_down(s1, stp); }
    int wv = threadIdx.x >> 6;
    if ((threadIdx.x & 63) == 0) { r0[wv] = s0; r1[wv] = s1; }
    __syncthreads();
    if (threadIdx.x == 0) {
        double sum = r0[0]+r0[1]+r0[2]+r0[3];
        double ssq = r1[0]+r1[1]+r1[2]+r1[3];
        double mean = sum / cnt;
        double var = ssq / cnt - mean*mean;
        if (var < 0.0) var = 0.0;
        st[o] = mean;
        st[NCH+o] = 1.0 / sqrt(var + BNEPSD);
    }
}

// ---------------- block1 (f64) -> BN2 partials; 8 threads/pair, 32 pairs/block ----------------
__global__ __launch_bounds__(256) void k_b1_bn2part(const double* __restrict__ Pf, const double* __restrict__ Qf,
                                                    const double* __restrict__ Pd, const double* __restrict__ Qd,
                                                    const int* __restrict__ idx, const double* __restrict__ st1,
                                                    const float* __restrict__ w2f_g, double* __restrict__ part) {
    __shared__ double h1L[32][65];
    __shared__ double w2s[NCH*NCH];
    __shared__ double s1[42];
    __shared__ double wred[4][42];
    int tid = threadIdx.x;
    int p = tid >> 3, j = tid & 7;
    int t = blockIdx.x*32 + p;
    for (int i = tid; i < NCH*NCH; i += 256) w2s[i] = (double)w2f_g[i];
    if (tid < 42) s1[tid] = st1[tid];
    int bn = t / KNN;
    int n = bn & (NPT-1), b = bn >> 11;
    int m = idx[t];
    const double* PF = Pf + ((size_t)b*NPT + m)*64;
    const double* QF = Qf + ((size_t)b*NPT + n)*64;
    const double* PD = Pd + ((size_t)b*NPT + m)*64;
    const double* QD = Qd + ((size_t)b*NPT + n)*64;
    __syncthreads();
    for (int o = j; o < NCH; o += 8) {
        double p0 = PF[o*3+0] + QF[o*3+0];
        double p1 = PF[o*3+1] + QF[o*3+1];
        double p2 = PF[o*3+2] + QF[o*3+2];
        double d0 = PD[o*3+0] + QD[o*3+0];
        double d1 = PD[o*3+1] + QD[o*3+1];
        double d2 = PD[o*3+2] + QD[o*3+2];
        double nr = sqrt(p0*p0 + p1*p1 + p2*p2) + EPSD;
        double fac = (nr - s1[o]) * s1[NCH+o] / nr;
        p0 *= fac; p1 *= fac; p2 *= fac;
        double dot = p0*d0 + p1*d1 + p2*d2;
        double dd  = d0*d0 + d1*d1 + d2*d2;
        double coef = dot / (dd + EPSD);
        double w0 = (dot >= 0.0) ? p0 : (p0 - coef*d0);
        double w1 = (dot >= 0.0) ? p1 : (p1 - coef*d1);
        double w2 = (dot >= 0.0) ? p2 : (p2 - coef*d2);
        h1L[p][o*3+0] = 0.2*p0 + 0.8*w0;
        h1L[p][o*3+1] = 0.2*p1 + 0.8*w1;
        h1L[p][o*3+2] = 0.2*p2 + 0.8*w2;
    }
    __syncthreads();
    double s[3] = {0.0,0.0,0.0}, q[3] = {0.0,0.0,0.0};
    {
        int oi = 0;
        for (int o = j; o < NCH; o += 8, oi++) {
            double a0 = 0.0, a1 = 0.0, a2 = 0.0;
            #pragma unroll
            for (int c = 0; c < NCH; c++) {
                double w = w2s[o*NCH+c];
                a0 += w*h1L[p][c*3+0]; a1 += w*h1L[p][c*3+1]; a2 += w*h1L[p][c*3+2];
            }
            double nr = sqrt(a0*a0 + a1*a1 + a2*a2) + EPSD;
            s[oi] = nr; q[oi] = nr*nr;
        }
    }
    #pragma unroll
    for (int st = 8; st < 64; st <<= 1) {
        #pragma unroll
        for (int u = 0; u < 3; u++) { s[u] += __shfl_down(s[u], st); q[u] += __shfl_down(q[u], st); }
    }
    if ((tid & 63) < 8) {           // lanes 0..7 hold per-wave sums for their j
        int wv = tid >> 6, oi = 0;
        for (int o = j; o < NCH; o += 8, oi++) { wred[wv][o] = s[oi]; wred[wv][NCH+o] = q[oi]; }
    }
    __syncthreads();
    if (tid < 42)
        part[(size_t)blockIdx.x*42 + tid] = wred[0][tid]+wred[1][tid]+wred[2][tid]+wred[3][tid];
}

// ---------------- block1+block2 (f64) -> h2 f32 + pool dots f64; 8 thr/pair, single LDS tile ----------------
__global__ __launch_bounds__(256) void k_apply_d(const double* __restrict__ Pf, const double* __restrict__ Qf,
                                                 const double* __restrict__ Pd, const double* __restrict__ Qd,
                                                 const int* __restrict__ idx,
                                                 const double* __restrict__ st1, const double* __restrict__ st2,
                                                 const float* __restrict__ w2f_g, const float* __restrict__ w2d_g,
                                                 const float* __restrict__ wp_g,
                                                 float* __restrict__ h2f, double* __restrict__ dots) {
    __shared__ double hL[32][65];           // h1, then reused for h2
    __shared__ double w2fs[NCH*NCH];
    __shared__ double w2ds[NCH*NCH];
    __shared__ double wps[NCH*NCH];
    __shared__ double s1[42], s2[42];
    int tid = threadIdx.x;
    int p = tid >> 3, j = tid & 7;
    int t = blockIdx.x*32 + p;
    for (int i = tid; i < NCH*NCH; i += 256) {
        w2fs[i] = (double)w2f_g[i]; w2ds[i] = (double)w2d_g[i]; wps[i] = (double)wp_g[i];
    }
    if (tid < 42) { s1[tid] = st1[tid]; s2[tid] = st2[tid]; }
    int k = t % KNN; int bn = t / KNN;
    int n = bn & (NPT-1), b = bn >> 11;
    int m = idx[t];
    const double* PF = Pf + ((size_t)b*NPT + m)*64;
    const double* QF = Qf + ((size_t)b*NPT + n)*64;
    const double* PD = Pd + ((size_t)b*NPT + m)*64;
    const double* QD = Qd + ((size_t)b*NPT + n)*64;
    __syncthreads();
    // block1 -> hL (h1)
    #pragma unroll
    for (int oi = 0; oi < 3; oi++) {
        int o = j + oi*8;
        if (o < NCH) {
            double p0 = PF[o*3+0] + QF[o*3+0];
            double p1 = PF[o*3+1] + QF[o*3+1];
            double p2 = PF[o*3+2] + QF[o*3+2];
            double d0 = PD[o*3+0] + QD[o*3+0];
            double d1 = PD[o*3+1] + QD[o*3+1];
            double d2 = PD[o*3+2] + QD[o*3+2];
            double nr = sqrt(p0*p0 + p1*p1 + p2*p2) + EPSD;
            double fac = (nr - s1[o]) * s1[NCH+o] / nr;
            p0 *= fac; p1 *= fac; p2 *= fac;
            double dot = p0*d0 + p1*d1 + p2*d2;
            double dd  = d0*d0 + d1*d1 + d2*d2;
            double coef = dot / (dd + EPSD);
            double w0 = (dot >= 0.0) ? p0 : (p0 - coef*d0);
            double w1 = (dot >= 0.0) ? p1 : (p1 - coef*d1);
            double w2 = (dot >= 0.0) ? p2 : (p2 - coef*d2);
            hL[p][o*3+0] = 0.2*p0 + 0.8*w0;
            hL[p][o*3+1] = 0.2*p1 + 0.8*w1;
            hL[p][o*3+2] = 0.2*p2 + 0.8*w2;
        }
    }
    __syncthreads();
    // block2 into registers (compile-time oi indexing), write h2f as we go
    double h2r[3][3];
    #pragma unroll
    for (int oi = 0; oi < 3; oi++) {
        int o = j + oi*8;
        if (o < NCH) {
            double p0 = 0.0, p1 = 0.0, p2 = 0.0, d0 = 0.0, d1 = 0.0, d2 = 0.0;
            #pragma unroll
            for (int c = 0; c < NCH; c++) {
                double wa = w2fs[o*NCH+c], wb = w2ds[o*NCH+c];
                double x0 = hL[p][c*3+0], x1 = hL[p][c*3+1], x2 = hL[p][c*3+2];
                p0 += wa*x0; p1 += wa*x1; p2 += wa*x2;
                d0 += wb*x0; d1 += wb*x1; d2 += wb*x2;
            }
            double nr = sqrt(p0*p0 + p1*p1 + p2*p2) + EPSD;
            double fac = (nr - s2[o]) * s2[NCH+o] / nr;
            p0 *= fac; p1 *= fac; p2 *= fac;
            double dot = p0*d0 + p1*d1 + p2*d2;
            double dd  = d0*d0 + d1*d1 + d2*d2;
            double coef = dot / (dd + EPSD);
            double w0 = (dot >= 0.0) ? p0 : (p0 - coef*d0);
            double w1 = (dot >= 0.0) ? p1 : (p1 - coef*d1);
            double w2 = (dot >= 0.0) ? p2 : (p2 - coef*d2);
            double h0 = 0.2*p0 + 0.8*w0, h1v = 0.2*p1 + 0.8*w1, h2v = 0.2*p2 + 0.8*w2;
            h2r[oi][0] = h0; h2r[oi][1] = h1v; h2r[oi][2] = h2v;
            h2f[((size_t)(b*63 + o*3+0)*NPT + n)*KNN + k] = (float)h0;
            h2f[((size_t)(b*63 + o*3+1)*NPT + n)*KNN + k] = (float)h1v;
            h2f[((size_t)(b*63 + o*3+2)*NPT + n)*KNN + k] = (float)h2v;
        }
    }
    __syncthreads();        // everyone done reading h1
    #pragma unroll
    for (int oi = 0; oi < 3; oi++) {
        int o = j + oi*8;
        if (o < NCH) {
            hL[p][o*3+0] = h2r[oi][0];
            hL[p][o*3+1] = h2r[oi][1];
            hL[p][o*3+2] = h2r[oi][2];
        }
    }
    __syncthreads();
    // pool dots from hL (= h2)
    #pragma unroll
    for (int oi = 0; oi < 3; oi++) {
        int o = j + oi*8;
        if (o < NCH) {
            double dv0 = 0.0, dv1 = 0.0, dv2 = 0.0;
            #pragma unroll
            for (int c = 0; c < NCH; c++) {
                double w = wps[o*NCH+c];
                dv0 += w*hL[p][c*3+0]; dv1 += w*hL[p][c*3+1]; dv2 += w*hL[p][c*3+2];
            }
            double dt = hL[p][o*3+0]*dv0 + hL[p][o*3+1]*dv1 + hL[p][o*3+2]*dv2;
            dots[(((size_t)b*NCH + o)*NPT + n)*KNN + k] = dt;
        }
    }
}

// ---------------- pool: exact f64 argmax, gather f32 values ----------------
__global__ __launch_bounds__(32) void k_pool_d(const double* __restrict__ dots, const float* __restrict__ h2f,
                                               float* __restrict__ pooled) {
    int b = blockIdx.x >> 11, n = blockIdx.x & (NPT-1);
    int o = threadIdx.x;
    if (o >= NCH) return;
    const double* dp = dots + (((size_t)b*NCH + o)*NPT + n)*KNN;
    double best = dp[0]; int bk = 0;
    #pragma unroll
    for (int k = 1; k < KNN; k++) { double v = dp[k]; if (v > best) { best = v; bk = k; } }
    #pragma unroll
    for (int v = 0; v < 3; v++)
        pooled[((size_t)b*63 + o*3+v)*NPT + n] = h2f[(((size_t)b*63 + o*3+v)*NPT + n)*KNN + bk];
}

// ---------------- conv1 (63->256) + stats ----------------
__global__ __launch_bounds__(256) void k_conv1(const float* __restrict__ pooled, const float* __restrict__ w1,
                                               float* __restrict__ y1, float* __restrict__ sums) {
    int n = blockIdx.x*256 + threadIdx.x;
    int o = blockIdx.y, b = blockIdx.z;
    const float* pb = pooled + (size_t)b*63*NPT + n;
    const float* wo = w1 + o*63;
    float acc = 0.f;
    #pragma unroll
    for (int c = 0; c < 63; c++) acc += wo[c]*pb[(size_t)c*NPT];
    y1[((size_t)b*256 + o)*NPT + n] = acc;
    float a = acc, c2 = acc*acc;
    #pragma unroll
    for (int st = 32; st > 0; st >>= 1) { a += __shfl_down(a, st); c2 += __shfl_down(c2, st); }
    __shared__ float ra[4], rc[4];
    int wv = threadIdx.x >> 6;
    if ((threadIdx.x & 63) == 0) { ra[wv] = a; rc[wv] = c2; }
    __syncthreads();
    if (threadIdx.x == 0) {
        atomicAdd(&sums[o], ra[0]+ra[1]+ra[2]+ra[3]);
        atomicAdd(&sums[256+o], rc[0]+rc[1]+rc[2]+rc[3]);
    }
}

// ---------------- finalize f32 stats ----------------
__global__ void k_finalize(const float* __restrict__ sums, float* __restrict__ stats, float invcnt, int nch) {
    int o = blockIdx.x*blockDim.x + threadIdx.x;
    if (o >= nch) return;
    float mean = sums[o]*invcnt;
    float var = sums[nch+o]*invcnt - mean*mean;
    if (var < 0.f) var = 0.f;
    stats[o] = mean;
    stats[nch+o] = 1.0f / sqrtf(var + BNEPS);
}

// ---------------- bn+lrelu in place ----------------
__global__ __launch_bounds__(256) void k_act(float* __restrict__ y, const float* __restrict__ stats, int nch) {
    int t = blockIdx.x*256 + threadIdx.x;
    int o = (t >> 11) % nch;
    float z = (y[t] - stats[o]) * stats[nch+o];
    y[t] = z >= 0.f ? z : NEGS*z;
}

// ---------------- conv2 (256->128) + stats ----------------
__global__ __launch_bounds__(256) void k_conv2(const float* __restrict__ z1, const float* __restrict__ w2,
                                               float* __restrict__ y2, float* __restrict__ sums) {
    int n = blockIdx.x*256 + threadIdx.x;
    int o = blockIdx.y, b = blockIdx.z;
    const float* pb = z1 + (size_t)b*256*NPT + n;
    const float* wo = w2 + o*256;
    float acc = 0.f;
    #pragma unroll 4
    for (int c = 0; c < 256; c++) acc += wo[c]*pb[(size_t)c*NPT];
    y2[((size_t)b*128 + o)*NPT + n] = acc;
    float a = acc, c2 = acc*acc;
    #pragma unroll
    for (int st = 32; st > 0; st >>= 1) { a += __shfl_down(a, st); c2 += __shfl_down(c2, st); }
    __shared__ float ra[4], rc[4];
    int wv = threadIdx.x >> 6;
    if ((threadIdx.x & 63) == 0) { ra[wv] = a; rc[wv] = c2; }
    __syncthreads();
    if (threadIdx.x == 0) {
        atomicAdd(&sums[o], ra[0]+ra[1]+ra[2]+ra[3]);
        atomicAdd(&sums[128+o], rc[0]+rc[1]+rc[2]+rc[3]);
    }
}

// ---------------- final: act(conv2) -> conv3 + bias ----------------
__global__ __launch_bounds__(256) void k_final(const float* __restrict__ y2, const float* __restrict__ w3,
                                               const float* __restrict__ b3, const float* __restrict__ stats,
                                               float* __restrict__ out) {
    int t = blockIdx.x*256 + threadIdx.x;       // B*N
    int n = t & (NPT-1); int b = t >> 11;
    const float* yb = y2 + (size_t)b*128*NPT + n;
    float acc = b3[0];
    #pragma unroll 4
    for (int c = 0; c < 128; c++) {
        float z = (yb[(size_t)c*NPT] - stats[c]) * stats[128+c];
        z = z >= 0.f ? z : NEGS*z;
        acc += w3[c]*z;
    }
    out[t] = acc;
}

extern "C" void kernel_launch(void* const* d_in, const int* in_sizes, int n_in,
                              void* d_out, int out_size, void* d_ws, size_t ws_size,
                              hipStream_t stream) {
    const float* x   = (const float*)d_in[0];
    const float* w1f = (const float*)d_in[1];
    const float* w1d = (const float*)d_in[2];
    const float* w2f = (const float*)d_in[3];
    const float* w2d = (const float*)d_in[4];
    const float* wp  = (const float*)d_in[5];
    const float* wc1 = (const float*)d_in[6];
    const float* wc2 = (const float*)d_in[7];
    const float* wc3 = (const float*)d_in[8];
    const float* bc3 = (const float*)d_in[9];
    float* out = (float*)d_out;

    float* ws = (float*)d_ws;
    float*  scores4 = ws;                          // 16,777,216 (4 x N x N)
    float*  xxf     = ws + 16777216;               // 8,192
    double* xxd     = (double*)(ws + 16785408);    // 8,192 d
    int*    cand    = (int*)(ws + 16801792);       // 262,144
    int*    idx     = (int*)(ws + 17063936);       // 163,840
    float*  xT      = ws + 17227776;               // 3,145,728
    double* Pfd     = (double*)(ws + 20373504);    // 524,288 d each (point-major [b*N+n][64])
    double* Qfd     = (double*)(ws + 21422080);
    double* Pdd     = (double*)(ws + 22470656);
    double* Qdd     = (double*)(ws + 23519232);
    double* part1   = (double*)(ws + 24567808);    // 640*42 d
    double* part2   = (double*)(ws + 24621568);    // 5120*42 d
    double* st1     = (double*)(ws + 25051648);    // 42 d
    double* st2     = (double*)(ws + 25051776);    // 42 d
    float*  sums_f  = ws + 25051904;               // 1024
    float*  stats_f = ws + 25052928;               // 1024
    double* dots    = (double*)(ws + 25053952);    // 3,440,640 d
    float*  h2f     = ws + 31935232;               // 10,321,920
    float*  pooled  = ws + 42257152;               // 516,096
    float*  y1      = ws + 42773248;               // 2,097,152
    float*  y2      = ws + 44870400;               // 1,048,576 (end 45,918,976 f = 176 MB)

    k_zero<<<4, 256, 0, stream>>>(sums_f, 1024);
    k_xx<<<BB*NPT/256, 256, 0, stream>>>(x, xxf, xxd);
    k_xt<<<dim3(NPT/64, CC/64, BB), 256, 0, stream>>>(x, xT);
    k_gram<<<dim3(136, BB), 256, 0, stream>>>(x, xxf, scores4);
    k_topk<<<dim3(NPT, BB), 256, 0, stream>>>(scores4, cand);
    k_rescore<<<BB*NPT, 256, 0, stream>>>(xT, xxd, cand, idx);
    k_pq_d<<<BB*NPT*64/256, 256, 0, stream>>>(x, w1f, w1d, Pfd, Qfd, Pdd, Qdd);
    k_bn1_part<<<TOT/256, 256, 0, stream>>>(Pfd, Qfd, idx, part1);
    k_fin_d<<<NCH, 256, 0, stream>>>(part1, st1, TOT/256, (double)TOT);
    k_b1_bn2part<<<TOT/32, 256, 0, stream>>>(Pfd, Qfd, Pdd, Qdd, idx, st1, w2f, part2);
    k_fin_d<<<NCH, 256, 0, stream>>>(part2, st2, TOT/32, (double)TOT);
    k_apply_d<<<TOT/32, 256, 0, stream>>>(Pfd, Qfd, Pdd, Qdd, idx, st1, st2, w2f, w2d, wp, h2f, dots);
    k_pool_d<<<BB*NPT, 32, 0, stream>>>(dots, h2f, pooled);
    k_conv1<<<dim3(NPT/256, 256, BB), 256, 0, stream>>>(pooled, wc1, y1, sums_f);
    k_finalize<<<1, 256, 0, stream>>>(sums_f, stats_f, 1.f/(float)(BB*NPT), 256);
    k_act<<<BB*256*NPT/256, 256, 0, stream>>>(y1, stats_f, 256);
    k_conv2<<<dim3(NPT/256, 128, BB), 256, 0, stream>>>(y1, wc2, y2, sums_f+512);
    k_finalize<<<1, 128, 0, stream>>>(sums_f+512, stats_f+512, 1.f/(float)(BB*NPT), 128);
    k_final<<<BB*NPT/256, 256, 0, stream>>>(y2, wc3, bc3, stats_f+512, out);
}

// Round 11
// 880.655 us; speedup vs baseline: 1.0894x; 1.0894x over previous
//
#include <hip/hip_runtime.h>
#include <cstddef>

#define BB 4
#define CC 384
#define NPT 2048
#define KNN 20
#define NCAND 32
#define NCH 21
#define NKT (NPT*KNN)
#define TOT (BB*NKT)
#define EPSD 1e-6
#define BNEPSD 1e-5
#define EPSF 1e-6f
#define BNEPS 1e-5f
#define NEGS 0.2f

// ---------------- zero ----------------
__global__ __launch_bounds__(256) void k_zero(float* p, int n) {
    int t = blockIdx.x*256 + threadIdx.x;
    if (t < n) p[t] = 0.f;
}

// ---------------- xx = sum_c x^2 (f64) ----------------
__global__ __launch_bounds__(256) void k_xx(const float* __restrict__ x, float* __restrict__ xx,
                                            double* __restrict__ xxd) {
    int t = blockIdx.x*256 + threadIdx.x;       // B*N
    int n = t & (NPT-1); int b = t >> 11;
    const float* xp = x + (size_t)b*CC*NPT + n;
    double acc = 0.0;
    #pragma unroll 8
    for (int c = 0; c < CC; c++) { double v = (double)xp[(size_t)c*NPT]; acc += v*v; }
    xx[t] = (float)acc;
    xxd[t] = acc;
}

// ---------------- transpose x -> xT (B,N,C) ----------------
__global__ __launch_bounds__(256) void k_xt(const float* __restrict__ x, float* __restrict__ xT) {
    __shared__ float tile[64][65];
    int n0 = blockIdx.x*64, c0 = blockIdx.y*64, b = blockIdx.z;
    int tx = threadIdx.x & 63, ty = threadIdx.x >> 6;
    const float* xb = x + (size_t)b*CC*NPT;
    #pragma unroll
    for (int r = 0; r < 64; r += 4)
        tile[r+ty][tx] = xb[(size_t)(c0+r+ty)*NPT + n0 + tx];
    __syncthreads();
    float* xtb = xT + (size_t)b*NPT*CC;
    #pragma unroll
    for (int r = 0; r < 64; r += 4)
        xtb[(size_t)(n0+r+ty)*CC + c0 + tx] = tile[tx][r+ty];
}

// ---------------- f32 Gram, 128x128 tiles, 8x8/thread, triangular grid ----------------
__global__ __launch_bounds__(256) void k_gram(const float* __restrict__ x, const float* __restrict__ xx,
                                              float* __restrict__ scores4) {
    __shared__ float As[16][128];
    __shared__ float Bs[16][128];
    int tid = blockIdx.x;               // 0..135 triangular tile
    int b = blockIdx.y;
    int by = 0, rem = tid;
    while (rem >= 16 - by) { rem -= 16 - by; by++; }
    int bx = by + rem;
    int n0 = by*128, m0 = bx*128;
    int t = threadIdx.x;
    int tx = t & 15, ty = t >> 4;
    const float* xb = x + (size_t)b*CC*NPT;
    float* scores = scores4 + (size_t)b*NPT*NPT;
    float acc[8][8] = {};
    for (int c0 = 0; c0 < CC; c0 += 16) {
        #pragma unroll
        for (int i = 0; i < 8; i++) {
            int e = t + i*256;
            int cc = e >> 7, col = e & 127;
            As[cc][col] = xb[(size_t)(c0+cc)*NPT + n0 + col];
            Bs[cc][col] = xb[(size_t)(c0+cc)*NPT + m0 + col];
        }
        __syncthreads();
        #pragma unroll
        for (int kk = 0; kk < 16; kk++) {
            float4 a0 = *(const float4*)&As[kk][ty*8];
            float4 a1 = *(const float4*)&As[kk][ty*8+4];
            float4 b0 = *(const float4*)&Bs[kk][tx*8];
            float4 b1 = *(const float4*)&Bs[kk][tx*8+4];
            float av[8] = {a0.x,a0.y,a0.z,a0.w,a1.x,a1.y,a1.z,a1.w};
            float bv[8] = {b0.x,b0.y,b0.z,b0.w,b1.x,b1.y,b1.z,b1.w};
            #pragma unroll
            for (int i = 0; i < 8; i++)
                #pragma unroll
                for (int j = 0; j < 8; j++)
                    acc[i][j] += av[i]*bv[j];
        }
        __syncthreads();
    }
    int nb = n0 + ty*8, mb = m0 + tx*8;
    float xn[8], xm[8];
    #pragma unroll
    for (int i = 0; i < 8; i++) { xn[i] = xx[b*NPT + nb + i]; xm[i] = xx[b*NPT + mb + i]; }
    float val[8][8];
    #pragma unroll
    for (int i = 0; i < 8; i++)
        #pragma unroll
        for (int j = 0; j < 8; j++) {
            val[i][j] = 2.f*acc[i][j] - xn[i] - xm[j];
            scores[(size_t)(nb+i)*NPT + mb + j] = val[i][j];
        }
    if (bx != by) {
        #pragma unroll
        for (int j = 0; j < 8; j++)
            #pragma unroll
            for (int i = 0; i < 8; i++)
                scores[(size_t)(mb+j)*NPT + nb + i] = val[i][j];
    }
}

// ---------------- top-NCAND per row: radix select (set-identical to f32 top-32) ----------------
__global__ __launch_bounds__(256) void k_topk(const float* __restrict__ scores4, int* __restrict__ candout) {
    int n = blockIdx.x, b = blockIdx.y;
    const float* row = scores4 + ((size_t)b*NPT + n)*NPT;
    unsigned key[8];
    #pragma unroll
    for (int w = 0; w < 8; w++) {
        unsigned u = __float_as_uint(row[threadIdx.x + w*256]);
        key[w] = (u & 0x80000000u) ? ~u : (u | 0x80000000u);   // monotone float->uint
    }
    __shared__ int hist[4][257];
    __shared__ int histsum[256];
    __shared__ unsigned s_pfx;
    __shared__ int s_need, s_slot, s_tie;
    __shared__ unsigned long long tiel[256];
    int wv = threadIdx.x >> 6;
    if (threadIdx.x == 0) { s_pfx = 0u; s_need = NCAND; s_slot = 0; s_tie = 0; }
    #pragma unroll
    for (int pass = 0; pass < 3; pass++) {
        int sh = (pass == 0) ? 24 : (pass == 1 ? 16 : 8);
        unsigned maskhi = (pass == 0) ? 0u : (pass == 1 ? 0xFF000000u : 0xFFFF0000u);
        hist[0][threadIdx.x] = 0; hist[1][threadIdx.x] = 0;
        hist[2][threadIdx.x] = 0; hist[3][threadIdx.x] = 0;
        __syncthreads();
        unsigned pfx = s_pfx;
        #pragma unroll
        for (int w = 0; w < 8; w++) {
            unsigned v = key[w];
            if ((v & maskhi) == (pfx & maskhi))
                atomicAdd(&hist[wv][(v >> sh) & 0xFF], 1);
        }
        __syncthreads();
        histsum[threadIdx.x] = hist[0][threadIdx.x] + hist[1][threadIdx.x]
                             + hist[2][threadIdx.x] + hist[3][threadIdx.x];
        __syncthreads();
        if (threadIdx.x < 64) {
            int l = threadIdx.x, base = l*4;
            int c0 = histsum[base], c1 = histsum[base+1], c2 = histsum[base+2], c3 = histsum[base+3];
            int mysum = c0 + c1 + c2 + c3;
            int suf = mysum;
            #pragma unroll
            for (int st = 1; st < 64; st <<= 1) {
                int u2 = __shfl_down(suf, st);
                if (l + st >= 64) u2 = 0;
                suf += u2;
            }
            int need = s_need;
            int sufNext = suf - mysum;
            if (suf >= need && sufNext < need) {        // exactly one lane
                int s3 = sufNext + c3, s2p = s3 + c2, s1p = s2p + c1;
                int B, Sb1;
                if (s3 >= need)       { B = base+3; Sb1 = sufNext; }
                else if (s2p >= need) { B = base+2; Sb1 = s3; }
                else if (s1p >= need) { B = base+1; Sb1 = s2p; }
                else                  { B = base;   Sb1 = s1p; }
                s_pfx = s_pfx | ((unsigned)B << sh);
                s_need = need - Sb1;
            }
        }
        __syncthreads();
    }
    unsigned pfx24 = s_pfx & 0xFFFFFF00u;
    int* outp = candout + ((size_t)b*NPT + n)*NCAND;
    #pragma unroll
    for (int w = 0; w < 8; w++) {
        unsigned v = key[w];
        unsigned hi = v & 0xFFFFFF00u;
        int i = threadIdx.x + w*256;
        if (hi > pfx24) {
            int s = atomicAdd(&s_slot, 1);
            outp[s] = i;
        } else if (hi == pfx24) {
            int ti = atomicAdd(&s_tie, 1);
            if (ti < 256) tiel[ti] = ((unsigned long long)v << 32) | (unsigned)(NPT-1-i);
        }
    }
    __syncthreads();
    if (threadIdx.x == 0) {
        int A = s_slot, r = s_need, T = s_tie < 256 ? s_tie : 256;
        for (int kk = 0; kk < r; kk++) {
            unsigned long long best = 0ull; int bj = 0;
            for (int j2 = 0; j2 < T; j2++) if (tiel[j2] > best) { best = tiel[j2]; bj = j2; }
            tiel[bj] = 0ull;
            outp[A + kk] = NPT-1-(int)(best & 0xFFFFFFFFu);
        }
    }
}

// ---------------- exact f64 rescore -> final top-20 (wave-parallel selection) ----------------
__global__ __launch_bounds__(256) void k_rescore(const float* __restrict__ xT, const double* __restrict__ xxd,
                                                 const int* __restrict__ cand, int* __restrict__ idxout) {
    __shared__ float xn[CC];
    __shared__ double sc[NCAND];
    __shared__ int ci[NCAND];
    int t = blockIdx.x;             // b*N + n
    int b = t >> 11;
    const float* xrow = xT + (size_t)t*CC;
    for (int i = threadIdx.x; i < CC; i += 256) xn[i] = xrow[i];
    if (threadIdx.x < NCAND) ci[threadIdx.x] = cand[(size_t)t*NCAND + threadIdx.x];
    __syncthreads();
    int j = threadIdx.x >> 3, l = threadIdx.x & 7;
    int m = ci[j];
    const float* xm = xT + ((size_t)b*NPT + m)*CC;
    double acc = 0.0;
    int cbase = l*48;
    #pragma unroll 8
    for (int c = 0; c < 48; c++) acc += (double)xn[cbase+c] * (double)xm[cbase+c];
    acc += __shfl_down(acc, 4, 8);
    acc += __shfl_down(acc, 2, 8);
    acc += __shfl_down(acc, 1, 8);
    if (l == 0) sc[j] = 2.0*acc - xxd[t] - xxd[(size_t)b*NPT + m];
    __syncthreads();
    if (threadIdx.x < 64) {
        double v = (threadIdx.x < NCAND) ? sc[threadIdx.x] : -1e300;
        int oi = (threadIdx.x < NCAND) ? ci[threadIdx.x] : NPT;
        for (int kk = 0; kk < KNN; kk++) {
            double bv = v; int bo = oi;
            #pragma unroll
            for (int st = 16; st > 0; st >>= 1) {
                double ov = __shfl_xor(bv, st, 32);
                int    oo = __shfl_xor(bo, st, 32);
                if (ov > bv || (ov == bv && oo < bo)) { bv = ov; bo = oo; }
            }
            if (threadIdx.x == 0) idxout[(size_t)t*KNN + kk] = bo;
            if (oi == bo) v = -1e300;   // unique owner eliminates winner
        }
    }
}

// ---------------- P/Q precompute (f64), point-major out, xT-fed LDS staging ----------------
__global__ __launch_bounds__(256) void k_pq_d(const float* __restrict__ xT,
                                              const float* __restrict__ wf, const float* __restrict__ wd,
                                              double* __restrict__ Pf, double* __restrict__ Qf,
                                              double* __restrict__ Pd, double* __restrict__ Qd) {
    __shared__ float xs[4][CC];
    int pt = threadIdx.x >> 6;                  // 0..3 local point
    int ov = threadIdx.x & 63;
    int row0 = blockIdx.x*4;                    // b*N+n base
    for (int i = threadIdx.x; i < 4*CC; i += 256)
        xs[i/CC][i%CC] = xT[(size_t)(row0 + i/CC)*CC + (i%CC)];
    __syncthreads();
    if (ov >= 63) return;
    int o = ov / 3, v = ov % 3;
    const float* wfo = wf + o*256;
    const float* wdo = wd + o*256;
    const float* xp = &xs[pt][v];
    double pf = 0.0, qf = 0.0, pd = 0.0, qd = 0.0;
    #pragma unroll 4
    for (int c3 = 0; c3 < 128; c3++) {
        double xv = (double)xp[c3*3];
        double waf = (double)wfo[c3], wbf = (double)wfo[128+c3];
        double wad = (double)wdo[c3], wbd = (double)wdo[128+c3];
        pf += waf*xv; qf += (wbf-waf)*xv;
        pd += wad*xv; qd += (wbd-wad)*xv;
    }
    size_t off = (size_t)(row0 + pt)*64 + ov;
    Pf[off] = pf; Qf[off] = qf; Pd[off] = pd; Qd[off] = qd;
}

// ---------------- BN1 partial sums (f64, deterministic) ----------------
__global__ __launch_bounds__(256) void k_bn1_part(const double* __restrict__ Pf, const double* __restrict__ Qf,
                                                  const int* __restrict__ idx, double* __restrict__ part) {
    __shared__ double red[4][42];
    int t = blockIdx.x*256 + threadIdx.x;       // (b*N+n)*K+k
    int bn = t / KNN;
    int n = bn & (NPT-1); int b = bn >> 11;
    int m = idx[t];
    const double* PF = Pf + ((size_t)b*NPT + m)*64;
    const double* QF = Qf + ((size_t)b*NPT + n)*64;
    int wave = threadIdx.x >> 6;
    #pragma unroll
    for (int o = 0; o < NCH; o++) {
        double p0 = PF[o*3+0] + QF[o*3+0];
        double p1 = PF[o*3+1] + QF[o*3+1];
        double p2 = PF[o*3+2] + QF[o*3+2];
        double nr = sqrt(p0*p0 + p1*p1 + p2*p2) + EPSD;
        double a = nr, c2 = nr*nr;
        #pragma unroll
        for (int st = 32; st > 0; st >>= 1) { a += __shfl_down(a, st); c2 += __shfl_down(c2, st); }
        if ((threadIdx.x & 63) == 0) { red[wave][o] = a; red[wave][NCH+o] = c2; }
    }
    __syncthreads();
    if (threadIdx.x < 42)
        part[(size_t)blockIdx.x*42 + threadIdx.x] =
            red[0][threadIdx.x] + red[1][threadIdx.x] + red[2][threadIdx.x] + red[3][threadIdx.x];
}

// ---------------- finalize f64 stats (parallel: 21 blocks x 256 thr) ----------------
__global__ __launch_bounds__(256) void k_fin_d(const double* __restrict__ part, double* __restrict__ st,
                                               int nblk, double cnt) {
    __shared__ double r0[4], r1[4];
    int o = blockIdx.x;             // 0..NCH-1
    double s0 = 0.0, s1 = 0.0;
    for (int i = threadIdx.x; i < nblk; i += 256) {
        s0 += part[(size_t)i*42 + o];
        s1 += part[(size_t)i*42 + NCH + o];
    }
    #pragma unroll
    for (int stp = 32; stp > 0; stp >>= 1) { s0 += __shfl_down(s0, stp); s1 += __shfl_down(s1, stp); }
    int wv = threadIdx.x >> 6;
    if ((threadIdx.x & 63) == 0) { r0[wv] = s0; r1[wv] = s1; }
    __syncthreads();
    if (threadIdx.x == 0) {
        double sum = r0[0]+r0[1]+r0[2]+r0[3];
        double ssq = r1[0]+r1[1]+r1[2]+r1[3];
        double mean = sum / cnt;
        double var = ssq / cnt - mean*mean;
        if (var < 0.0) var = 0.0;
        st[o] = mean;
        st[NCH+o] = 1.0 / sqrt(var + BNEPSD);
    }
}

// ---------------- block1 (f64) -> BN2 partials; 8 threads/pair, 32 pairs/block ----------------
__global__ __launch_bounds__(256) void k_b1_bn2part(const double* __restrict__ Pf, const double* __restrict__ Qf,
                                                    const double* __restrict__ Pd, const double* __restrict__ Qd,
                                                    const int* __restrict__ idx, const double* __restrict__ st1,
                                                    const float* __restrict__ w2f_g, double* __restrict__ part) {
    __shared__ double h1L[32][65];
    __shared__ double w2s[NCH*NCH];
    __shared__ double s1[42];
    __shared__ double wred[4][42];
    int tid = threadIdx.x;
    int p = tid >> 3, j = tid & 7;
    int t = blockIdx.x*32 + p;
    for (int i = tid; i < NCH*NCH; i += 256) w2s[i] = (double)w2f_g[i];
    if (tid < 42) s1[tid] = st1[tid];
    int bn = t / KNN;
    int n = bn & (NPT-1), b = bn >> 11;
    int m = idx[t];
    const double* PF = Pf + ((size_t)b*NPT + m)*64;
    const double* QF = Qf + ((size_t)b*NPT + n)*64;
    const double* PD = Pd + ((size_t)b*NPT + m)*64;
    const double* QD = Qd + ((size_t)b*NPT + n)*64;
    __syncthreads();
    for (int o = j; o < NCH; o += 8) {
        double p0 = PF[o*3+0] + QF[o*3+0];
        double p1 = PF[o*3+1] + QF[o*3+1];
        double p2 = PF[o*3+2] + QF[o*3+2];
        double d0 = PD[o*3+0] + QD[o*3+0];
        double d1 = PD[o*3+1] + QD[o*3+1];
        double d2 = PD[o*3+2] + QD[o*3+2];
        double nr = sqrt(p0*p0 + p1*p1 + p2*p2) + EPSD;
        double fac = (nr - s1[o]) * s1[NCH+o] / nr;
        p0 *= fac; p1 *= fac; p2 *= fac;
        double dot = p0*d0 + p1*d1 + p2*d2;
        double dd  = d0*d0 + d1*d1 + d2*d2;
        double coef = dot / (dd + EPSD);
        double w0 = (dot >= 0.0) ? p0 : (p0 - coef*d0);
        double w1 = (dot >= 0.0) ? p1 : (p1 - coef*d1);
        double w2 = (dot >= 0.0) ? p2 : (p2 - coef*d2);
        h1L[p][o*3+0] = 0.2*p0 + 0.8*w0;
        h1L[p][o*3+1] = 0.2*p1 + 0.8*w1;
        h1L[p][o*3+2] = 0.2*p2 + 0.8*w2;
    }
    __syncthreads();
    double s[3] = {0.0,0.0,0.0}, q[3] = {0.0,0.0,0.0};
    {
        int oi = 0;
        for (int o = j; o < NCH; o += 8, oi++) {
            double a0 = 0.0, a1 = 0.0, a2 = 0.0;
            #pragma unroll
            for (int c = 0; c < NCH; c++) {
                double w = w2s[o*NCH+c];
                a0 += w*h1L[p][c*3+0]; a1 += w*h1L[p][c*3+1]; a2 += w*h1L[p][c*3+2];
            }
            double nr = sqrt(a0*a0 + a1*a1 + a2*a2) + EPSD;
            s[oi] = nr; q[oi] = nr*nr;
        }
    }
    #pragma unroll
    for (int st = 8; st < 64; st <<= 1) {
        #pragma unroll
        for (int u = 0; u < 3; u++) { s[u] += __shfl_down(s[u], st); q[u] += __shfl_down(q[u], st); }
    }
    if ((tid & 63) < 8) {           // lanes 0..7 hold per-wave sums for their j
        int wv = tid >> 6, oi = 0;
        for (int o = j; o < NCH; o += 8, oi++) { wred[wv][o] = s[oi]; wred[wv][NCH+o] = q[oi]; }
    }
    __syncthreads();
    if (tid < 42)
        part[(size_t)blockIdx.x*42 + tid] = wred[0][tid]+wred[1][tid]+wred[2][tid]+wred[3][tid];
}

// ---------------- block1+block2 (f64) -> h2 f32 + pool dots f64; 8 thr/pair, single LDS tile ----------------
__global__ __launch_bounds__(256) void k_apply_d(const double* __restrict__ Pf, const double* __restrict__ Qf,
                                                 const double* __restrict__ Pd, const double* __restrict__ Qd,
                                                 const int* __restrict__ idx,
                                                 const double* __restrict__ st1, const double* __restrict__ st2,
                                                 const float* __restrict__ w2f_g, const float* __restrict__ w2d_g,
                                                 const float* __restrict__ wp_g,
                                                 float* __restrict__ h2f, double* __restrict__ dots) {
    __shared__ double hL[32][65];           // h1, then reused for h2
    __shared__ double w2fs[NCH*NCH];
    __shared__ double w2ds[NCH*NCH];
    __shared__ double wps[NCH*NCH];
    __shared__ double s1[42], s2[42];
    int tid = threadIdx.x;
    int p = tid >> 3, j = tid & 7;
    int t = blockIdx.x*32 + p;
    for (int i = tid; i < NCH*NCH; i += 256) {
        w2fs[i] = (double)w2f_g[i]; w2ds[i] = (double)w2d_g[i]; wps[i] = (double)wp_g[i];
    }
    if (tid < 42) { s1[tid] = st1[tid]; s2[tid] = st2[tid]; }
    int k = t % KNN; int bn = t / KNN;
    int n = bn & (NPT-1), b = bn >> 11;
    int m = idx[t];
    const double* PF = Pf + ((size_t)b*NPT + m)*64;
    const double* QF = Qf + ((size_t)b*NPT + n)*64;
    const double* PD = Pd + ((size_t)b*NPT + m)*64;
    const double* QD = Qd + ((size_t)b*NPT + n)*64;
    __syncthreads();
    // block1 -> hL (h1)
    #pragma unroll
    for (int oi = 0; oi < 3; oi++) {
        int o = j + oi*8;
        if (o < NCH) {
            double p0 = PF[o*3+0] + QF[o*3+0];
            double p1 = PF[o*3+1] + QF[o*3+1];
            double p2 = PF[o*3+2] + QF[o*3+2];
            double d0 = PD[o*3+0] + QD[o*3+0];
            double d1 = PD[o*3+1] + QD[o*3+1];
            double d2 = PD[o*3+2] + QD[o*3+2];
            double nr = sqrt(p0*p0 + p1*p1 + p2*p2) + EPSD;
            double fac = (nr - s1[o]) * s1[NCH+o] / nr;
            p0 *= fac; p1 *= fac; p2 *= fac;
            double dot = p0*d0 + p1*d1 + p2*d2;
            double dd  = d0*d0 + d1*d1 + d2*d2;
            double coef = dot / (dd + EPSD);
            double w0 = (dot >= 0.0) ? p0 : (p0 - coef*d0);
            double w1 = (dot >= 0.0) ? p1 : (p1 - coef*d1);
            double w2 = (dot >= 0.0) ? p2 : (p2 - coef*d2);
            hL[p][o*3+0] = 0.2*p0 + 0.8*w0;
            hL[p][o*3+1] = 0.2*p1 + 0.8*w1;
            hL[p][o*3+2] = 0.2*p2 + 0.8*w2;
        }
    }
    __syncthreads();
    // block2 into registers (compile-time oi indexing), write h2f as we go
    double h2r[3][3];
    #pragma unroll
    for (int oi = 0; oi < 3; oi++) {
        int o = j + oi*8;
        if (o < NCH) {
            double p0 = 0.0, p1 = 0.0, p2 = 0.0, d0 = 0.0, d1 = 0.0, d2 = 0.0;
            #pragma unroll
            for (int c = 0; c < NCH; c++) {
                double wa = w2fs[o*NCH+c], wb = w2ds[o*NCH+c];
                double x0 = hL[p][c*3+0], x1 = hL[p][c*3+1], x2 = hL[p][c*3+2];
                p0 += wa*x0; p1 += wa*x1; p2 += wa*x2;
                d0 += wb*x0; d1 += wb*x1; d2 += wb*x2;
            }
            double nr = sqrt(p0*p0 + p1*p1 + p2*p2) + EPSD;
            double fac = (nr - s2[o]) * s2[NCH+o] / nr;
            p0 *= fac; p1 *= fac; p2 *= fac;
            double dot = p0*d0 + p1*d1 + p2*d2;
            double dd  = d0*d0 + d1*d1 + d2*d2;
            double coef = dot / (dd + EPSD);
            double w0 = (dot >= 0.0) ? p0 : (p0 - coef*d0);
            double w1 = (dot >= 0.0) ? p1 : (p1 - coef*d1);
            double w2 = (dot >= 0.0) ? p2 : (p2 - coef*d2);
            double h0 = 0.2*p0 + 0.8*w0, h1v = 0.2*p1 + 0.8*w1, h2v = 0.2*p2 + 0.8*w2;
            h2r[oi][0] = h0; h2r[oi][1] = h1v; h2r[oi][2] = h2v;
            h2f[((size_t)(b*63 + o*3+0)*NPT + n)*KNN + k] = (float)h0;
            h2f[((size_t)(b*63 + o*3+1)*NPT + n)*KNN + k] = (float)h1v;
            h2f[((size_t)(b*63 + o*3+2)*NPT + n)*KNN + k] = (float)h2v;
        }
    }
    __syncthreads();        // everyone done reading h1
    #pragma unroll
    for (int oi = 0; oi < 3; oi++) {
        int o = j + oi*8;
        if (o < NCH) {
            hL[p][o*3+0] = h2r[oi][0];
            hL[p][o*3+1] = h2r[oi][1];
            hL[p][o*3+2] = h2r[oi][2];
        }
    }
    __syncthreads();
    // pool dots from hL (= h2)
    #pragma unroll
    for (int oi = 0; oi < 3; oi++) {
        int o = j + oi*8;
        if (o < NCH) {
            double dv0 = 0.0, dv1 = 0.0, dv2 = 0.0;
            #pragma unroll
            for (int c = 0; c < NCH; c++) {
                double w = wps[o*NCH+c];
                dv0 += w*hL[p][c*3+0]; dv1 += w*hL[p][c*3+1]; dv2 += w*hL[p][c*3+2];
            }
            double dt = hL[p][o*3+0]*dv0 + hL[p][o*3+1]*dv1 + hL[p][o*3+2]*dv2;
            dots[(((size_t)b*NCH + o)*NPT + n)*KNN + k] = dt;
        }
    }
}

// ---------------- pool: exact f64 argmax, gather f32 values ----------------
__global__ __launch_bounds__(32) void k_pool_d(const double* __restrict__ dots, const float* __restrict__ h2f,
                                               float* __restrict__ pooled) {
    int b = blockIdx.x >> 11, n = blockIdx.x & (NPT-1);
    int o = threadIdx.x;
    if (o >= NCH) return;
    const double* dp = dots + (((size_t)b*NCH + o)*NPT + n)*KNN;
    double best = dp[0]; int bk = 0;
    #pragma unroll
    for (int k = 1; k < KNN; k++) { double v = dp[k]; if (v > best) { best = v; bk = k; } }
    #pragma unroll
    for (int v = 0; v < 3; v++)
        pooled[((size_t)b*63 + o*3+v)*NPT + n] = h2f[(((size_t)b*63 + o*3+v)*NPT + n)*KNN + bk];
}

// ---------------- conv1 (63->256) + stats ----------------
__global__ __launch_bounds__(256) void k_conv1(const float* __restrict__ pooled, const float* __restrict__ w1,
                                               float* __restrict__ y1, float* __restrict__ sums) {
    int n = blockIdx.x*256 + threadIdx.x;
    int o = blockIdx.y, b = blockIdx.z;
    const float* pb = pooled + (size_t)b*63*NPT + n;
    const float* wo = w1 + o*63;
    float acc = 0.f;
    #pragma unroll
    for (int c = 0; c < 63; c++) acc += wo[c]*pb[(size_t)c*NPT];
    y1[((size_t)b*256 + o)*NPT + n] = acc;
    float a = acc, c2 = acc*acc;
    #pragma unroll
    for (int st = 32; st > 0; st >>= 1) { a += __shfl_down(a, st); c2 += __shfl_down(c2, st); }
    __shared__ float ra[4], rc[4];
    int wv = threadIdx.x >> 6;
    if ((threadIdx.x & 63) == 0) { ra[wv] = a; rc[wv] = c2; }
    __syncthreads();
    if (threadIdx.x == 0) {
        atomicAdd(&sums[o], ra[0]+ra[1]+ra[2]+ra[3]);
        atomicAdd(&sums[256+o], rc[0]+rc[1]+rc[2]+rc[3]);
    }
}

// ---------------- finalize f32 stats ----------------
__global__ void k_finalize(const float* __restrict__ sums, float* __restrict__ stats, float invcnt, int nch) {
    int o = blockIdx.x*blockDim.x + threadIdx.x;
    if (o >= nch) return;
    float mean = sums[o]*invcnt;
    float var = sums[nch+o]*invcnt - mean*mean;
    if (var < 0.f) var = 0.f;
    stats[o] = mean;
    stats[nch+o] = 1.0f / sqrtf(var + BNEPS);
}

// ---------------- bn+lrelu in place ----------------
__global__ __launch_bounds__(256) void k_act(float* __restrict__ y, const float* __restrict__ stats, int nch) {
    int t = blockIdx.x*256 + threadIdx.x;
    int o = (t >> 11) % nch;
    float z = (y[t] - stats[o]) * stats[nch+o];
    y[t] = z >= 0.f ? z : NEGS*z;
}

// ---------------- conv2 (256->128) + stats ----------------
__global__ __launch_bounds__(256) void k_conv2(const float* __restrict__ z1, const float* __restrict__ w2,
                                               float* __restrict__ y2, float* __restrict__ sums) {
    int n = blockIdx.x*256 + threadIdx.x;
    int o = blockIdx.y, b = blockIdx.z;
    const float* pb = z1 + (size_t)b*256*NPT + n;
    const float* wo = w2 + o*256;
    float acc = 0.f;
    #pragma unroll 4
    for (int c = 0; c < 256; c++) acc += wo[c]*pb[(size_t)c*NPT];
    y2[((size_t)b*128 + o)*NPT + n] = acc;
    float a = acc, c2 = acc*acc;
    #pragma unroll
    for (int st = 32; st > 0; st >>= 1) { a += __shfl_down(a, st); c2 += __shfl_down(c2, st); }
    __shared__ float ra[4], rc[4];
    int wv = threadIdx.x >> 6;
    if ((threadIdx.x & 63) == 0) { ra[wv] = a; rc[wv] = c2; }
    __syncthreads();
    if (threadIdx.x == 0) {
        atomicAdd(&sums[o], ra[0]+ra[1]+ra[2]+ra[3]);
        atomicAdd(&sums[128+o], rc[0]+rc[1]+rc[2]+rc[3]);
    }
}

// ---------------- final: act(conv2) -> conv3 + bias ----------------
__global__ __launch_bounds__(256) void k_final(const float* __restrict__ y2, const float* __restrict__ w3,
                                               const float* __restrict__ b3, const float* __restrict__ stats,
                                               float* __restrict__ out) {
    int t = blockIdx.x*256 + threadIdx.x;       // B*N
    int n = t & (NPT-1); int b = t >> 11;
    const float* yb = y2 + (size_t)b*128*NPT + n;
    float acc = b3[0];
    #pragma unroll 4
    for (int c = 0; c < 128; c++) {
        float z = (yb[(size_t)c*NPT] - stats[c]) * stats[128+c];
        z = z >= 0.f ? z : NEGS*z;
        acc += w3[c]*z;
    }
    out[t] = acc;
}

extern "C" void kernel_launch(void* const* d_in, const int* in_sizes, int n_in,
                              void* d_out, int out_size, void* d_ws, size_t ws_size,
                              hipStream_t stream) {
    const float* x   = (const float*)d_in[0];
    const float* w1f = (const float*)d_in[1];
    const float* w1d = (const float*)d_in[2];
    const float* w2f = (const float*)d_in[3];
    const float* w2d = (const float*)d_in[4];
    const float* wp  = (const float*)d_in[5];
    const float* wc1 = (const float*)d_in[6];
    const float* wc2 = (const float*)d_in[7];
    const float* wc3 = (const float*)d_in[8];
    const float* bc3 = (const float*)d_in[9];
    float* out = (float*)d_out;

    float* ws = (float*)d_ws;
    float*  scores4 = ws;                          // 16,777,216 (4 x N x N)
    float*  xxf     = ws + 16777216;               // 8,192
    double* xxd     = (double*)(ws + 16785408);    // 8,192 d
    int*    cand    = (int*)(ws + 16801792);       // 262,144
    int*    idx     = (int*)(ws + 17063936);       // 163,840
    float*  xT      = ws + 17227776;               // 3,145,728
    double* Pfd     = (double*)(ws + 20373504);    // 524,288 d each (point-major [b*N+n][64])
    double* Qfd     = (double*)(ws + 21422080);
    double* Pdd     = (double*)(ws + 22470656);
    double* Qdd     = (double*)(ws + 23519232);
    double* part1   = (double*)(ws + 24567808);    // 640*42 d
    double* part2   = (double*)(ws + 24621568);    // 5120*42 d
    double* st1     = (double*)(ws + 25051648);    // 42 d
    double* st2     = (double*)(ws + 25051776);    // 42 d
    float*  sums_f  = ws + 25051904;               // 1024
    float*  stats_f = ws + 25052928;               // 1024
    double* dots    = (double*)(ws + 25053952);    // 3,440,640 d
    float*  h2f     = ws + 31935232;               // 10,321,920
    float*  pooled  = ws + 42257152;               // 516,096
    float*  y1      = ws + 42773248;               // 2,097,152
    float*  y2      = ws + 44870400;               // 1,048,576 (end 45,918,976 f = 176 MB)

    k_zero<<<4, 256, 0, stream>>>(sums_f, 1024);
    k_xx<<<BB*NPT/256, 256, 0, stream>>>(x, xxf, xxd);
    k_xt<<<dim3(NPT/64, CC/64, BB), 256, 0, stream>>>(x, xT);
    k_gram<<<dim3(136, BB), 256, 0, stream>>>(x, xxf, scores4);
    k_topk<<<dim3(NPT, BB), 256, 0, stream>>>(scores4, cand);
    k_rescore<<<BB*NPT, 256, 0, stream>>>(xT, xxd, cand, idx);
    k_pq_d<<<BB*NPT/4, 256, 0, stream>>>(xT, w1f, w1d, Pfd, Qfd, Pdd, Qdd);
    k_bn1_part<<<TOT/256, 256, 0, stream>>>(Pfd, Qfd, idx, part1);
    k_fin_d<<<NCH, 256, 0, stream>>>(part1, st1, TOT/256, (double)TOT);
    k_b1_bn2part<<<TOT/32, 256, 0, stream>>>(Pfd, Qfd, Pdd, Qdd, idx, st1, w2f, part2);
    k_fin_d<<<NCH, 256, 0, stream>>>(part2, st2, TOT/32, (double)TOT);
    k_apply_d<<<TOT/32, 256, 0, stream>>>(Pfd, Qfd, Pdd, Qdd, idx, st1, st2, w2f, w2d, wp, h2f, dots);
    k_pool_d<<<BB*NPT, 32, 0, stream>>>(dots, h2f, pooled);
    k_conv1<<<dim3(NPT/256, 256, BB), 256, 0, stream>>>(pooled, wc1, y1, sums_f);
    k_finalize<<<1, 256, 0, stream>>>(sums_f, stats_f, 1.f/(float)(BB*NPT), 256);
    k_act<<<BB*256*NPT/256, 256, 0, stream>>>(y1, stats_f, 256);
    k_conv2<<<dim3(NPT/256, 128, BB), 256, 0, stream>>>(y1, wc2, y2, sums_f+512);
    k_finalize<<<1, 128, 0, stream>>>(sums_f+512, stats_f+512, 1.f/(float)(BB*NPT), 128);
    k_final<<<BB*NPT/256, 256, 0, stream>>>(y2, wc3, bc3, stats_f+512, out);
}

// Round 12
// 666.830 us; speedup vs baseline: 1.4387x; 1.3207x over previous
//
#include <hip/hip_runtime.h>
#include <cstddef>

#define BB 4
#define CC 384
#define NPT 2048
#define KNN 20
#define NCAND 32
#define NCH 21
#define NKT (NPT*KNN)
#define TOT (BB*NKT)
#define EPSD 1e-6
#define BNEPSD 1e-5
#define EPSF 1e-6f
#define BNEPS 1e-5f
#define NEGS 0.2f

// ---------------- zero ----------------
__global__ __launch_bounds__(256) void k_zero(float* p, int n) {
    int t = blockIdx.x*256 + threadIdx.x;
    if (t < n) p[t] = 0.f;
}

// ---------------- xx = sum_c x^2 (f64) ----------------
__global__ __launch_bounds__(256) void k_xx(const float* __restrict__ x, float* __restrict__ xx,
                                            double* __restrict__ xxd) {
    int t = blockIdx.x*256 + threadIdx.x;       // B*N
    int n = t & (NPT-1); int b = t >> 11;
    const float* xp = x + (size_t)b*CC*NPT + n;
    double acc = 0.0;
    #pragma unroll 8
    for (int c = 0; c < CC; c++) { double v = (double)xp[(size_t)c*NPT]; acc += v*v; }
    xx[t] = (float)acc;
    xxd[t] = acc;
}

// ---------------- transpose x -> xT (B,N,C) ----------------
__global__ __launch_bounds__(256) void k_xt(const float* __restrict__ x, float* __restrict__ xT) {
    __shared__ float tile[64][65];
    int n0 = blockIdx.x*64, c0 = blockIdx.y*64, b = blockIdx.z;
    int tx = threadIdx.x & 63, ty = threadIdx.x >> 6;
    const float* xb = x + (size_t)b*CC*NPT;
    #pragma unroll
    for (int r = 0; r < 64; r += 4)
        tile[r+ty][tx] = xb[(size_t)(c0+r+ty)*NPT + n0 + tx];
    __syncthreads();
    float* xtb = xT + (size_t)b*NPT*CC;
    #pragma unroll
    for (int r = 0; r < 64; r += 4)
        xtb[(size_t)(n0+r+ty)*CC + c0 + tx] = tile[tx][r+ty];
}

// ---------------- f32 Gram, 128x128 tiles, 8x8/thread, triangular grid ----------------
__global__ __launch_bounds__(256) void k_gram(const float* __restrict__ x, const float* __restrict__ xx,
                                              float* __restrict__ scores4) {
    __shared__ float As[16][128];
    __shared__ float Bs[16][128];
    int tid = blockIdx.x;               // 0..135 triangular tile
    int b = blockIdx.y;
    int by = 0, rem = tid;
    while (rem >= 16 - by) { rem -= 16 - by; by++; }
    int bx = by + rem;
    int n0 = by*128, m0 = bx*128;
    int t = threadIdx.x;
    int tx = t & 15, ty = t >> 4;
    const float* xb = x + (size_t)b*CC*NPT;
    float* scores = scores4 + (size_t)b*NPT*NPT;
    float acc[8][8] = {};
    for (int c0 = 0; c0 < CC; c0 += 16) {
        #pragma unroll
        for (int i = 0; i < 8; i++) {
            int e = t + i*256;
            int cc = e >> 7, col = e & 127;
            As[cc][col] = xb[(size_t)(c0+cc)*NPT + n0 + col];
            Bs[cc][col] = xb[(size_t)(c0+cc)*NPT + m0 + col];
        }
        __syncthreads();
        #pragma unroll
        for (int kk = 0; kk < 16; kk++) {
            float4 a0 = *(const float4*)&As[kk][ty*8];
            float4 a1 = *(const float4*)&As[kk][ty*8+4];
            float4 b0 = *(const float4*)&Bs[kk][tx*8];
            float4 b1 = *(const float4*)&Bs[kk][tx*8+4];
            float av[8] = {a0.x,a0.y,a0.z,a0.w,a1.x,a1.y,a1.z,a1.w};
            float bv[8] = {b0.x,b0.y,b0.z,b0.w,b1.x,b1.y,b1.z,b1.w};
            #pragma unroll
            for (int i = 0; i < 8; i++)
                #pragma unroll
                for (int j = 0; j < 8; j++)
                    acc[i][j] += av[i]*bv[j];
        }
        __syncthreads();
    }
    int nb = n0 + ty*8, mb = m0 + tx*8;
    float xn[8], xm[8];
    #pragma unroll
    for (int i = 0; i < 8; i++) { xn[i] = xx[b*NPT + nb + i]; xm[i] = xx[b*NPT + mb + i]; }
    float val[8][8];
    #pragma unroll
    for (int i = 0; i < 8; i++)
        #pragma unroll
        for (int j = 0; j < 8; j++) {
            val[i][j] = 2.f*acc[i][j] - xn[i] - xm[j];
            scores[(size_t)(nb+i)*NPT + mb + j] = val[i][j];
        }
    if (bx != by) {
        #pragma unroll
        for (int j = 0; j < 8; j++)
            #pragma unroll
            for (int i = 0; i < 8; i++)
                scores[(size_t)(mb+j)*NPT + nb + i] = val[i][j];
    }
}

// ---------------- top-NCAND per row: radix select (set-identical to f32 top-32) ----------------
__global__ __launch_bounds__(256) void k_topk(const float* __restrict__ scores4, int* __restrict__ candout) {
    int n = blockIdx.x, b = blockIdx.y;
    const float* row = scores4 + ((size_t)b*NPT + n)*NPT;
    unsigned key[8];
    #pragma unroll
    for (int w = 0; w < 8; w++) {
        unsigned u = __float_as_uint(row[threadIdx.x + w*256]);
        key[w] = (u & 0x80000000u) ? ~u : (u | 0x80000000u);   // monotone float->uint
    }
    __shared__ int hist[4][257];
    __shared__ int histsum[256];
    __shared__ unsigned s_pfx;
    __shared__ int s_need, s_slot, s_tie;
    __shared__ unsigned long long tiel[256];
    int wv = threadIdx.x >> 6;
    if (threadIdx.x == 0) { s_pfx = 0u; s_need = NCAND; s_slot = 0; s_tie = 0; }
    #pragma unroll
    for (int pass = 0; pass < 3; pass++) {
        int sh = (pass == 0) ? 24 : (pass == 1 ? 16 : 8);
        unsigned maskhi = (pass == 0) ? 0u : (pass == 1 ? 0xFF000000u : 0xFFFF0000u);
        hist[0][threadIdx.x] = 0; hist[1][threadIdx.x] = 0;
        hist[2][threadIdx.x] = 0; hist[3][threadIdx.x] = 0;
        __syncthreads();
        unsigned pfx = s_pfx;
        #pragma unroll
        for (int w = 0; w < 8; w++) {
            unsigned v = key[w];
            if ((v & maskhi) == (pfx & maskhi))
                atomicAdd(&hist[wv][(v >> sh) & 0xFF], 1);
        }
        __syncthreads();
        histsum[threadIdx.x] = hist[0][threadIdx.x] + hist[1][threadIdx.x]
                             + hist[2][threadIdx.x] + hist[3][threadIdx.x];
        __syncthreads();
        if (threadIdx.x < 64) {
            int l = threadIdx.x, base = l*4;
            int c0 = histsum[base], c1 = histsum[base+1], c2 = histsum[base+2], c3 = histsum[base+3];
            int mysum = c0 + c1 + c2 + c3;
            int suf = mysum;
            #pragma unroll
            for (int st = 1; st < 64; st <<= 1) {
                int u2 = __shfl_down(suf, st);
                if (l + st >= 64) u2 = 0;
                suf += u2;
            }
            int need = s_need;
            int sufNext = suf - mysum;
            if (suf >= need && sufNext < need) {        // exactly one lane
                int s3 = sufNext + c3, s2p = s3 + c2, s1p = s2p + c1;
                int B, Sb1;
                if (s3 >= need)       { B = base+3; Sb1 = sufNext; }
                else if (s2p >= need) { B = base+2; Sb1 = s3; }
                else if (s1p >= need) { B = base+1; Sb1 = s2p; }
                else                  { B = base;   Sb1 = s1p; }
                s_pfx = s_pfx | ((unsigned)B << sh);
                s_need = need - Sb1;
            }
        }
        __syncthreads();
    }
    unsigned pfx24 = s_pfx & 0xFFFFFF00u;
    int* outp = candout + ((size_t)b*NPT + n)*NCAND;
    #pragma unroll
    for (int w = 0; w < 8; w++) {
        unsigned v = key[w];
        unsigned hi = v & 0xFFFFFF00u;
        int i = threadIdx.x + w*256;
        if (hi > pfx24) {
            int s = atomicAdd(&s_slot, 1);
            outp[s] = i;
        } else if (hi == pfx24) {
            int ti = atomicAdd(&s_tie, 1);
            if (ti < 256) tiel[ti] = ((unsigned long long)v << 32) | (unsigned)(NPT-1-i);
        }
    }
    __syncthreads();
    if (threadIdx.x == 0) {
        int A = s_slot, r = s_need, T = s_tie < 256 ? s_tie : 256;
        for (int kk = 0; kk < r; kk++) {
            unsigned long long best = 0ull; int bj = 0;
            for (int j2 = 0; j2 < T; j2++) if (tiel[j2] > best) { best = tiel[j2]; bj = j2; }
            tiel[bj] = 0ull;
            outp[A + kk] = NPT-1-(int)(best & 0xFFFFFFFFu);
        }
    }
}

// ---------------- exact f64 rescore -> final top-20 (wave-parallel selection) ----------------
__global__ __launch_bounds__(256) void k_rescore(const float* __restrict__ xT, const double* __restrict__ xxd,
                                                 const int* __restrict__ cand, int* __restrict__ idxout) {
    __shared__ float xn[CC];
    __shared__ double sc[NCAND];
    __shared__ int ci[NCAND];
    int t = blockIdx.x;             // b*N + n
    int b = t >> 11;
    const float* xrow = xT + (size_t)t*CC;
    for (int i = threadIdx.x; i < CC; i += 256) xn[i] = xrow[i];
    if (threadIdx.x < NCAND) ci[threadIdx.x] = cand[(size_t)t*NCAND + threadIdx.x];
    __syncthreads();
    int j = threadIdx.x >> 3, l = threadIdx.x & 7;
    int m = ci[j];
    const float* xm = xT + ((size_t)b*NPT + m)*CC;
    double acc = 0.0;
    int cbase = l*48;
    #pragma unroll 8
    for (int c = 0; c < 48; c++) acc += (double)xn[cbase+c] * (double)xm[cbase+c];
    acc += __shfl_down(acc, 4, 8);
    acc += __shfl_down(acc, 2, 8);
    acc += __shfl_down(acc, 1, 8);
    if (l == 0) sc[j] = 2.0*acc - xxd[t] - xxd[(size_t)b*NPT + m];
    __syncthreads();
    if (threadIdx.x < 64) {
        double v = (threadIdx.x < NCAND) ? sc[threadIdx.x] : -1e300;
        int oi = (threadIdx.x < NCAND) ? ci[threadIdx.x] : NPT;
        for (int kk = 0; kk < KNN; kk++) {
            double bv = v; int bo = oi;
            #pragma unroll
            for (int st = 16; st > 0; st >>= 1) {
                double ov = __shfl_xor(bv, st, 32);
                int    oo = __shfl_xor(bo, st, 32);
                if (ov > bv || (ov == bv && oo < bo)) { bv = ov; bo = oo; }
            }
            if (threadIdx.x == 0) idxout[(size_t)t*KNN + kk] = bo;
            if (oi == bo) v = -1e300;   // unique owner eliminates winner
        }
    }
}

// ---------------- P/Q precompute (f64), point-major out, LDS x + LDS transposed weights ----------------
__global__ __launch_bounds__(256) void k_pq_d(const float* __restrict__ xT,
                                              const float* __restrict__ wf, const float* __restrict__ wd,
                                              double* __restrict__ Pf, double* __restrict__ Qf,
                                              double* __restrict__ Pd, double* __restrict__ Qd) {
    __shared__ float xs[4][CC];             // 6144 B
    __shared__ float wfa[128*NCH];          // wf[o*256+c3]      -> [c3*21+o]
    __shared__ float wfb[128*NCH];          // wf[o*256+128+c3]  -> [c3*21+o]
    __shared__ float wda[128*NCH];
    __shared__ float wdb[128*NCH];
    int pt = threadIdx.x >> 6;                  // 0..3 local point
    int ov = threadIdx.x & 63;
    int row0 = blockIdx.x*4;                    // b*N+n base
    for (int i = threadIdx.x; i < 4*CC; i += 256)
        xs[i/CC][i%CC] = xT[(size_t)(row0 + i/CC)*CC + (i%CC)];
    for (int i = threadIdx.x; i < 128*NCH; i += 256) {
        int o2 = i >> 7, c3 = i & 127;          // o2=0..20, c3 coalesced
        wfa[c3*NCH+o2] = wf[o2*256 + c3];
        wfb[c3*NCH+o2] = wf[o2*256 + 128 + c3];
        wda[c3*NCH+o2] = wd[o2*256 + c3];
        wdb[c3*NCH+o2] = wd[o2*256 + 128 + c3];
    }
    __syncthreads();
    if (ov >= 63) return;
    int o = ov / 3, v = ov % 3;
    const float* xp = &xs[pt][v];
    double pf = 0.0, qf = 0.0, pd = 0.0, qd = 0.0;
    #pragma unroll 4
    for (int c3 = 0; c3 < 128; c3++) {
        double xv = (double)xp[c3*3];
        double waf = (double)wfa[c3*NCH+o], wbf = (double)wfb[c3*NCH+o];
        double wad = (double)wda[c3*NCH+o], wbd = (double)wdb[c3*NCH+o];
        pf += waf*xv; qf += (wbf-waf)*xv;
        pd += wad*xv; qd += (wbd-wad)*xv;
    }
    size_t off = (size_t)(row0 + pt)*64 + ov;
    Pf[off] = pf; Qf[off] = qf; Pd[off] = pd; Qd[off] = qd;
}

// ---------------- BN1 partial sums (f64, deterministic) ----------------
__global__ __launch_bounds__(256) void k_bn1_part(const double* __restrict__ Pf, const double* __restrict__ Qf,
                                                  const int* __restrict__ idx, double* __restrict__ part) {
    __shared__ double red[4][42];
    int t = blockIdx.x*256 + threadIdx.x;       // (b*N+n)*K+k
    int bn = t / KNN;
    int n = bn & (NPT-1); int b = bn >> 11;
    int m = idx[t];
    const double* PF = Pf + ((size_t)b*NPT + m)*64;
    const double* QF = Qf + ((size_t)b*NPT + n)*64;
    int wave = threadIdx.x >> 6;
    #pragma unroll
    for (int o = 0; o < NCH; o++) {
        double p0 = PF[o*3+0] + QF[o*3+0];
        double p1 = PF[o*3+1] + QF[o*3+1];
        double p2 = PF[o*3+2] + QF[o*3+2];
        double nr = sqrt(p0*p0 + p1*p1 + p2*p2) + EPSD;
        double a = nr, c2 = nr*nr;
        #pragma unroll
        for (int st = 32; st > 0; st >>= 1) { a += __shfl_down(a, st); c2 += __shfl_down(c2, st); }
        if ((threadIdx.x & 63) == 0) { red[wave][o] = a; red[wave][NCH+o] = c2; }
    }
    __syncthreads();
    if (threadIdx.x < 42)
        part[(size_t)blockIdx.x*42 + threadIdx.x] =
            red[0][threadIdx.x] + red[1][threadIdx.x] + red[2][threadIdx.x] + red[3][threadIdx.x];
}

// ---------------- finalize f64 stats (parallel: 21 blocks x 256 thr) ----------------
__global__ __launch_bounds__(256) void k_fin_d(const double* __restrict__ part, double* __restrict__ st,
                                               int nblk, double cnt) {
    __shared__ double r0[4], r1[4];
    int o = blockIdx.x;             // 0..NCH-1
    double s0 = 0.0, s1 = 0.0;
    for (int i = threadIdx.x; i < nblk; i += 256) {
        s0 += part[(size_t)i*42 + o];
        s1 += part[(size_t)i*42 + NCH + o];
    }
    #pragma unroll
    for (int stp = 32; stp > 0; stp >>= 1) { s0 += __shfl_down(s0, stp); s1 += __shfl_down(s1, stp); }
    int wv = threadIdx.x >> 6;
    if ((threadIdx.x & 63) == 0) { r0[wv] = s0; r1[wv] = s1; }
    __syncthreads();
    if (threadIdx.x == 0) {
        double sum = r0[0]+r0[1]+r0[2]+r0[3];
        double ssq = r1[0]+r1[1]+r1[2]+r1[3];
        double mean = sum / cnt;
        double var = ssq / cnt - mean*mean;
        if (var < 0.0) var = 0.0;
        st[o] = mean;
        st[NCH+o] = 1.0 / sqrt(var + BNEPSD);
    }
}

// ---------------- block1 (f64) -> BN2 partials; 8 threads/pair, 32 pairs/block ----------------
__global__ __launch_bounds__(256) void k_b1_bn2part(const double* __restrict__ Pf, const double* __restrict__ Qf,
                                                    const double* __restrict__ Pd, const double* __restrict__ Qd,
                                                    const int* __restrict__ idx, const double* __restrict__ st1,
                                                    const float* __restrict__ w2f_g, double* __restrict__ part) {
    __shared__ double h1L[32][65];
    __shared__ double w2s[NCH*NCH];
    __shared__ double s1[42];
    __shared__ double wred[4][42];
    int tid = threadIdx.x;
    int p = tid >> 3, j = tid & 7;
    int t = blockIdx.x*32 + p;
    for (int i = tid; i < NCH*NCH; i += 256) w2s[i] = (double)w2f_g[i];
    if (tid < 42) s1[tid] = st1[tid];
    int bn = t / KNN;
    int n = bn & (NPT-1), b = bn >> 11;
    int m = idx[t];
    const double* PF = Pf + ((size_t)b*NPT + m)*64;
    const double* QF = Qf + ((size_t)b*NPT + n)*64;
    const double* PD = Pd + ((size_t)b*NPT + m)*64;
    const double* QD = Qd + ((size_t)b*NPT + n)*64;
    __syncthreads();
    for (int o = j; o < NCH; o += 8) {
        double p0 = PF[o*3+0] + QF[o*3+0];
        double p1 = PF[o*3+1] + QF[o*3+1];
        double p2 = PF[o*3+2] + QF[o*3+2];
        double d0 = PD[o*3+0] + QD[o*3+0];
        double d1 = PD[o*3+1] + QD[o*3+1];
        double d2 = PD[o*3+2] + QD[o*3+2];
        double nr = sqrt(p0*p0 + p1*p1 + p2*p2) + EPSD;
        double fac = (nr - s1[o]) * s1[NCH+o] / nr;
        p0 *= fac; p1 *= fac; p2 *= fac;
        double dot = p0*d0 + p1*d1 + p2*d2;
        double dd  = d0*d0 + d1*d1 + d2*d2;
        double coef = dot / (dd + EPSD);
        double w0 = (dot >= 0.0) ? p0 : (p0 - coef*d0);
        double w1 = (dot >= 0.0) ? p1 : (p1 - coef*d1);
        double w2 = (dot >= 0.0) ? p2 : (p2 - coef*d2);
        h1L[p][o*3+0] = 0.2*p0 + 0.8*w0;
        h1L[p][o*3+1] = 0.2*p1 + 0.8*w1;
        h1L[p][o*3+2] = 0.2*p2 + 0.8*w2;
    }
    __syncthreads();
    double s[3] = {0.0,0.0,0.0}, q[3] = {0.0,0.0,0.0};
    {
        int oi = 0;
        for (int o = j; o < NCH; o += 8, oi++) {
            double a0 = 0.0, a1 = 0.0, a2 = 0.0;
            #pragma unroll
            for (int c = 0; c < NCH; c++) {
                double w = w2s[o*NCH+c];
                a0 += w*h1L[p][c*3+0]; a1 += w*h1L[p][c*3+1]; a2 += w*h1L[p][c*3+2];
            }
            double nr = sqrt(a0*a0 + a1*a1 + a2*a2) + EPSD;
            s[oi] = nr; q[oi] = nr*nr;
        }
    }
    #pragma unroll
    for (int st = 8; st < 64; st <<= 1) {
        #pragma unroll
        for (int u = 0; u < 3; u++) { s[u] += __shfl_down(s[u], st); q[u] += __shfl_down(q[u], st); }
    }
    if ((tid & 63) < 8) {           // lanes 0..7 hold per-wave sums for their j
        int wv = tid >> 6, oi = 0;
        for (int o = j; o < NCH; o += 8, oi++) { wred[wv][o] = s[oi]; wred[wv][NCH+o] = q[oi]; }
    }
    __syncthreads();
    if (tid < 42)
        part[(size_t)blockIdx.x*42 + tid] = wred[0][tid]+wred[1][tid]+wred[2][tid]+wred[3][tid];
}

// ---------------- block1+block2 (f64) -> h2 f32 + pool dots f64; 8 thr/pair, single LDS tile ----------------
__global__ __launch_bounds__(256) void k_apply_d(const double* __restrict__ Pf, const double* __restrict__ Qf,
                                                 const double* __restrict__ Pd, const double* __restrict__ Qd,
                                                 const int* __restrict__ idx,
                                                 const double* __restrict__ st1, const double* __restrict__ st2,
                                                 const float* __restrict__ w2f_g, const float* __restrict__ w2d_g,
                                                 const float* __restrict__ wp_g,
                                                 float* __restrict__ h2f, double* __restrict__ dots) {
    __shared__ double hL[32][65];           // h1, then reused for h2
    __shared__ double w2fs[NCH*NCH];
    __shared__ double w2ds[NCH*NCH];
    __shared__ double wps[NCH*NCH];
    __shared__ double s1[42], s2[42];
    int tid = threadIdx.x;
    int p = tid >> 3, j = tid & 7;
    int t = blockIdx.x*32 + p;
    for (int i = tid; i < NCH*NCH; i += 256) {
        w2fs[i] = (double)w2f_g[i]; w2ds[i] = (double)w2d_g[i]; wps[i] = (double)wp_g[i];
    }
    if (tid < 42) { s1[tid] = st1[tid]; s2[tid] = st2[tid]; }
    int k = t % KNN; int bn = t / KNN;
    int n = bn & (NPT-1), b = bn >> 11;
    int m = idx[t];
    const double* PF = Pf + ((size_t)b*NPT + m)*64;
    const double* QF = Qf + ((size_t)b*NPT + n)*64;
    const double* PD = Pd + ((size_t)b*NPT + m)*64;
    const double* QD = Qd + ((size_t)b*NPT + n)*64;
    __syncthreads();
    // block1 -> hL (h1)
    #pragma unroll
    for (int oi = 0; oi < 3; oi++) {
        int o = j + oi*8;
        if (o < NCH) {
            double p0 = PF[o*3+0] + QF[o*3+0];
            double p1 = PF[o*3+1] + QF[o*3+1];
            double p2 = PF[o*3+2] + QF[o*3+2];
            double d0 = PD[o*3+0] + QD[o*3+0];
            double d1 = PD[o*3+1] + QD[o*3+1];
            double d2 = PD[o*3+2] + QD[o*3+2];
            double nr = sqrt(p0*p0 + p1*p1 + p2*p2) + EPSD;
            double fac = (nr - s1[o]) * s1[NCH+o] / nr;
            p0 *= fac; p1 *= fac; p2 *= fac;
            double dot = p0*d0 + p1*d1 + p2*d2;
            double dd  = d0*d0 + d1*d1 + d2*d2;
            double coef = dot / (dd + EPSD);
            double w0 = (dot >= 0.0) ? p0 : (p0 - coef*d0);
            double w1 = (dot >= 0.0) ? p1 : (p1 - coef*d1);
            double w2 = (dot >= 0.0) ? p2 : (p2 - coef*d2);
            hL[p][o*3+0] = 0.2*p0 + 0.8*w0;
            hL[p][o*3+1] = 0.2*p1 + 0.8*w1;
            hL[p][o*3+2] = 0.2*p2 + 0.8*w2;
        }
    }
    __syncthreads();
    // block2 into registers (compile-time oi indexing), write h2f as we go
    double h2r[3][3];
    #pragma unroll
    for (int oi = 0; oi < 3; oi++) {
        int o = j + oi*8;
        if (o < NCH) {
            double p0 = 0.0, p1 = 0.0, p2 = 0.0, d0 = 0.0, d1 = 0.0, d2 = 0.0;
            #pragma unroll
            for (int c = 0; c < NCH; c++) {
                double wa = w2fs[o*NCH+c], wb = w2ds[o*NCH+c];
                double x0 = hL[p][c*3+0], x1 = hL[p][c*3+1], x2 = hL[p][c*3+2];
                p0 += wa*x0; p1 += wa*x1; p2 += wa*x2;
                d0 += wb*x0; d1 += wb*x1; d2 += wb*x2;
            }
            double nr = sqrt(p0*p0 + p1*p1 + p2*p2) + EPSD;
            double fac = (nr - s2[o]) * s2[NCH+o] / nr;
            p0 *= fac; p1 *= fac; p2 *= fac;
            double dot = p0*d0 + p1*d1 + p2*d2;
            double dd  = d0*d0 + d1*d1 + d2*d2;
            double coef = dot / (dd + EPSD);
            double w0 = (dot >= 0.0) ? p0 : (p0 - coef*d0);
            double w1 = (dot >= 0.0) ? p1 : (p1 - coef*d1);
            double w2 = (dot >= 0.0) ? p2 : (p2 - coef*d2);
            double h0 = 0.2*p0 + 0.8*w0, h1v = 0.2*p1 + 0.8*w1, h2v = 0.2*p2 + 0.8*w2;
            h2r[oi][0] = h0; h2r[oi][1] = h1v; h2r[oi][2] = h2v;
            h2f[((size_t)(b*63 + o*3+0)*NPT + n)*KNN + k] = (float)h0;
            h2f[((size_t)(b*63 + o*3+1)*NPT + n)*KNN + k] = (float)h1v;
            h2f[((size_t)(b*63 + o*3+2)*NPT + n)*KNN + k] = (float)h2v;
        }
    }
    __syncthreads();        // everyone done reading h1
    #pragma unroll
    for (int oi = 0; oi < 3; oi++) {
        int o = j + oi*8;
        if (o < NCH) {
            hL[p][o*3+0] = h2r[oi][0];
            hL[p][o*3+1] = h2r[oi][1];
            hL[p][o*3+2] = h2r[oi][2];
        }
    }
    __syncthreads();
    // pool dots from hL (= h2)
    #pragma unroll
    for (int oi = 0; oi < 3; oi++) {
        int o = j + oi*8;
        if (o < NCH) {
            double dv0 = 0.0, dv1 = 0.0, dv2 = 0.0;
            #pragma unroll
            for (int c = 0; c < NCH; c++) {
                double w = wps[o*NCH+c];
                dv0 += w*hL[p][c*3+0]; dv1 += w*hL[p][c*3+1]; dv2 += w*hL[p][c*3+2];
            }
            double dt = hL[p][o*3+0]*dv0 + hL[p][o*3+1]*dv1 + hL[p][o*3+2]*dv2;
            dots[(((size_t)b*NCH + o)*NPT + n)*KNN + k] = dt;
        }
    }
}

// ---------------- pool: exact f64 argmax, gather f32 values ----------------
__global__ __launch_bounds__(32) void k_pool_d(const double* __restrict__ dots, const float* __restrict__ h2f,
                                               float* __restrict__ pooled) {
    int b = blockIdx.x >> 11, n = blockIdx.x & (NPT-1);
    int o = threadIdx.x;
    if (o >= NCH) return;
    const double* dp = dots + (((size_t)b*NCH + o)*NPT + n)*KNN;
    double best = dp[0]; int bk = 0;
    #pragma unroll
    for (int k = 1; k < KNN; k++) { double v = dp[k]; if (v > best) { best = v; bk = k; } }
    #pragma unroll
    for (int v = 0; v < 3; v++)
        pooled[((size_t)b*63 + o*3+v)*NPT + n] = h2f[(((size_t)b*63 + o*3+v)*NPT + n)*KNN + bk];
}

// ---------------- conv1 (63->256) + stats ----------------
__global__ __launch_bounds__(256) void k_conv1(const float* __restrict__ pooled, const float* __restrict__ w1,
                                               float* __restrict__ y1, float* __restrict__ sums) {
    int n = blockIdx.x*256 + threadIdx.x;
    int o = blockIdx.y, b = blockIdx.z;
    const float* pb = pooled + (size_t)b*63*NPT + n;
    const float* wo = w1 + o*63;
    float acc = 0.f;
    #pragma unroll
    for (int c = 0; c < 63; c++) acc += wo[c]*pb[(size_t)c*NPT];
    y1[((size_t)b*256 + o)*NPT + n] = acc;
    float a = acc, c2 = acc*acc;
    #pragma unroll
    for (int st = 32; st > 0; st >>= 1) { a += __shfl_down(a, st); c2 += __shfl_down(c2, st); }
    __shared__ float ra[4], rc[4];
    int wv = threadIdx.x >> 6;
    if ((threadIdx.x & 63) == 0) { ra[wv] = a; rc[wv] = c2; }
    __syncthreads();
    if (threadIdx.x == 0) {
        atomicAdd(&sums[o], ra[0]+ra[1]+ra[2]+ra[3]);
        atomicAdd(&sums[256+o], rc[0]+rc[1]+rc[2]+rc[3]);
    }
}

// ---------------- finalize f32 stats ----------------
__global__ void k_finalize(const float* __restrict__ sums, float* __restrict__ stats, float invcnt, int nch) {
    int o = blockIdx.x*blockDim.x + threadIdx.x;
    if (o >= nch) return;
    float mean = sums[o]*invcnt;
    float var = sums[nch+o]*invcnt - mean*mean;
    if (var < 0.f) var = 0.f;
    stats[o] = mean;
    stats[nch+o] = 1.0f / sqrtf(var + BNEPS);
}

// ---------------- bn+lrelu in place ----------------
__global__ __launch_bounds__(256) void k_act(float* __restrict__ y, const float* __restrict__ stats, int nch) {
    int t = blockIdx.x*256 + threadIdx.x;
    int o = (t >> 11) % nch;
    float z = (y[t] - stats[o]) * stats[nch+o];
    y[t] = z >= 0.f ? z : NEGS*z;
}

// ---------------- conv2 (256->128) + stats ----------------
__global__ __launch_bounds__(256) void k_conv2(const float* __restrict__ z1, const float* __restrict__ w2,
                                               float* __restrict__ y2, float* __restrict__ sums) {
    int n = blockIdx.x*256 + threadIdx.x;
    int o = blockIdx.y, b = blockIdx.z;
    const float* pb = z1 + (size_t)b*256*NPT + n;
    const float* wo = w2 + o*256;
    float acc = 0.f;
    #pragma unroll 4
    for (int c = 0; c < 256; c++) acc += wo[c]*pb[(size_t)c*NPT];
    y2[((size_t)b*128 + o)*NPT + n] = acc;
    float a = acc, c2 = acc*acc;
    #pragma unroll
    for (int st = 32; st > 0; st >>= 1) { a += __shfl_down(a, st); c2 += __shfl_down(c2, st); }
    __shared__ float ra[4], rc[4];
    int wv = threadIdx.x >> 6;
    if ((threadIdx.x & 63) == 0) { ra[wv] = a; rc[wv] = c2; }
    __syncthreads();
    if (threadIdx.x == 0) {
        atomicAdd(&sums[o], ra[0]+ra[1]+ra[2]+ra[3]);
        atomicAdd(&sums[128+o], rc[0]+rc[1]+rc[2]+rc[3]);
    }
}

// ---------------- final: act(conv2) -> conv3 + bias ----------------
__global__ __launch_bounds__(256) void k_final(const float* __restrict__ y2, const float* __restrict__ w3,
                                               const float* __restrict__ b3, const float* __restrict__ stats,
                                               float* __restrict__ out) {
    int t = blockIdx.x*256 + threadIdx.x;       // B*N
    int n = t & (NPT-1); int b = t >> 11;
    const float* yb = y2 + (size_t)b*128*NPT + n;
    float acc = b3[0];
    #pragma unroll 4
    for (int c = 0; c < 128; c++) {
        float z = (yb[(size_t)c*NPT] - stats[c]) * stats[128+c];
        z = z >= 0.f ? z : NEGS*z;
        acc += w3[c]*z;
    }
    out[t] = acc;
}

extern "C" void kernel_launch(void* const* d_in, const int* in_sizes, int n_in,
                              void* d_out, int out_size, void* d_ws, size_t ws_size,
                              hipStream_t stream) {
    const float* x   = (const float*)d_in[0];
    const float* w1f = (const float*)d_in[1];
    const float* w1d = (const float*)d_in[2];
    const float* w2f = (const float*)d_in[3];
    const float* w2d = (const float*)d_in[4];
    const float* wp  = (const float*)d_in[5];
    const float* wc1 = (const float*)d_in[6];
    const float* wc2 = (const float*)d_in[7];
    const float* wc3 = (const float*)d_in[8];
    const float* bc3 = (const float*)d_in[9];
    float* out = (float*)d_out;

    float* ws = (float*)d_ws;
    float*  scores4 = ws;                          // 16,777,216 (4 x N x N)
    float*  xxf     = ws + 16777216;               // 8,192
    double* xxd     = (double*)(ws + 16785408);    // 8,192 d
    int*    cand    = (int*)(ws + 16801792);       // 262,144
    int*    idx     = (int*)(ws + 17063936);       // 163,840
    float*  xT      = ws + 17227776;               // 3,145,728
    double* Pfd     = (double*)(ws + 20373504);    // 524,288 d each (point-major [b*N+n][64])
    double* Qfd     = (double*)(ws + 21422080);
    double* Pdd     = (double*)(ws + 22470656);
    double* Qdd     = (double*)(ws + 23519232);
    double* part1   = (double*)(ws + 24567808);    // 640*42 d
    double* part2   = (double*)(ws + 24621568);    // 5120*42 d
    double* st1     = (double*)(ws + 25051648);    // 42 d
    double* st2     = (double*)(ws + 25051776);    // 42 d
    float*  sums_f  = ws + 25051904;               // 1024
    float*  stats_f = ws + 25052928;               // 1024
    double* dots    = (double*)(ws + 25053952);    // 3,440,640 d
    float*  h2f     = ws + 31935232;               // 10,321,920
    float*  pooled  = ws + 42257152;               // 516,096
    float*  y1      = ws + 42773248;               // 2,097,152
    float*  y2      = ws + 44870400;               // 1,048,576 (end 45,918,976 f = 176 MB)

    k_zero<<<4, 256, 0, stream>>>(sums_f, 1024);
    k_xx<<<BB*NPT/256, 256, 0, stream>>>(x, xxf, xxd);
    k_xt<<<dim3(NPT/64, CC/64, BB), 256, 0, stream>>>(x, xT);
    k_gram<<<dim3(136, BB), 256, 0, stream>>>(x, xxf, scores4);
    k_topk<<<dim3(NPT, BB), 256, 0, stream>>>(scores4, cand);
    k_rescore<<<BB*NPT, 256, 0, stream>>>(xT, xxd, cand, idx);
    k_pq_d<<<BB*NPT/4, 256, 0, stream>>>(xT, w1f, w1d, Pfd, Qfd, Pdd, Qdd);
    k_bn1_part<<<TOT/256, 256, 0, stream>>>(Pfd, Qfd, idx, part1);
    k_fin_d<<<NCH, 256, 0, stream>>>(part1, st1, TOT/256, (double)TOT);
    k_b1_bn2part<<<TOT/32, 256, 0, stream>>>(Pfd, Qfd, Pdd, Qdd, idx, st1, w2f, part2);
    k_fin_d<<<NCH, 256, 0, stream>>>(part2, st2, TOT/32, (double)TOT);
    k_apply_d<<<TOT/32, 256, 0, stream>>>(Pfd, Qfd, Pdd, Qdd, idx, st1, st2, w2f, w2d, wp, h2f, dots);
    k_pool_d<<<BB*NPT, 32, 0, stream>>>(dots, h2f, pooled);
    k_conv1<<<dim3(NPT/256, 256, BB), 256, 0, stream>>>(pooled, wc1, y1, sums_f);
    k_finalize<<<1, 256, 0, stream>>>(sums_f, stats_f, 1.f/(float)(BB*NPT), 256);
    k_act<<<BB*256*NPT/256, 256, 0, stream>>>(y1, stats_f, 256);
    k_conv2<<<dim3(NPT/256, 128, BB), 256, 0, stream>>>(y1, wc2, y2, sums_f+512);
    k_finalize<<<1, 128, 0, stream>>>(sums_f+512, stats_f+512, 1.f/(float)(BB*NPT), 128);
    k_final<<<BB*NPT/256, 256, 0, stream>>>(y2, wc3, bc3, stats_f+512, out);
}

// Round 13
// 662.334 us; speedup vs baseline: 1.4484x; 1.0068x over previous
//
#include <hip/hip_runtime.h>
#include <cstddef>

#define BB 4
#define CC 384
#define NPT 2048
#define KNN 20
#define NCAND 32
#define NCH 21
#define NKT (NPT*KNN)
#define TOT (BB*NKT)
#define EPSD 1e-6
#define BNEPSD 1e-5
#define EPSF 1e-6f
#define BNEPS 1e-5f
#define NEGS 0.2f

// ---------------- zero ----------------
__global__ __launch_bounds__(256) void k_zero(float* p, int n) {
    int t = blockIdx.x*256 + threadIdx.x;
    if (t < n) p[t] = 0.f;
}

// ---------------- xx = sum_c x^2 (f64) ----------------
__global__ __launch_bounds__(256) void k_xx(const float* __restrict__ x, float* __restrict__ xx,
                                            double* __restrict__ xxd) {
    int t = blockIdx.x*256 + threadIdx.x;       // B*N
    int n = t & (NPT-1); int b = t >> 11;
    const float* xp = x + (size_t)b*CC*NPT + n;
    double acc = 0.0;
    #pragma unroll 8
    for (int c = 0; c < CC; c++) { double v = (double)xp[(size_t)c*NPT]; acc += v*v; }
    xx[t] = (float)acc;
    xxd[t] = acc;
}

// ---------------- transpose x -> xT (B,N,C) ----------------
__global__ __launch_bounds__(256) void k_xt(const float* __restrict__ x, float* __restrict__ xT) {
    __shared__ float tile[64][65];
    int n0 = blockIdx.x*64, c0 = blockIdx.y*64, b = blockIdx.z;
    int tx = threadIdx.x & 63, ty = threadIdx.x >> 6;
    const float* xb = x + (size_t)b*CC*NPT;
    #pragma unroll
    for (int r = 0; r < 64; r += 4)
        tile[r+ty][tx] = xb[(size_t)(c0+r+ty)*NPT + n0 + tx];
    __syncthreads();
    float* xtb = xT + (size_t)b*NPT*CC;
    #pragma unroll
    for (int r = 0; r < 64; r += 4)
        xtb[(size_t)(n0+r+ty)*CC + c0 + tx] = tile[tx][r+ty];
}

// ---------------- f32 Gram, 128x128 tiles, 8x8/thread (4+4 split, bank-conflict-free) ----------------
__global__ __launch_bounds__(256) void k_gram(const float* __restrict__ x, const float* __restrict__ xx,
                                              float* __restrict__ scores4) {
    __shared__ float As[16][128];
    __shared__ float Bs[16][128];
    int tid = blockIdx.x;               // 0..135 triangular tile
    int b = blockIdx.y;
    int by = 0, rem = tid;
    while (rem >= 16 - by) { rem -= 16 - by; by++; }
    int bx = by + rem;
    int n0 = by*128, m0 = bx*128;
    int t = threadIdx.x;
    int tx = t & 15, ty = t >> 4;
    const float* xb = x + (size_t)b*CC*NPT;
    float* scores = scores4 + (size_t)b*NPT*NPT;
    float acc[8][8] = {};
    for (int c0 = 0; c0 < CC; c0 += 16) {
        #pragma unroll
        for (int i = 0; i < 8; i++) {
            int e = t + i*256;
            int cc = e >> 7, col = e & 127;
            As[cc][col] = xb[(size_t)(c0+cc)*NPT + n0 + col];
            Bs[cc][col] = xb[(size_t)(c0+cc)*NPT + m0 + col];
        }
        __syncthreads();
        #pragma unroll
        for (int kk = 0; kk < 16; kk++) {
            float4 a0 = *(const float4*)&As[kk][ty*4];
            float4 a1 = *(const float4*)&As[kk][64 + ty*4];
            float4 b0 = *(const float4*)&Bs[kk][tx*4];
            float4 b1 = *(const float4*)&Bs[kk][64 + tx*4];
            float av[8] = {a0.x,a0.y,a0.z,a0.w,a1.x,a1.y,a1.z,a1.w};
            float bv[8] = {b0.x,b0.y,b0.z,b0.w,b1.x,b1.y,b1.z,b1.w};
            #pragma unroll
            for (int i = 0; i < 8; i++)
                #pragma unroll
                for (int j = 0; j < 8; j++)
                    acc[i][j] += av[i]*bv[j];
        }
        __syncthreads();
    }
    int nb0 = n0 + ty*4, nb1 = n0 + 64 + ty*4;
    int mb0 = m0 + tx*4, mb1 = m0 + 64 + tx*4;
    float xn[8], xm[8];
    #pragma unroll
    for (int i = 0; i < 4; i++) {
        xn[i]   = xx[b*NPT + nb0 + i];
        xn[4+i] = xx[b*NPT + nb1 + i];
        xm[i]   = xx[b*NPT + mb0 + i];
        xm[4+i] = xx[b*NPT + mb1 + i];
    }
    float val[8][8];
    #pragma unroll
    for (int i = 0; i < 8; i++) {
        int row = (i < 4) ? (nb0 + i) : (nb1 + i - 4);
        #pragma unroll
        for (int j = 0; j < 8; j++) {
            int col = (j < 4) ? (mb0 + j) : (mb1 + j - 4);
            val[i][j] = 2.f*acc[i][j] - xn[i] - xm[j];
            scores[(size_t)row*NPT + col] = val[i][j];
        }
    }
    if (bx != by) {
        #pragma unroll
        for (int j = 0; j < 8; j++) {
            int col = (j < 4) ? (mb0 + j) : (mb1 + j - 4);
            #pragma unroll
            for (int i = 0; i < 8; i++) {
                int row = (i < 4) ? (nb0 + i) : (nb1 + i - 4);
                scores[(size_t)col*NPT + row] = val[i][j];
            }
        }
    }
}

// ---------------- top-NCAND per row: radix select (set-identical to f32 top-32) ----------------
__global__ __launch_bounds__(256) void k_topk(const float* __restrict__ scores4, int* __restrict__ candout) {
    int n = blockIdx.x, b = blockIdx.y;
    const float* row = scores4 + ((size_t)b*NPT + n)*NPT;
    unsigned key[8];
    #pragma unroll
    for (int w = 0; w < 8; w++) {
        unsigned u = __float_as_uint(row[threadIdx.x + w*256]);
        key[w] = (u & 0x80000000u) ? ~u : (u | 0x80000000u);   // monotone float->uint
    }
    __shared__ int hist[4][257];
    __shared__ int histsum[256];
    __shared__ unsigned s_pfx;
    __shared__ int s_need, s_slot, s_tie;
    __shared__ unsigned long long tiel[256];
    int wv = threadIdx.x >> 6;
    if (threadIdx.x == 0) { s_pfx = 0u; s_need = NCAND; s_slot = 0; s_tie = 0; }
    #pragma unroll
    for (int pass = 0; pass < 3; pass++) {
        int sh = (pass == 0) ? 24 : (pass == 1 ? 16 : 8);
        unsigned maskhi = (pass == 0) ? 0u : (pass == 1 ? 0xFF000000u : 0xFFFF0000u);
        hist[0][threadIdx.x] = 0; hist[1][threadIdx.x] = 0;
        hist[2][threadIdx.x] = 0; hist[3][threadIdx.x] = 0;
        __syncthreads();
        unsigned pfx = s_pfx;
        #pragma unroll
        for (int w = 0; w < 8; w++) {
            unsigned v = key[w];
            if ((v & maskhi) == (pfx & maskhi))
                atomicAdd(&hist[wv][(v >> sh) & 0xFF], 1);
        }
        __syncthreads();
        histsum[threadIdx.x] = hist[0][threadIdx.x] + hist[1][threadIdx.x]
                             + hist[2][threadIdx.x] + hist[3][threadIdx.x];
        __syncthreads();
        if (threadIdx.x < 64) {
            int l = threadIdx.x, base = l*4;
            int c0 = histsum[base], c1 = histsum[base+1], c2 = histsum[base+2], c3 = histsum[base+3];
            int mysum = c0 + c1 + c2 + c3;
            int suf = mysum;
            #pragma unroll
            for (int st = 1; st < 64; st <<= 1) {
                int u2 = __shfl_down(suf, st);
                if (l + st >= 64) u2 = 0;
                suf += u2;
            }
            int need = s_need;
            int sufNext = suf - mysum;
            if (suf >= need && sufNext < need) {        // exactly one lane
                int s3 = sufNext + c3, s2p = s3 + c2, s1p = s2p + c1;
                int B, Sb1;
                if (s3 >= need)       { B = base+3; Sb1 = sufNext; }
                else if (s2p >= need) { B = base+2; Sb1 = s3; }
                else if (s1p >= need) { B = base+1; Sb1 = s2p; }
                else                  { B = base;   Sb1 = s1p; }
                s_pfx = s_pfx | ((unsigned)B << sh);
                s_need = need - Sb1;
            }
        }
        __syncthreads();
    }
    unsigned pfx24 = s_pfx & 0xFFFFFF00u;
    int* outp = candout + ((size_t)b*NPT + n)*NCAND;
    #pragma unroll
    for (int w = 0; w < 8; w++) {
        unsigned v = key[w];
        unsigned hi = v & 0xFFFFFF00u;
        int i = threadIdx.x + w*256;
        if (hi > pfx24) {
            int s = atomicAdd(&s_slot, 1);
            outp[s] = i;
        } else if (hi == pfx24) {
            int ti = atomicAdd(&s_tie, 1);
            if (ti < 256) tiel[ti] = ((unsigned long long)v << 32) | (unsigned)(NPT-1-i);
        }
    }
    __syncthreads();
    if (threadIdx.x == 0) {
        int A = s_slot, r = s_need, T = s_tie < 256 ? s_tie : 256;
        for (int kk = 0; kk < r; kk++) {
            unsigned long long best = 0ull; int bj = 0;
            for (int j2 = 0; j2 < T; j2++) if (tiel[j2] > best) { best = tiel[j2]; bj = j2; }
            tiel[bj] = 0ull;
            outp[A + kk] = NPT-1-(int)(best & 0xFFFFFFFFu);
        }
    }
}

// ---------------- exact f64 rescore -> final top-20 (wave-parallel selection) ----------------
__global__ __launch_bounds__(256) void k_rescore(const float* __restrict__ xT, const double* __restrict__ xxd,
                                                 const int* __restrict__ cand, int* __restrict__ idxout) {
    __shared__ float xn[CC];
    __shared__ double sc[NCAND];
    __shared__ int ci[NCAND];
    int t = blockIdx.x;             // b*N + n
    int b = t >> 11;
    const float* xrow = xT + (size_t)t*CC;
    for (int i = threadIdx.x; i < CC; i += 256) xn[i] = xrow[i];
    if (threadIdx.x < NCAND) ci[threadIdx.x] = cand[(size_t)t*NCAND + threadIdx.x];
    __syncthreads();
    int j = threadIdx.x >> 3, l = threadIdx.x & 7;
    int m = ci[j];
    const float* xm = xT + ((size_t)b*NPT + m)*CC;
    double acc = 0.0;
    int cbase = l*48;
    #pragma unroll 8
    for (int c = 0; c < 48; c++) acc += (double)xn[cbase+c] * (double)xm[cbase+c];
    acc += __shfl_down(acc, 4, 8);
    acc += __shfl_down(acc, 2, 8);
    acc += __shfl_down(acc, 1, 8);
    if (l == 0) sc[j] = 2.0*acc - xxd[t] - xxd[(size_t)b*NPT + m];
    __syncthreads();
    if (threadIdx.x < 64) {
        double v = (threadIdx.x < NCAND) ? sc[threadIdx.x] : -1e300;
        int oi = (threadIdx.x < NCAND) ? ci[threadIdx.x] : NPT;
        for (int kk = 0; kk < KNN; kk++) {
            double bv = v; int bo = oi;
            #pragma unroll
            for (int st = 16; st > 0; st >>= 1) {
                double ov = __shfl_xor(bv, st, 32);
                int    oo = __shfl_xor(bo, st, 32);
                if (ov > bv || (ov == bv && oo < bo)) { bv = ov; bo = oo; }
            }
            if (threadIdx.x == 0) idxout[(size_t)t*KNN + kk] = bo;
            if (oi == bo) v = -1e300;   // unique owner eliminates winner
        }
    }
}

// ---------------- P/Q precompute (f64), point-major out, LDS x + LDS transposed weights ----------------
__global__ __launch_bounds__(256) void k_pq_d(const float* __restrict__ xT,
                                              const float* __restrict__ wf, const float* __restrict__ wd,
                                              double* __restrict__ Pf, double* __restrict__ Qf,
                                              double* __restrict__ Pd, double* __restrict__ Qd) {
    __shared__ float xs[4][CC];             // 6144 B
    __shared__ float wfa[128*NCH];          // wf[o*256+c3]      -> [c3*21+o]
    __shared__ float wfb[128*NCH];          // wf[o*256+128+c3]  -> [c3*21+o]
    __shared__ float wda[128*NCH];
    __shared__ float wdb[128*NCH];
    int pt = threadIdx.x >> 6;                  // 0..3 local point
    int ov = threadIdx.x & 63;
    int row0 = blockIdx.x*4;                    // b*N+n base
    for (int i = threadIdx.x; i < 4*CC; i += 256)
        xs[i/CC][i%CC] = xT[(size_t)(row0 + i/CC)*CC + (i%CC)];
    for (int i = threadIdx.x; i < 128*NCH; i += 256) {
        int o2 = i >> 7, c3 = i & 127;          // o2=0..20, c3 coalesced
        wfa[c3*NCH+o2] = wf[o2*256 + c3];
        wfb[c3*NCH+o2] = wf[o2*256 + 128 + c3];
        wda[c3*NCH+o2] = wd[o2*256 + c3];
        wdb[c3*NCH+o2] = wd[o2*256 + 128 + c3];
    }
    __syncthreads();
    if (ov >= 63) return;
    int o = ov / 3, v = ov % 3;
    const float* xp = &xs[pt][v];
    double pf = 0.0, qf = 0.0, pd = 0.0, qd = 0.0;
    #pragma unroll 4
    for (int c3 = 0; c3 < 128; c3++) {
        double xv = (double)xp[c3*3];
        double waf = (double)wfa[c3*NCH+o], wbf = (double)wfb[c3*NCH+o];
        double wad = (double)wda[c3*NCH+o], wbd = (double)wdb[c3*NCH+o];
        pf += waf*xv; qf += (wbf-waf)*xv;
        pd += wad*xv; qd += (wbd-wad)*xv;
    }
    size_t off = (size_t)(row0 + pt)*64 + ov;
    Pf[off] = pf; Qf[off] = qf; Pd[off] = pd; Qd[off] = qd;
}

// ---------------- BN1 partial sums (f64, deterministic) ----------------
__global__ __launch_bounds__(256) void k_bn1_part(const double* __restrict__ Pf, const double* __restrict__ Qf,
                                                  const int* __restrict__ idx, double* __restrict__ part) {
    __shared__ double red[4][42];
    int t = blockIdx.x*256 + threadIdx.x;       // (b*N+n)*K+k
    int bn = t / KNN;
    int n = bn & (NPT-1); int b = bn >> 11;
    int m = idx[t];
    const double* PF = Pf + ((size_t)b*NPT + m)*64;
    const double* QF = Qf + ((size_t)b*NPT + n)*64;
    int wave = threadIdx.x >> 6;
    #pragma unroll
    for (int o = 0; o < NCH; o++) {
        double p0 = PF[o*3+0] + QF[o*3+0];
        double p1 = PF[o*3+1] + QF[o*3+1];
        double p2 = PF[o*3+2] + QF[o*3+2];
        double nr = sqrt(p0*p0 + p1*p1 + p2*p2) + EPSD;
        double a = nr, c2 = nr*nr;
        #pragma unroll
        for (int st = 32; st > 0; st >>= 1) { a += __shfl_down(a, st); c2 += __shfl_down(c2, st); }
        if ((threadIdx.x & 63) == 0) { red[wave][o] = a; red[wave][NCH+o] = c2; }
    }
    __syncthreads();
    if (threadIdx.x < 42)
        part[(size_t)blockIdx.x*42 + threadIdx.x] =
            red[0][threadIdx.x] + red[1][threadIdx.x] + red[2][threadIdx.x] + red[3][threadIdx.x];
}

// ---------------- finalize f64 stats (parallel: 21 blocks x 256 thr) ----------------
__global__ __launch_bounds__(256) void k_fin_d(const double* __restrict__ part, double* __restrict__ st,
                                               int nblk, double cnt) {
    __shared__ double r0[4], r1[4];
    int o = blockIdx.x;             // 0..NCH-1
    double s0 = 0.0, s1 = 0.0;
    for (int i = threadIdx.x; i < nblk; i += 256) {
        s0 += part[(size_t)i*42 + o];
        s1 += part[(size_t)i*42 + NCH + o];
    }
    #pragma unroll
    for (int stp = 32; stp > 0; stp >>= 1) { s0 += __shfl_down(s0, stp); s1 += __shfl_down(s1, stp); }
    int wv = threadIdx.x >> 6;
    if ((threadIdx.x & 63) == 0) { r0[wv] = s0; r1[wv] = s1; }
    __syncthreads();
    if (threadIdx.x == 0) {
        double sum = r0[0]+r0[1]+r0[2]+r0[3];
        double ssq = r1[0]+r1[1]+r1[2]+r1[3];
        double mean = sum / cnt;
        double var = ssq / cnt - mean*mean;
        if (var < 0.0) var = 0.0;
        st[o] = mean;
        st[NCH+o] = 1.0 / sqrt(var + BNEPSD);
    }
}

// ---------------- block1 (f64) -> BN2 partials; 8 threads/pair, 32 pairs/block ----------------
__global__ __launch_bounds__(256) void k_b1_bn2part(const double* __restrict__ Pf, const double* __restrict__ Qf,
                                                    const double* __restrict__ Pd, const double* __restrict__ Qd,
                                                    const int* __restrict__ idx, const double* __restrict__ st1,
                                                    const float* __restrict__ w2f_g, double* __restrict__ part) {
    __shared__ double h1L[32][65];
    __shared__ double w2s[NCH*NCH];
    __shared__ double s1[42];
    __shared__ double wred[4][42];
    int tid = threadIdx.x;
    int p = tid >> 3, j = tid & 7;
    int t = blockIdx.x*32 + p;
    for (int i = tid; i < NCH*NCH; i += 256) w2s[i] = (double)w2f_g[i];
    if (tid < 42) s1[tid] = st1[tid];
    int bn = t / KNN;
    int n = bn & (NPT-1), b = bn >> 11;
    int m = idx[t];
    const double* PF = Pf + ((size_t)b*NPT + m)*64;
    const double* QF = Qf + ((size_t)b*NPT + n)*64;
    const double* PD = Pd + ((size_t)b*NPT + m)*64;
    const double* QD = Qd + ((size_t)b*NPT + n)*64;
    __syncthreads();
    for (int o = j; o < NCH; o += 8) {
        double p0 = PF[o*3+0] + QF[o*3+0];
        double p1 = PF[o*3+1] + QF[o*3+1];
        double p2 = PF[o*3+2] + QF[o*3+2];
        double d0 = PD[o*3+0] + QD[o*3+0];
        double d1 = PD[o*3+1] + QD[o*3+1];
        double d2 = PD[o*3+2] + QD[o*3+2];
        double nr = sqrt(p0*p0 + p1*p1 + p2*p2) + EPSD;
        double fac = (nr - s1[o]) * s1[NCH+o] / nr;
        p0 *= fac; p1 *= fac; p2 *= fac;
        double dot = p0*d0 + p1*d1 + p2*d2;
        double dd  = d0*d0 + d1*d1 + d2*d2;
        double coef = dot / (dd + EPSD);
        double w0 = (dot >= 0.0) ? p0 : (p0 - coef*d0);
        double w1 = (dot >= 0.0) ? p1 : (p1 - coef*d1);
        double w2 = (dot >= 0.0) ? p2 : (p2 - coef*d2);
        h1L[p][o*3+0] = 0.2*p0 + 0.8*w0;
        h1L[p][o*3+1] = 0.2*p1 + 0.8*w1;
        h1L[p][o*3+2] = 0.2*p2 + 0.8*w2;
    }
    __syncthreads();
    double s[3] = {0.0,0.0,0.0}, q[3] = {0.0,0.0,0.0};
    {
        int oi = 0;
        for (int o = j; o < NCH; o += 8, oi++) {
            double a0 = 0.0, a1 = 0.0, a2 = 0.0;
            #pragma unroll
            for (int c = 0; c < NCH; c++) {
                double w = w2s[o*NCH+c];
                a0 += w*h1L[p][c*3+0]; a1 += w*h1L[p][c*3+1]; a2 += w*h1L[p][c*3+2];
            }
            double nr = sqrt(a0*a0 + a1*a1 + a2*a2) + EPSD;
            s[oi] = nr; q[oi] = nr*nr;
        }
    }
    #pragma unroll
    for (int st = 8; st < 64; st <<= 1) {
        #pragma unroll
        for (int u = 0; u < 3; u++) { s[u] += __shfl_down(s[u], st); q[u] += __shfl_down(q[u], st); }
    }
    if ((tid & 63) < 8) {           // lanes 0..7 hold per-wave sums for their j
        int wv = tid >> 6, oi = 0;
        for (int o = j; o < NCH; o += 8, oi++) { wred[wv][o] = s[oi]; wred[wv][NCH+o] = q[oi]; }
    }
    __syncthreads();
    if (tid < 42)
        part[(size_t)blockIdx.x*42 + tid] = wred[0][tid]+wred[1][tid]+wred[2][tid]+wred[3][tid];
}

// ---------------- block1+block2 (f64) -> h2 f32 + pool dots f64; 8 thr/pair, single LDS tile ----------------
__global__ __launch_bounds__(256) void k_apply_d(const double* __restrict__ Pf, const double* __restrict__ Qf,
                                                 const double* __restrict__ Pd, const double* __restrict__ Qd,
                                                 const int* __restrict__ idx,
                                                 const double* __restrict__ st1, const double* __restrict__ st2,
                                                 const float* __restrict__ w2f_g, const float* __restrict__ w2d_g,
                                                 const float* __restrict__ wp_g,
                                                 float* __restrict__ h2f, double* __restrict__ dots) {
    __shared__ double hL[32][65];           // h1, then reused for h2
    __shared__ double w2fs[NCH*NCH];
    __shared__ double w2ds[NCH*NCH];
    __shared__ double wps[NCH*NCH];
    __shared__ double s1[42], s2[42];
    int tid = threadIdx.x;
    int p = tid >> 3, j = tid & 7;
    int t = blockIdx.x*32 + p;
    for (int i = tid; i < NCH*NCH; i += 256) {
        w2fs[i] = (double)w2f_g[i]; w2ds[i] = (double)w2d_g[i]; wps[i] = (double)wp_g[i];
    }
    if (tid < 42) { s1[tid] = st1[tid]; s2[tid] = st2[tid]; }
    int k = t % KNN; int bn = t / KNN;
    int n = bn & (NPT-1), b = bn >> 11;
    int m = idx[t];
    const double* PF = Pf + ((size_t)b*NPT + m)*64;
    const double* QF = Qf + ((size_t)b*NPT + n)*64;
    const double* PD = Pd + ((size_t)b*NPT + m)*64;
    const double* QD = Qd + ((size_t)b*NPT + n)*64;
    __syncthreads();
    // block1 -> hL (h1)
    #pragma unroll
    for (int oi = 0; oi < 3; oi++) {
        int o = j + oi*8;
        if (o < NCH) {
            double p0 = PF[o*3+0] + QF[o*3+0];
            double p1 = PF[o*3+1] + QF[o*3+1];
            double p2 = PF[o*3+2] + QF[o*3+2];
            double d0 = PD[o*3+0] + QD[o*3+0];
            double d1 = PD[o*3+1] + QD[o*3+1];
            double d2 = PD[o*3+2] + QD[o*3+2];
            double nr = sqrt(p0*p0 + p1*p1 + p2*p2) + EPSD;
            double fac = (nr - s1[o]) * s1[NCH+o] / nr;
            p0 *= fac; p1 *= fac; p2 *= fac;
            double dot = p0*d0 + p1*d1 + p2*d2;
            double dd  = d0*d0 + d1*d1 + d2*d2;
            double coef = dot / (dd + EPSD);
            double w0 = (dot >= 0.0) ? p0 : (p0 - coef*d0);
            double w1 = (dot >= 0.0) ? p1 : (p1 - coef*d1);
            double w2 = (dot >= 0.0) ? p2 : (p2 - coef*d2);
            hL[p][o*3+0] = 0.2*p0 + 0.8*w0;
            hL[p][o*3+1] = 0.2*p1 + 0.8*w1;
            hL[p][o*3+2] = 0.2*p2 + 0.8*w2;
        }
    }
    __syncthreads();
    // block2 into registers (compile-time oi indexing), write h2f as we go
    double h2r[3][3];
    #pragma unroll
    for (int oi = 0; oi < 3; oi++) {
        int o = j + oi*8;
        if (o < NCH) {
            double p0 = 0.0, p1 = 0.0, p2 = 0.0, d0 = 0.0, d1 = 0.0, d2 = 0.0;
            #pragma unroll
            for (int c = 0; c < NCH; c++) {
                double wa = w2fs[o*NCH+c], wb = w2ds[o*NCH+c];
                double x0 = hL[p][c*3+0], x1 = hL[p][c*3+1], x2 = hL[p][c*3+2];
                p0 += wa*x0; p1 += wa*x1; p2 += wa*x2;
                d0 += wb*x0; d1 += wb*x1; d2 += wb*x2;
            }
            double nr = sqrt(p0*p0 + p1*p1 + p2*p2) + EPSD;
            double fac = (nr - s2[o]) * s2[NCH+o] / nr;
            p0 *= fac; p1 *= fac; p2 *= fac;
            double dot = p0*d0 + p1*d1 + p2*d2;
            double dd  = d0*d0 + d1*d1 + d2*d2;
            double coef = dot / (dd + EPSD);
            double w0 = (dot >= 0.0) ? p0 : (p0 - coef*d0);
            double w1 = (dot >= 0.0) ? p1 : (p1 - coef*d1);
            double w2 = (dot >= 0.0) ? p2 : (p2 - coef*d2);
            double h0 = 0.2*p0 + 0.8*w0, h1v = 0.2*p1 + 0.8*w1, h2v = 0.2*p2 + 0.8*w2;
            h2r[oi][0] = h0; h2r[oi][1] = h1v; h2r[oi][2] = h2v;
            h2f[((size_t)(b*63 + o*3+0)*NPT + n)*KNN + k] = (float)h0;
            h2f[((size_t)(b*63 + o*3+1)*NPT + n)*KNN + k] = (float)h1v;
            h2f[((size_t)(b*63 + o*3+2)*NPT + n)*KNN + k] = (float)h2v;
        }
    }
    __syncthreads();        // everyone done reading h1
    #pragma unroll
    for (int oi = 0; oi < 3; oi++) {
        int o = j + oi*8;
        if (o < NCH) {
            hL[p][o*3+0] = h2r[oi][0];
            hL[p][o*3+1] = h2r[oi][1];
            hL[p][o*3+2] = h2r[oi][2];
        }
    }
    __syncthreads();
    // pool dots from hL (= h2)
    #pragma unroll
    for (int oi = 0; oi < 3; oi++) {
        int o = j + oi*8;
        if (o < NCH) {
            double dv0 = 0.0, dv1 = 0.0, dv2 = 0.0;
            #pragma unroll
            for (int c = 0; c < NCH; c++) {
                double w = wps[o*NCH+c];
                dv0 += w*hL[p][c*3+0]; dv1 += w*hL[p][c*3+1]; dv2 += w*hL[p][c*3+2];
            }
            double dt = hL[p][o*3+0]*dv0 + hL[p][o*3+1]*dv1 + hL[p][o*3+2]*dv2;
            dots[(((size_t)b*NCH + o)*NPT + n)*KNN + k] = dt;
        }
    }
}

// ---------------- pool: exact f64 argmax, gather f32 values ----------------
__global__ __launch_bounds__(32) void k_pool_d(const double* __restrict__ dots, const float* __restrict__ h2f,
                                               float* __restrict__ pooled) {
    int b = blockIdx.x >> 11, n = blockIdx.x & (NPT-1);
    int o = threadIdx.x;
    if (o >= NCH) return;
    const double* dp = dots + (((size_t)b*NCH + o)*NPT + n)*KNN;
    double best = dp[0]; int bk = 0;
    #pragma unroll
    for (int k = 1; k < KNN; k++) { double v = dp[k]; if (v > best) { best = v; bk = k; } }
    #pragma unroll
    for (int v = 0; v < 3; v++)
        pooled[((size_t)b*63 + o*3+v)*NPT + n] = h2f[(((size_t)b*63 + o*3+v)*NPT + n)*KNN + bk];
}

// ---------------- conv1 (63->256) + stats ----------------
__global__ __launch_bounds__(256) void k_conv1(const float* __restrict__ pooled, const float* __restrict__ w1,
                                               float* __restrict__ y1, float* __restrict__ sums) {
    int n = blockIdx.x*256 + threadIdx.x;
    int o = blockIdx.y, b = blockIdx.z;
    const float* pb = pooled + (size_t)b*63*NPT + n;
    const float* wo = w1 + o*63;
    float acc = 0.f;
    #pragma unroll
    for (int c = 0; c < 63; c++) acc += wo[c]*pb[(size_t)c*NPT];
    y1[((size_t)b*256 + o)*NPT + n] = acc;
    float a = acc, c2 = acc*acc;
    #pragma unroll
    for (int st = 32; st > 0; st >>= 1) { a += __shfl_down(a, st); c2 += __shfl_down(c2, st); }
    __shared__ float ra[4], rc[4];
    int wv = threadIdx.x >> 6;
    if ((threadIdx.x & 63) == 0) { ra[wv] = a; rc[wv] = c2; }
    __syncthreads();
    if (threadIdx.x == 0) {
        atomicAdd(&sums[o], ra[0]+ra[1]+ra[2]+ra[3]);
        atomicAdd(&sums[256+o], rc[0]+rc[1]+rc[2]+rc[3]);
    }
}

// ---------------- finalize f32 stats ----------------
__global__ void k_finalize(const float* __restrict__ sums, float* __restrict__ stats, float invcnt, int nch) {
    int o = blockIdx.x*blockDim.x + threadIdx.x;
    if (o >= nch) return;
    float mean = sums[o]*invcnt;
    float var = sums[nch+o]*invcnt - mean*mean;
    if (var < 0.f) var = 0.f;
    stats[o] = mean;
    stats[nch+o] = 1.0f / sqrtf(var + BNEPS);
}

// ---------------- bn+lrelu in place ----------------
__global__ __launch_bounds__(256) void k_act(float* __restrict__ y, const float* __restrict__ stats, int nch) {
    int t = blockIdx.x*256 + threadIdx.x;
    int o = (t >> 11) % nch;
    float z = (y[t] - stats[o]) * stats[nch+o];
    y[t] = z >= 0.f ? z : NEGS*z;
}

// ---------------- conv2 (256->128) + stats ----------------
__global__ __launch_bounds__(256) void k_conv2(const float* __restrict__ z1, const float* __restrict__ w2,
                                               float* __restrict__ y2, float* __restrict__ sums) {
    int n = blockIdx.x*256 + threadIdx.x;
    int o = blockIdx.y, b = blockIdx.z;
    const float* pb = z1 + (size_t)b*256*NPT + n;
    const float* wo = w2 + o*256;
    float acc = 0.f;
    #pragma unroll 4
    for (int c = 0; c < 256; c++) acc += wo[c]*pb[(size_t)c*NPT];
    y2[((size_t)b*128 + o)*NPT + n] = acc;
    float a = acc, c2 = acc*acc;
    #pragma unroll
    for (int st = 32; st > 0; st >>= 1) { a += __shfl_down(a, st); c2 += __shfl_down(c2, st); }
    __shared__ float ra[4], rc[4];
    int wv = threadIdx.x >> 6;
    if ((threadIdx.x & 63) == 0) { ra[wv] = a; rc[wv] = c2; }
    __syncthreads();
    if (threadIdx.x == 0) {
        atomicAdd(&sums[o], ra[0]+ra[1]+ra[2]+ra[3]);
        atomicAdd(&sums[128+o], rc[0]+rc[1]+rc[2]+rc[3]);
    }
}

// ---------------- final: act(conv2) -> conv3 + bias ----------------
__global__ __launch_bounds__(256) void k_final(const float* __restrict__ y2, const float* __restrict__ w3,
                                               const float* __restrict__ b3, const float* __restrict__ stats,
                                               float* __restrict__ out) {
    int t = blockIdx.x*256 + threadIdx.x;       // B*N
    int n = t & (NPT-1); int b = t >> 11;
    const float* yb = y2 + (size_t)b*128*NPT + n;
    float acc = b3[0];
    #pragma unroll 4
    for (int c = 0; c < 128; c++) {
        float z = (yb[(size_t)c*NPT] - stats[c]) * stats[128+c];
        z = z >= 0.f ? z : NEGS*z;
        acc += w3[c]*z;
    }
    out[t] = acc;
}

extern "C" void kernel_launch(void* const* d_in, const int* in_sizes, int n_in,
                              void* d_out, int out_size, void* d_ws, size_t ws_size,
                              hipStream_t stream) {
    const float* x   = (const float*)d_in[0];
    const float* w1f = (const float*)d_in[1];
    const float* w1d = (const float*)d_in[2];
    const float* w2f = (const float*)d_in[3];
    const float* w2d = (const float*)d_in[4];
    const float* wp  = (const float*)d_in[5];
    const float* wc1 = (const float*)d_in[6];
    const float* wc2 = (const float*)d_in[7];
    const float* wc3 = (const float*)d_in[8];
    const float* bc3 = (const float*)d_in[9];
    float* out = (float*)d_out;

    float* ws = (float*)d_ws;
    float*  scores4 = ws;                          // 16,777,216 (4 x N x N)
    float*  xxf     = ws + 16777216;               // 8,192
    double* xxd     = (double*)(ws + 16785408);    // 8,192 d
    int*    cand    = (int*)(ws + 16801792);       // 262,144
    int*    idx     = (int*)(ws + 17063936);       // 163,840
    float*  xT      = ws + 17227776;               // 3,145,728
    double* Pfd     = (double*)(ws + 20373504);    // 524,288 d each (point-major [b*N+n][64])
    double* Qfd     = (double*)(ws + 21422080);
    double* Pdd     = (double*)(ws + 22470656);
    double* Qdd     = (double*)(ws + 23519232);
    double* part1   = (double*)(ws + 24567808);    // 640*42 d
    double* part2   = (double*)(ws + 24621568);    // 5120*42 d
    double* st1     = (double*)(ws + 25051648);    // 42 d
    double* st2     = (double*)(ws + 25051776);    // 42 d
    float*  sums_f  = ws + 25051904;               // 1024
    float*  stats_f = ws + 25052928;               // 1024
    double* dots    = (double*)(ws + 25053952);    // 3,440,640 d
    float*  h2f     = ws + 31935232;               // 10,321,920
    float*  pooled  = ws + 42257152;               // 516,096
    float*  y1      = ws + 42773248;               // 2,097,152
    float*  y2      = ws + 44870400;               // 1,048,576 (end 45,918,976 f = 176 MB)

    k_zero<<<4, 256, 0, stream>>>(sums_f, 1024);
    k_xx<<<BB*NPT/256, 256, 0, stream>>>(x, xxf, xxd);
    k_xt<<<dim3(NPT/64, CC/64, BB), 256, 0, stream>>>(x, xT);
    k_gram<<<dim3(136, BB), 256, 0, stream>>>(x, xxf, scores4);
    k_topk<<<dim3(NPT, BB), 256, 0, stream>>>(scores4, cand);
    k_rescore<<<BB*NPT, 256, 0, stream>>>(xT, xxd, cand, idx);
    k_pq_d<<<BB*NPT/4, 256, 0, stream>>>(xT, w1f, w1d, Pfd, Qfd, Pdd, Qdd);
    k_bn1_part<<<TOT/256, 256, 0, stream>>>(Pfd, Qfd, idx, part1);
    k_fin_d<<<NCH, 256, 0, stream>>>(part1, st1, TOT/256, (double)TOT);
    k_b1_bn2part<<<TOT/32, 256, 0, stream>>>(Pfd, Qfd, Pdd, Qdd, idx, st1, w2f, part2);
    k_fin_d<<<NCH, 256, 0, stream>>>(part2, st2, TOT/32, (double)TOT);
    k_apply_d<<<TOT/32, 256, 0, stream>>>(Pfd, Qfd, Pdd, Qdd, idx, st1, st2, w2f, w2d, wp, h2f, dots);
    k_pool_d<<<BB*NPT, 32, 0, stream>>>(dots, h2f, pooled);
    k_conv1<<<dim3(NPT/256, 256, BB), 256, 0, stream>>>(pooled, wc1, y1, sums_f);
    k_finalize<<<1, 256, 0, stream>>>(sums_f, stats_f, 1.f/(float)(BB*NPT), 256);
    k_act<<<BB*256*NPT/256, 256, 0, stream>>>(y1, stats_f, 256);
    k_conv2<<<dim3(NPT/256, 128, BB), 256, 0, stream>>>(y1, wc2, y2, sums_f+512);
    k_finalize<<<1, 128, 0, stream>>>(sums_f+512, stats_f+512, 1.f/(float)(BB*NPT), 128);
    k_final<<<BB*NPT/256, 256, 0, stream>>>(y2, wc3, bc3, stats_f+512, out);
}

// Round 14
// 629.404 us; speedup vs baseline: 1.5242x; 1.0523x over previous
//
#include <hip/hip_runtime.h>
#include <cstddef>

#define BB 4
#define CC 384
#define NPT 2048
#define KNN 20
#define NCAND 32
#define NCH 21
#define NKT (NPT*KNN)
#define TOT (BB*NKT)
#define EPSD 1e-6
#define BNEPSD 1e-5
#define EPSF 1e-6f
#define BNEPS 1e-5f
#define NEGS 0.2f

// ---------------- zero ----------------
__global__ __launch_bounds__(256) void k_zero(float* p, int n) {
    int t = blockIdx.x*256 + threadIdx.x;
    if (t < n) p[t] = 0.f;
}

// ---------------- transpose x -> xT (B,N,C) ----------------
__global__ __launch_bounds__(256) void k_xt(const float* __restrict__ x, float* __restrict__ xT) {
    __shared__ float tile[64][65];
    int n0 = blockIdx.x*64, c0 = blockIdx.y*64, b = blockIdx.z;
    int tx = threadIdx.x & 63, ty = threadIdx.x >> 6;
    const float* xb = x + (size_t)b*CC*NPT;
    #pragma unroll
    for (int r = 0; r < 64; r += 4)
        tile[r+ty][tx] = xb[(size_t)(c0+r+ty)*NPT + n0 + tx];
    __syncthreads();
    float* xtb = xT + (size_t)b*NPT*CC;
    #pragma unroll
    for (int r = 0; r < 64; r += 4)
        xtb[(size_t)(n0+r+ty)*CC + c0 + tx] = tile[tx][r+ty];
}

// ---------------- xx = sum_c x^2 (f64), wave-per-point from xT ----------------
__global__ __launch_bounds__(256) void k_xx(const float* __restrict__ xT, float* __restrict__ xx,
                                            double* __restrict__ xxd) {
    int pid = blockIdx.x*4 + (threadIdx.x >> 6);    // b*N+n
    int lane = threadIdx.x & 63;
    const float* row = xT + (size_t)pid*CC;
    double acc = 0.0;
    #pragma unroll
    for (int c = lane; c < CC; c += 64) { double v = (double)row[c]; acc += v*v; }
    #pragma unroll
    for (int st = 32; st > 0; st >>= 1) acc += __shfl_down(acc, st);
    if (lane == 0) { xx[pid] = (float)acc; xxd[pid] = acc; }
}

// ---------------- f32 Gram, 64x64 tiles, 4x4/thread, triangular grid ----------------
__global__ __launch_bounds__(256) void k_gram(const float* __restrict__ x, const float* __restrict__ xx,
                                              float* __restrict__ scores4) {
    __shared__ float As[16][64];
    __shared__ float Bs[16][64];
    int tid = blockIdx.x;               // 0..527 triangular tile
    int b = blockIdx.y;
    int by = 0, rem = tid;
    while (rem >= 32 - by) { rem -= 32 - by; by++; }
    int bx = by + rem;
    int n0 = by*64, m0 = bx*64;
    int t = threadIdx.x;
    int tx = t & 15, ty = t >> 4;
    const float* xb = x + (size_t)b*CC*NPT;
    float* scores = scores4 + (size_t)b*NPT*NPT;
    float acc[4][4] = {};
    for (int c0 = 0; c0 < CC; c0 += 16) {
        #pragma unroll
        for (int i = 0; i < 4; i++) {
            int e = t + i*256;
            int cc = e >> 6, col = e & 63;
            As[cc][col] = xb[(size_t)(c0+cc)*NPT + n0 + col];
            Bs[cc][col] = xb[(size_t)(c0+cc)*NPT + m0 + col];
        }
        __syncthreads();
        #pragma unroll
        for (int kk = 0; kk < 16; kk++) {
            float4 a  = *(const float4*)&As[kk][ty*4];
            float4 bv = *(const float4*)&Bs[kk][tx*4];
            acc[0][0] += a.x*bv.x; acc[0][1] += a.x*bv.y; acc[0][2] += a.x*bv.z; acc[0][3] += a.x*bv.w;
            acc[1][0] += a.y*bv.x; acc[1][1] += a.y*bv.y; acc[1][2] += a.y*bv.z; acc[1][3] += a.y*bv.w;
            acc[2][0] += a.z*bv.x; acc[2][1] += a.z*bv.y; acc[2][2] += a.z*bv.z; acc[2][3] += a.z*bv.w;
            acc[3][0] += a.w*bv.x; acc[3][1] += a.w*bv.y; acc[3][2] += a.w*bv.z; acc[3][3] += a.w*bv.w;
        }
        __syncthreads();
    }
    int nb = n0 + ty*4, mb = m0 + tx*4;
    float xn[4], xm[4];
    #pragma unroll
    for (int i = 0; i < 4; i++) { xn[i] = xx[b*NPT + nb + i]; xm[i] = xx[b*NPT + mb + i]; }
    float val[4][4];
    #pragma unroll
    for (int i = 0; i < 4; i++)
        #pragma unroll
        for (int j = 0; j < 4; j++) {
            val[i][j] = 2.f*acc[i][j] - xn[i] - xm[j];
            scores[(size_t)(nb+i)*NPT + mb + j] = val[i][j];
        }
    if (bx != by) {
        #pragma unroll
        for (int j = 0; j < 4; j++)
            #pragma unroll
            for (int i = 0; i < 4; i++)
                scores[(size_t)(mb+j)*NPT + nb + i] = val[i][j];
    }
}

// ---------------- top-NCAND per row: radix select (set-identical to f32 top-32) ----------------
__global__ __launch_bounds__(256) void k_topk(const float* __restrict__ scores4, int* __restrict__ candout) {
    int n = blockIdx.x, b = blockIdx.y;
    const float* row = scores4 + ((size_t)b*NPT + n)*NPT;
    unsigned key[8];
    #pragma unroll
    for (int w = 0; w < 8; w++) {
        unsigned u = __float_as_uint(row[threadIdx.x + w*256]);
        key[w] = (u & 0x80000000u) ? ~u : (u | 0x80000000u);   // monotone float->uint
    }
    __shared__ int hist[4][257];
    __shared__ int histsum[256];
    __shared__ unsigned s_pfx;
    __shared__ int s_need, s_slot, s_tie;
    __shared__ unsigned long long tiel[256];
    int wv = threadIdx.x >> 6;
    if (threadIdx.x == 0) { s_pfx = 0u; s_need = NCAND; s_slot = 0; s_tie = 0; }
    #pragma unroll
    for (int pass = 0; pass < 3; pass++) {
        int sh = (pass == 0) ? 24 : (pass == 1 ? 16 : 8);
        unsigned maskhi = (pass == 0) ? 0u : (pass == 1 ? 0xFF000000u : 0xFFFF0000u);
        hist[0][threadIdx.x] = 0; hist[1][threadIdx.x] = 0;
        hist[2][threadIdx.x] = 0; hist[3][threadIdx.x] = 0;
        __syncthreads();
        unsigned pfx = s_pfx;
        #pragma unroll
        for (int w = 0; w < 8; w++) {
            unsigned v = key[w];
            if ((v & maskhi) == (pfx & maskhi))
                atomicAdd(&hist[wv][(v >> sh) & 0xFF], 1);
        }
        __syncthreads();
        histsum[threadIdx.x] = hist[0][threadIdx.x] + hist[1][threadIdx.x]
                             + hist[2][threadIdx.x] + hist[3][threadIdx.x];
        __syncthreads();
        if (threadIdx.x < 64) {
            int l = threadIdx.x, base = l*4;
            int c0 = histsum[base], c1 = histsum[base+1], c2 = histsum[base+2], c3 = histsum[base+3];
            int mysum = c0 + c1 + c2 + c3;
            int suf = mysum;
            #pragma unroll
            for (int st = 1; st < 64; st <<= 1) {
                int u2 = __shfl_down(suf, st);
                if (l + st >= 64) u2 = 0;
                suf += u2;
            }
            int need = s_need;
            int sufNext = suf - mysum;
            if (suf >= need && sufNext < need) {        // exactly one lane
                int s3 = sufNext + c3, s2p = s3 + c2, s1p = s2p + c1;
                int B, Sb1;
                if (s3 >= need)       { B = base+3; Sb1 = sufNext; }
                else if (s2p >= need) { B = base+2; Sb1 = s3; }
                else if (s1p >= need) { B = base+1; Sb1 = s2p; }
                else                  { B = base;   Sb1 = s1p; }
                s_pfx = s_pfx | ((unsigned)B << sh);
                s_need = need - Sb1;
            }
        }
        __syncthreads();
    }
    unsigned pfx24 = s_pfx & 0xFFFFFF00u;
    int* outp = candout + ((size_t)b*NPT + n)*NCAND;
    #pragma unroll
    for (int w = 0; w < 8; w++) {
        unsigned v = key[w];
        unsigned hi = v & 0xFFFFFF00u;
        int i = threadIdx.x + w*256;
        if (hi > pfx24) {
            int s = atomicAdd(&s_slot, 1);
            outp[s] = i;
        } else if (hi == pfx24) {
            int ti = atomicAdd(&s_tie, 1);
            if (ti < 256) tiel[ti] = ((unsigned long long)v << 32) | (unsigned)(NPT-1-i);
        }
    }
    __syncthreads();
    if (threadIdx.x == 0) {
        int A = s_slot, r = s_need, T = s_tie < 256 ? s_tie : 256;
        for (int kk = 0; kk < r; kk++) {
            unsigned long long best = 0ull; int bj = 0;
            for (int j2 = 0; j2 < T; j2++) if (tiel[j2] > best) { best = tiel[j2]; bj = j2; }
            tiel[bj] = 0ull;
            outp[A + kk] = NPT-1-(int)(best & 0xFFFFFFFFu);
        }
    }
}

// ---------------- exact f64 rescore -> final top-20 (wave-parallel selection) ----------------
__global__ __launch_bounds__(256) void k_rescore(const float* __restrict__ xT, const double* __restrict__ xxd,
                                                 const int* __restrict__ cand, int* __restrict__ idxout) {
    __shared__ float xn[CC];
    __shared__ double sc[NCAND];
    __shared__ int ci[NCAND];
    int t = blockIdx.x;             // b*N + n
    int b = t >> 11;
    const float* xrow = xT + (size_t)t*CC;
    for (int i = threadIdx.x; i < CC; i += 256) xn[i] = xrow[i];
    if (threadIdx.x < NCAND) ci[threadIdx.x] = cand[(size_t)t*NCAND + threadIdx.x];
    __syncthreads();
    int j = threadIdx.x >> 3, l = threadIdx.x & 7;
    int m = ci[j];
    const float* xm = xT + ((size_t)b*NPT + m)*CC;
    double acc = 0.0;
    int cbase = l*48;
    #pragma unroll 8
    for (int c = 0; c < 48; c++) acc += (double)xn[cbase+c] * (double)xm[cbase+c];
    acc += __shfl_down(acc, 4, 8);
    acc += __shfl_down(acc, 2, 8);
    acc += __shfl_down(acc, 1, 8);
    if (l == 0) sc[j] = 2.0*acc - xxd[t] - xxd[(size_t)b*NPT + m];
    __syncthreads();
    if (threadIdx.x < 64) {
        double v = (threadIdx.x < NCAND) ? sc[threadIdx.x] : -1e300;
        int oi = (threadIdx.x < NCAND) ? ci[threadIdx.x] : NPT;
        for (int kk = 0; kk < KNN; kk++) {
            double bv = v; int bo = oi;
            #pragma unroll
            for (int st = 16; st > 0; st >>= 1) {
                double ov = __shfl_xor(bv, st, 32);
                int    oo = __shfl_xor(bo, st, 32);
                if (ov > bv || (ov == bv && oo < bo)) { bv = ov; bo = oo; }
            }
            if (threadIdx.x == 0) idxout[(size_t)t*KNN + kk] = bo;
            if (oi == bo) v = -1e300;   // unique owner eliminates winner
        }
    }
}

// ---------------- P/Q precompute (f64), point-major out, LDS x + LDS transposed weights ----------------
__global__ __launch_bounds__(256) void k_pq_d(const float* __restrict__ xT,
                                              const float* __restrict__ wf, const float* __restrict__ wd,
                                              double* __restrict__ Pf, double* __restrict__ Qf,
                                              double* __restrict__ Pd, double* __restrict__ Qd) {
    __shared__ float xs[4][CC];             // 6144 B
    __shared__ float wfa[128*NCH];          // wf[o*256+c3]      -> [c3*21+o]
    __shared__ float wfb[128*NCH];          // wf[o*256+128+c3]  -> [c3*21+o]
    __shared__ float wda[128*NCH];
    __shared__ float wdb[128*NCH];
    int pt = threadIdx.x >> 6;                  // 0..3 local point
    int ov = threadIdx.x & 63;
    int row0 = blockIdx.x*4;                    // b*N+n base
    for (int i = threadIdx.x; i < 4*CC; i += 256)
        xs[i/CC][i%CC] = xT[(size_t)(row0 + i/CC)*CC + (i%CC)];
    for (int i = threadIdx.x; i < 128*NCH; i += 256) {
        int o2 = i >> 7, c3 = i & 127;          // o2=0..20, c3 coalesced
        wfa[c3*NCH+o2] = wf[o2*256 + c3];
        wfb[c3*NCH+o2] = wf[o2*256 + 128 + c3];
        wda[c3*NCH+o2] = wd[o2*256 + c3];
        wdb[c3*NCH+o2] = wd[o2*256 + 128 + c3];
    }
    __syncthreads();
    if (ov >= 63) return;
    int o = ov / 3, v = ov % 3;
    const float* xp = &xs[pt][v];
    double pf = 0.0, qf = 0.0, pd = 0.0, qd = 0.0;
    #pragma unroll 4
    for (int c3 = 0; c3 < 128; c3++) {
        double xv = (double)xp[c3*3];
        double waf = (double)wfa[c3*NCH+o], wbf = (double)wfb[c3*NCH+o];
        double wad = (double)wda[c3*NCH+o], wbd = (double)wdb[c3*NCH+o];
        pf += waf*xv; qf += (wbf-waf)*xv;
        pd += wad*xv; qd += (wbd-wad)*xv;
    }
    size_t off = (size_t)(row0 + pt)*64 + ov;
    Pf[off] = pf; Qf[off] = qf; Pd[off] = pd; Qd[off] = qd;
}

// ---------------- BN1 partial sums (f64, deterministic) ----------------
__global__ __launch_bounds__(256) void k_bn1_part(const double* __restrict__ Pf, const double* __restrict__ Qf,
                                                  const int* __restrict__ idx, double* __restrict__ part) {
    __shared__ double red[4][42];
    int t = blockIdx.x*256 + threadIdx.x;       // (b*N+n)*K+k
    int bn = t / KNN;
    int n = bn & (NPT-1); int b = bn >> 11;
    int m = idx[t];
    const double* PF = Pf + ((size_t)b*NPT + m)*64;
    const double* QF = Qf + ((size_t)b*NPT + n)*64;
    int wave = threadIdx.x >> 6;
    #pragma unroll
    for (int o = 0; o < NCH; o++) {
        double p0 = PF[o*3+0] + QF[o*3+0];
        double p1 = PF[o*3+1] + QF[o*3+1];
        double p2 = PF[o*3+2] + QF[o*3+2];
        double nr = sqrt(p0*p0 + p1*p1 + p2*p2) + EPSD;
        double a = nr, c2 = nr*nr;
        #pragma unroll
        for (int st = 32; st > 0; st >>= 1) { a += __shfl_down(a, st); c2 += __shfl_down(c2, st); }
        if ((threadIdx.x & 63) == 0) { red[wave][o] = a; red[wave][NCH+o] = c2; }
    }
    __syncthreads();
    if (threadIdx.x < 42)
        part[(size_t)blockIdx.x*42 + threadIdx.x] =
            red[0][threadIdx.x] + red[1][threadIdx.x] + red[2][threadIdx.x] + red[3][threadIdx.x];
}

// ---------------- finalize f64 stats (parallel: 21 blocks x 256 thr) ----------------
__global__ __launch_bounds__(256) void k_fin_d(const double* __restrict__ part, double* __restrict__ st,
                                               int nblk, double cnt) {
    __shared__ double r0[4], r1[4];
    int o = blockIdx.x;             // 0..NCH-1
    double s0 = 0.0, s1 = 0.0;
    for (int i = threadIdx.x; i < nblk; i += 256) {
        s0 += part[(size_t)i*42 + o];
        s1 += part[(size_t)i*42 + NCH + o];
    }
    #pragma unroll
    for (int stp = 32; stp > 0; stp >>= 1) { s0 += __shfl_down(s0, stp); s1 += __shfl_down(s1, stp); }
    int wv = threadIdx.x >> 6;
    if ((threadIdx.x & 63) == 0) { r0[wv] = s0; r1[wv] = s1; }
    __syncthreads();
    if (threadIdx.x == 0) {
        double sum = r0[0]+r0[1]+r0[2]+r0[3];
        double ssq = r1[0]+r1[1]+r1[2]+r1[3];
        double mean = sum / cnt;
        double var = ssq / cnt - mean*mean;
        if (var < 0.0) var = 0.0;
        st[o] = mean;
        st[NCH+o] = 1.0 / sqrt(var + BNEPSD);
    }
}

// ---------------- block1 (f64) -> BN2 partials; 8 threads/pair, 32 pairs/block ----------------
__global__ __launch_bounds__(256) void k_b1_bn2part(const double* __restrict__ Pf, const double* __restrict__ Qf,
                                                    const double* __restrict__ Pd, const double* __restrict__ Qd,
                                                    const int* __restrict__ idx, const double* __restrict__ st1,
                                                    const float* __restrict__ w2f_g, double* __restrict__ part) {
    __shared__ double h1L[32][65];
    __shared__ double w2s[NCH*NCH];
    __shared__ double s1[42];
    __shared__ double wred[4][42];
    int tid = threadIdx.x;
    int p = tid >> 3, j = tid & 7;
    int t = blockIdx.x*32 + p;
    for (int i = tid; i < NCH*NCH; i += 256) w2s[i] = (double)w2f_g[i];
    if (tid < 42) s1[tid] = st1[tid];
    int bn = t / KNN;
    int n = bn & (NPT-1), b = bn >> 11;
    int m = idx[t];
    const double* PF = Pf + ((size_t)b*NPT + m)*64;
    const double* QF = Qf + ((size_t)b*NPT + n)*64;
    const double* PD = Pd + ((size_t)b*NPT + m)*64;
    const double* QD = Qd + ((size_t)b*NPT + n)*64;
    __syncthreads();
    for (int o = j; o < NCH; o += 8) {
        double p0 = PF[o*3+0] + QF[o*3+0];
        double p1 = PF[o*3+1] + QF[o*3+1];
        double p2 = PF[o*3+2] + QF[o*3+2];
        double d0 = PD[o*3+0] + QD[o*3+0];
        double d1 = PD[o*3+1] + QD[o*3+1];
        double d2 = PD[o*3+2] + QD[o*3+2];
        double nr = sqrt(p0*p0 + p1*p1 + p2*p2) + EPSD;
        double fac = (nr - s1[o]) * s1[NCH+o] / nr;
        p0 *= fac; p1 *= fac; p2 *= fac;
        double dot = p0*d0 + p1*d1 + p2*d2;
        double dd  = d0*d0 + d1*d1 + d2*d2;
        double coef = dot / (dd + EPSD);
        double w0 = (dot >= 0.0) ? p0 : (p0 - coef*d0);
        double w1 = (dot >= 0.0) ? p1 : (p1 - coef*d1);
        double w2 = (dot >= 0.0) ? p2 : (p2 - coef*d2);
        h1L[p][o*3+0] = 0.2*p0 + 0.8*w0;
        h1L[p][o*3+1] = 0.2*p1 + 0.8*w1;
        h1L[p][o*3+2] = 0.2*p2 + 0.8*w2;
    }
    __syncthreads();
    double s[3] = {0.0,0.0,0.0}, q[3] = {0.0,0.0,0.0};
    {
        int oi = 0;
        for (int o = j; o < NCH; o += 8, oi++) {
            double a0 = 0.0, a1 = 0.0, a2 = 0.0;
            #pragma unroll
            for (int c = 0; c < NCH; c++) {
                double w = w2s[o*NCH+c];
                a0 += w*h1L[p][c*3+0]; a1 += w*h1L[p][c*3+1]; a2 += w*h1L[p][c*3+2];
            }
            double nr = sqrt(a0*a0 + a1*a1 + a2*a2) + EPSD;
            s[oi] = nr; q[oi] = nr*nr;
        }
    }
    #pragma unroll
    for (int st = 8; st < 64; st <<= 1) {
        #pragma unroll
        for (int u = 0; u < 3; u++) { s[u] += __shfl_down(s[u], st); q[u] += __shfl_down(q[u], st); }
    }
    if ((tid & 63) < 8) {           // lanes 0..7 hold per-wave sums for their j
        int wv = tid >> 6, oi = 0;
        for (int o = j; o < NCH; o += 8, oi++) { wred[wv][o] = s[oi]; wred[wv][NCH+o] = q[oi]; }
    }
    __syncthreads();
    if (tid < 42)
        part[(size_t)blockIdx.x*42 + tid] = wred[0][tid]+wred[1][tid]+wred[2][tid]+wred[3][tid];
}

// ---------------- block1+block2 (f64) -> h2 f32 + pool dots f64; 8 thr/pair, single LDS tile ----------------
__global__ __launch_bounds__(256) void k_apply_d(const double* __restrict__ Pf, const double* __restrict__ Qf,
                                                 const double* __restrict__ Pd, const double* __restrict__ Qd,
                                                 const int* __restrict__ idx,
                                                 const double* __restrict__ st1, const double* __restrict__ st2,
                                                 const float* __restrict__ w2f_g, const float* __restrict__ w2d_g,
                                                 const float* __restrict__ wp_g,
                                                 float* __restrict__ h2f, double* __restrict__ dots) {
    __shared__ double hL[32][65];           // h1, then reused for h2
    __shared__ double w2fs[NCH*NCH];
    __shared__ double w2ds[NCH*NCH];
    __shared__ double wps[NCH*NCH];
    __shared__ double s1[42], s2[42];
    int tid = threadIdx.x;
    int p = tid >> 3, j = tid & 7;
    int t = blockIdx.x*32 + p;
    for (int i = tid; i < NCH*NCH; i += 256) {
        w2fs[i] = (double)w2f_g[i]; w2ds[i] = (double)w2d_g[i]; wps[i] = (double)wp_g[i];
    }
    if (tid < 42) { s1[tid] = st1[tid]; s2[tid] = st2[tid]; }
    int k = t % KNN; int bn = t / KNN;
    int n = bn & (NPT-1), b = bn >> 11;
    int m = idx[t];
    const double* PF = Pf + ((size_t)b*NPT + m)*64;
    const double* QF = Qf + ((size_t)b*NPT + n)*64;
    const double* PD = Pd + ((size_t)b*NPT + m)*64;
    const double* QD = Qd + ((size_t)b*NPT + n)*64;
    __syncthreads();
    // block1 -> hL (h1)
    #pragma unroll
    for (int oi = 0; oi < 3; oi++) {
        int o = j + oi*8;
        if (o < NCH) {
            double p0 = PF[o*3+0] + QF[o*3+0];
            double p1 = PF[o*3+1] + QF[o*3+1];
            double p2 = PF[o*3+2] + QF[o*3+2];
            double d0 = PD[o*3+0] + QD[o*3+0];
            double d1 = PD[o*3+1] + QD[o*3+1];
            double d2 = PD[o*3+2] + QD[o*3+2];
            double nr = sqrt(p0*p0 + p1*p1 + p2*p2) + EPSD;
            double fac = (nr - s1[o]) * s1[NCH+o] / nr;
            p0 *= fac; p1 *= fac; p2 *= fac;
            double dot = p0*d0 + p1*d1 + p2*d2;
            double dd  = d0*d0 + d1*d1 + d2*d2;
            double coef = dot / (dd + EPSD);
            double w0 = (dot >= 0.0) ? p0 : (p0 - coef*d0);
            double w1 = (dot >= 0.0) ? p1 : (p1 - coef*d1);
            double w2 = (dot >= 0.0) ? p2 : (p2 - coef*d2);
            hL[p][o*3+0] = 0.2*p0 + 0.8*w0;
            hL[p][o*3+1] = 0.2*p1 + 0.8*w1;
            hL[p][o*3+2] = 0.2*p2 + 0.8*w2;
        }
    }
    __syncthreads();
    // block2 into registers (compile-time oi indexing), write h2f as we go
    double h2r[3][3];
    #pragma unroll
    for (int oi = 0; oi < 3; oi++) {
        int o = j + oi*8;
        if (o < NCH) {
            double p0 = 0.0, p1 = 0.0, p2 = 0.0, d0 = 0.0, d1 = 0.0, d2 = 0.0;
            #pragma unroll
            for (int c = 0; c < NCH; c++) {
                double wa = w2fs[o*NCH+c], wb = w2ds[o*NCH+c];
                double x0 = hL[p][c*3+0], x1 = hL[p][c*3+1], x2 = hL[p][c*3+2];
                p0 += wa*x0; p1 += wa*x1; p2 += wa*x2;
                d0 += wb*x0; d1 += wb*x1; d2 += wb*x2;
            }
            double nr = sqrt(p0*p0 + p1*p1 + p2*p2) + EPSD;
            double fac = (nr - s2[o]) * s2[NCH+o] / nr;
            p0 *= fac; p1 *= fac; p2 *= fac;
            double dot = p0*d0 + p1*d1 + p2*d2;
            double dd  = d0*d0 + d1*d1 + d2*d2;
            double coef = dot / (dd + EPSD);
            double w0 = (dot >= 0.0) ? p0 : (p0 - coef*d0);
            double w1 = (dot >= 0.0) ? p1 : (p1 - coef*d1);
            double w2 = (dot >= 0.0) ? p2 : (p2 - coef*d2);
            double h0 = 0.2*p0 + 0.8*w0, h1v = 0.2*p1 + 0.8*w1, h2v = 0.2*p2 + 0.8*w2;
            h2r[oi][0] = h0; h2r[oi][1] = h1v; h2r[oi][2] = h2v;
            h2f[((size_t)(b*63 + o*3+0)*NPT + n)*KNN + k] = (float)h0;
            h2f[((size_t)(b*63 + o*3+1)*NPT + n)*KNN + k] = (float)h1v;
            h2f[((size_t)(b*63 + o*3+2)*NPT + n)*KNN + k] = (float)h2v;
        }
    }
    __syncthreads();        // everyone done reading h1
    #pragma unroll
    for (int oi = 0; oi < 3; oi++) {
        int o = j + oi*8;
        if (o < NCH) {
            hL[p][o*3+0] = h2r[oi][0];
            hL[p][o*3+1] = h2r[oi][1];
            hL[p][o*3+2] = h2r[oi][2];
        }
    }
    __syncthreads();
    // pool dots from hL (= h2)
    #pragma unroll
    for (int oi = 0; oi < 3; oi++) {
        int o = j + oi*8;
        if (o < NCH) {
            double dv0 = 0.0, dv1 = 0.0, dv2 = 0.0;
            #pragma unroll
            for (int c = 0; c < NCH; c++) {
                double w = wps[o*NCH+c];
                dv0 += w*hL[p][c*3+0]; dv1 += w*hL[p][c*3+1]; dv2 += w*hL[p][c*3+2];
            }
            double dt = hL[p][o*3+0]*dv0 + hL[p][o*3+1]*dv1 + hL[p][o*3+2]*dv2;
            dots[(((size_t)b*NCH + o)*NPT + n)*KNN + k] = dt;
        }
    }
}

// ---------------- pool: exact f64 argmax, gather f32 values ----------------
__global__ __launch_bounds__(32) void k_pool_d(const double* __restrict__ dots, const float* __restrict__ h2f,
                                               float* __restrict__ pooled) {
    int b = blockIdx.x >> 11, n = blockIdx.x & (NPT-1);
    int o = threadIdx.x;
    if (o >= NCH) return;
    const double* dp = dots + (((size_t)b*NCH + o)*NPT + n)*KNN;
    double best = dp[0]; int bk = 0;
    #pragma unroll
    for (int k = 1; k < KNN; k++) { double v = dp[k]; if (v > best) { best = v; bk = k; } }
    #pragma unroll
    for (int v = 0; v < 3; v++)
        pooled[((size_t)b*63 + o*3+v)*NPT + n] = h2f[(((size_t)b*63 + o*3+v)*NPT + n)*KNN + bk];
}

// ---------------- conv1 (63->256) + stats ----------------
__global__ __launch_bounds__(256) void k_conv1(const float* __restrict__ pooled, const float* __restrict__ w1,
                                               float* __restrict__ y1, float* __restrict__ sums) {
    int n = blockIdx.x*256 + threadIdx.x;
    int o = blockIdx.y, b = blockIdx.z;
    const float* pb = pooled + (size_t)b*63*NPT + n;
    const float* wo = w1 + o*63;
    float acc = 0.f;
    #pragma unroll
    for (int c = 0; c < 63; c++) acc += wo[c]*pb[(size_t)c*NPT];
    y1[((size_t)b*256 + o)*NPT + n] = acc;
    float a = acc, c2 = acc*acc;
    #pragma unroll
    for (int st = 32; st > 0; st >>= 1) { a += __shfl_down(a, st); c2 += __shfl_down(c2, st); }
    __shared__ float ra[4], rc[4];
    int wv = threadIdx.x >> 6;
    if ((threadIdx.x & 63) == 0) { ra[wv] = a; rc[wv] = c2; }
    __syncthreads();
    if (threadIdx.x == 0) {
        atomicAdd(&sums[o], ra[0]+ra[1]+ra[2]+ra[3]);
        atomicAdd(&sums[256+o], rc[0]+rc[1]+rc[2]+rc[3]);
    }
}

// ---------------- finalize f32 stats ----------------
__global__ void k_finalize(const float* __restrict__ sums, float* __restrict__ stats, float invcnt, int nch) {
    int o = blockIdx.x*blockDim.x + threadIdx.x;
    if (o >= nch) return;
    float mean = sums[o]*invcnt;
    float var = sums[nch+o]*invcnt - mean*mean;
    if (var < 0.f) var = 0.f;
    stats[o] = mean;
    stats[nch+o] = 1.0f / sqrtf(var + BNEPS);
}

// ---------------- bn+lrelu in place ----------------
__global__ __launch_bounds__(256) void k_act(float* __restrict__ y, const float* __restrict__ stats, int nch) {
    int t = blockIdx.x*256 + threadIdx.x;
    int o = (t >> 11) % nch;
    float z = (y[t] - stats[o]) * stats[nch+o];
    y[t] = z >= 0.f ? z : NEGS*z;
}

// ---------------- conv2 (256->128) + stats ----------------
__global__ __launch_bounds__(256) void k_conv2(const float* __restrict__ z1, const float* __restrict__ w2,
                                               float* __restrict__ y2, float* __restrict__ sums) {
    int n = blockIdx.x*256 + threadIdx.x;
    int o = blockIdx.y, b = blockIdx.z;
    const float* pb = z1 + (size_t)b*256*NPT + n;
    const float* wo = w2 + o*256;
    float acc = 0.f;
    #pragma unroll 4
    for (int c = 0; c < 256; c++) acc += wo[c]*pb[(size_t)c*NPT];
    y2[((size_t)b*128 + o)*NPT + n] = acc;
    float a = acc, c2 = acc*acc;
    #pragma unroll
    for (int st = 32; st > 0; st >>= 1) { a += __shfl_down(a, st); c2 += __shfl_down(c2, st); }
    __shared__ float ra[4], rc[4];
    int wv = threadIdx.x >> 6;
    if ((threadIdx.x & 63) == 0) { ra[wv] = a; rc[wv] = c2; }
    __syncthreads();
    if (threadIdx.x == 0) {
        atomicAdd(&sums[o], ra[0]+ra[1]+ra[2]+ra[3]);
        atomicAdd(&sums[128+o], rc[0]+rc[1]+rc[2]+rc[3]);
    }
}

// ---------------- final: act(conv2) -> conv3 + bias ----------------
__global__ __launch_bounds__(256) void k_final(const float* __restrict__ y2, const float* __restrict__ w3,
                                               const float* __restrict__ b3, const float* __restrict__ stats,
                                               float* __restrict__ out) {
    int t = blockIdx.x*256 + threadIdx.x;       // B*N
    int n = t & (NPT-1); int b = t >> 11;
    const float* yb = y2 + (size_t)b*128*NPT + n;
    float acc = b3[0];
    #pragma unroll 4
    for (int c = 0; c < 128; c++) {
        float z = (yb[(size_t)c*NPT] - stats[c]) * stats[128+c];
        z = z >= 0.f ? z : NEGS*z;
        acc += w3[c]*z;
    }
    out[t] = acc;
}

extern "C" void kernel_launch(void* const* d_in, const int* in_sizes, int n_in,
                              void* d_out, int out_size, void* d_ws, size_t ws_size,
                              hipStream_t stream) {
    const float* x   = (const float*)d_in[0];
    const float* w1f = (const float*)d_in[1];
    const float* w1d = (const float*)d_in[2];
    const float* w2f = (const float*)d_in[3];
    const float* w2d = (const float*)d_in[4];
    const float* wp  = (const float*)d_in[5];
    const float* wc1 = (const float*)d_in[6];
    const float* wc2 = (const float*)d_in[7];
    const float* wc3 = (const float*)d_in[8];
    const float* bc3 = (const float*)d_in[9];
    float* out = (float*)d_out;

    float* ws = (float*)d_ws;
    float*  scores4 = ws;                          // 16,777,216 (4 x N x N)
    float*  xxf     = ws + 16777216;               // 8,192
    double* xxd     = (double*)(ws + 16785408);    // 8,192 d
    int*    cand    = (int*)(ws + 16801792);       // 262,144
    int*    idx     = (int*)(ws + 17063936);       // 163,840
    float*  xT      = ws + 17227776;               // 3,145,728
    double* Pfd     = (double*)(ws + 20373504);    // 524,288 d each (point-major [b*N+n][64])
    double* Qfd     = (double*)(ws + 21422080);
    double* Pdd     = (double*)(ws + 22470656);
    double* Qdd     = (double*)(ws + 23519232);
    double* part1   = (double*)(ws + 24567808);    // 640*42 d
    double* part2   = (double*)(ws + 24621568);    // 5120*42 d
    double* st1     = (double*)(ws + 25051648);    // 42 d
    double* st2     = (double*)(ws + 25051776);    // 42 d
    float*  sums_f  = ws + 25051904;               // 1024
    float*  stats_f = ws + 25052928;               // 1024
    double* dots    = (double*)(ws + 25053952);    // 3,440,640 d
    float*  h2f     = ws + 31935232;               // 10,321,920
    float*  pooled  = ws + 42257152;               // 516,096
    float*  y1      = ws + 42773248;               // 2,097,152
    float*  y2      = ws + 44870400;               // 1,048,576 (end 45,918,976 f = 176 MB)

    k_zero<<<4, 256, 0, stream>>>(sums_f, 1024);
    k_xt<<<dim3(NPT/64, CC/64, BB), 256, 0, stream>>>(x, xT);
    k_xx<<<BB*NPT/4, 256, 0, stream>>>(xT, xxf, xxd);
    k_gram<<<dim3(528, BB), 256, 0, stream>>>(x, xxf, scores4);
    k_topk<<<dim3(NPT, BB), 256, 0, stream>>>(scores4, cand);
    k_rescore<<<BB*NPT, 256, 0, stream>>>(xT, xxd, cand, idx);
    k_pq_d<<<BB*NPT/4, 256, 0, stream>>>(xT, w1f, w1d, Pfd, Qfd, Pdd, Qdd);
    k_bn1_part<<<TOT/256, 256, 0, stream>>>(Pfd, Qfd, idx, part1);
    k_fin_d<<<NCH, 256, 0, stream>>>(part1, st1, TOT/256, (double)TOT);
    k_b1_bn2part<<<TOT/32, 256, 0, stream>>>(Pfd, Qfd, Pdd, Qdd, idx, st1, w2f, part2);
    k_fin_d<<<NCH, 256, 0, stream>>>(part2, st2, TOT/32, (double)TOT);
    k_apply_d<<<TOT/32, 256, 0, stream>>>(Pfd, Qfd, Pdd, Qdd, idx, st1, st2, w2f, w2d, wp, h2f, dots);
    k_pool_d<<<BB*NPT, 32, 0, stream>>>(dots, h2f, pooled);
    k_conv1<<<dim3(NPT/256, 256, BB), 256, 0, stream>>>(pooled, wc1, y1, sums_f);
    k_finalize<<<1, 256, 0, stream>>>(sums_f, stats_f, 1.f/(float)(BB*NPT), 256);
    k_act<<<BB*256*NPT/256, 256, 0, stream>>>(y1, stats_f, 256);
    k_conv2<<<dim3(NPT/256, 128, BB), 256, 0, stream>>>(y1, wc2, y2, sums_f+512);
    k_finalize<<<1, 128, 0, stream>>>(sums_f+512, stats_f+512, 1.f/(float)(BB*NPT), 128);
    k_final<<<BB*NPT/256, 256, 0, stream>>>(y2, wc3, bc3, stats_f+512, out);
}

// Round 15
// 603.749 us; speedup vs baseline: 1.5890x; 1.0425x over previous
//
#include <hip/hip_runtime.h>
#include <cstddef>

#define BB 4
#define CC 384
#define NPT 2048
#define KNN 20
#define NCAND 32
#define NCH 21
#define NKT (NPT*KNN)
#define TOT (BB*NKT)
#define EPSD 1e-6
#define BNEPSD 1e-5
#define EPSF 1e-6f
#define BNEPS 1e-5f
#define NEGS 0.2f

// ---------------- zero ----------------
__global__ __launch_bounds__(256) void k_zero(float* p, int n) {
    int t = blockIdx.x*256 + threadIdx.x;
    if (t < n) p[t] = 0.f;
}

// ---------------- transpose x -> xT (B,N,C) ----------------
__global__ __launch_bounds__(256) void k_xt(const float* __restrict__ x, float* __restrict__ xT) {
    __shared__ float tile[64][65];
    int n0 = blockIdx.x*64, c0 = blockIdx.y*64, b = blockIdx.z;
    int tx = threadIdx.x & 63, ty = threadIdx.x >> 6;
    const float* xb = x + (size_t)b*CC*NPT;
    #pragma unroll
    for (int r = 0; r < 64; r += 4)
        tile[r+ty][tx] = xb[(size_t)(c0+r+ty)*NPT + n0 + tx];
    __syncthreads();
    float* xtb = xT + (size_t)b*NPT*CC;
    #pragma unroll
    for (int r = 0; r < 64; r += 4)
        xtb[(size_t)(n0+r+ty)*CC + c0 + tx] = tile[tx][r+ty];
}

// ---------------- xx = sum_c x^2 (f64), wave-per-point from xT ----------------
__global__ __launch_bounds__(256) void k_xx(const float* __restrict__ xT, float* __restrict__ xx,
                                            double* __restrict__ xxd) {
    int pid = blockIdx.x*4 + (threadIdx.x >> 6);    // b*N+n
    int lane = threadIdx.x & 63;
    const float* row = xT + (size_t)pid*CC;
    double acc = 0.0;
    #pragma unroll
    for (int c = lane; c < CC; c += 64) { double v = (double)row[c]; acc += v*v; }
    #pragma unroll
    for (int st = 32; st > 0; st >>= 1) acc += __shfl_down(acc, st);
    if (lane == 0) { xx[pid] = (float)acc; xxd[pid] = acc; }
}

// ---------------- f32 Gram, 64x64 tiles, 4x4/thread, triangular grid ----------------
__global__ __launch_bounds__(256) void k_gram(const float* __restrict__ x, const float* __restrict__ xx,
                                              float* __restrict__ scores4) {
    __shared__ float As[16][64];
    __shared__ float Bs[16][64];
    int tid = blockIdx.x;               // 0..527 triangular tile
    int b = blockIdx.y;
    int by = 0, rem = tid;
    while (rem >= 32 - by) { rem -= 32 - by; by++; }
    int bx = by + rem;
    int n0 = by*64, m0 = bx*64;
    int t = threadIdx.x;
    int tx = t & 15, ty = t >> 4;
    const float* xb = x + (size_t)b*CC*NPT;
    float* scores = scores4 + (size_t)b*NPT*NPT;
    float acc[4][4] = {};
    for (int c0 = 0; c0 < CC; c0 += 16) {
        #pragma unroll
        for (int i = 0; i < 4; i++) {
            int e = t + i*256;
            int cc = e >> 6, col = e & 63;
            As[cc][col] = xb[(size_t)(c0+cc)*NPT + n0 + col];
            Bs[cc][col] = xb[(size_t)(c0+cc)*NPT + m0 + col];
        }
        __syncthreads();
        #pragma unroll
        for (int kk = 0; kk < 16; kk++) {
            float4 a  = *(const float4*)&As[kk][ty*4];
            float4 bv = *(const float4*)&Bs[kk][tx*4];
            acc[0][0] += a.x*bv.x; acc[0][1] += a.x*bv.y; acc[0][2] += a.x*bv.z; acc[0][3] += a.x*bv.w;
            acc[1][0] += a.y*bv.x; acc[1][1] += a.y*bv.y; acc[1][2] += a.y*bv.z; acc[1][3] += a.y*bv.w;
            acc[2][0] += a.z*bv.x; acc[2][1] += a.z*bv.y; acc[2][2] += a.z*bv.z; acc[2][3] += a.z*bv.w;
            acc[3][0] += a.w*bv.x; acc[3][1] += a.w*bv.y; acc[3][2] += a.w*bv.z; acc[3][3] += a.w*bv.w;
        }
        __syncthreads();
    }
    int nb = n0 + ty*4, mb = m0 + tx*4;
    float xn[4], xm[4];
    #pragma unroll
    for (int i = 0; i < 4; i++) { xn[i] = xx[b*NPT + nb + i]; xm[i] = xx[b*NPT + mb + i]; }
    float val[4][4];
    #pragma unroll
    for (int i = 0; i < 4; i++)
        #pragma unroll
        for (int j = 0; j < 4; j++) {
            val[i][j] = 2.f*acc[i][j] - xn[i] - xm[j];
            scores[(size_t)(nb+i)*NPT + mb + j] = val[i][j];
        }
    if (bx != by) {
        #pragma unroll
        for (int j = 0; j < 4; j++)
            #pragma unroll
            for (int i = 0; i < 4; i++)
                scores[(size_t)(mb+j)*NPT + nb + i] = val[i][j];
    }
}

// ---------------- top-NCAND per row: radix select (set-identical to f32 top-32) ----------------
__global__ __launch_bounds__(256) void k_topk(const float* __restrict__ scores4, int* __restrict__ candout) {
    int n = blockIdx.x, b = blockIdx.y;
    const float* row = scores4 + ((size_t)b*NPT + n)*NPT;
    unsigned key[8];
    #pragma unroll
    for (int w = 0; w < 8; w++) {
        unsigned u = __float_as_uint(row[threadIdx.x + w*256]);
        key[w] = (u & 0x80000000u) ? ~u : (u | 0x80000000u);   // monotone float->uint
    }
    __shared__ int hist[4][257];
    __shared__ int histsum[256];
    __shared__ unsigned s_pfx;
    __shared__ int s_need, s_slot, s_tie;
    __shared__ unsigned long long tiel[256];
    int wv = threadIdx.x >> 6;
    if (threadIdx.x == 0) { s_pfx = 0u; s_need = NCAND; s_slot = 0; s_tie = 0; }
    #pragma unroll
    for (int pass = 0; pass < 3; pass++) {
        int sh = (pass == 0) ? 24 : (pass == 1 ? 16 : 8);
        unsigned maskhi = (pass == 0) ? 0u : (pass == 1 ? 0xFF000000u : 0xFFFF0000u);
        hist[0][threadIdx.x] = 0; hist[1][threadIdx.x] = 0;
        hist[2][threadIdx.x] = 0; hist[3][threadIdx.x] = 0;
        __syncthreads();
        unsigned pfx = s_pfx;
        #pragma unroll
        for (int w = 0; w < 8; w++) {
            unsigned v = key[w];
            if ((v & maskhi) == (pfx & maskhi))
                atomicAdd(&hist[wv][(v >> sh) & 0xFF], 1);
        }
        __syncthreads();
        histsum[threadIdx.x] = hist[0][threadIdx.x] + hist[1][threadIdx.x]
                             + hist[2][threadIdx.x] + hist[3][threadIdx.x];
        __syncthreads();
        if (threadIdx.x < 64) {
            int l = threadIdx.x, base = l*4;
            int c0 = histsum[base], c1 = histsum[base+1], c2 = histsum[base+2], c3 = histsum[base+3];
            int mysum = c0 + c1 + c2 + c3;
            int suf = mysum;
            #pragma unroll
            for (int st = 1; st < 64; st <<= 1) {
                int u2 = __shfl_down(suf, st);
                if (l + st >= 64) u2 = 0;
                suf += u2;
            }
            int need = s_need;
            int sufNext = suf - mysum;
            if (suf >= need && sufNext < need) {        // exactly one lane
                int s3 = sufNext + c3, s2p = s3 + c2, s1p = s2p + c1;
                int B, Sb1;
                if (s3 >= need)       { B = base+3; Sb1 = sufNext; }
                else if (s2p >= need) { B = base+2; Sb1 = s3; }
                else if (s1p >= need) { B = base+1; Sb1 = s2p; }
                else                  { B = base;   Sb1 = s1p; }
                s_pfx = s_pfx | ((unsigned)B << sh);
                s_need = need - Sb1;
            }
        }
        __syncthreads();
    }
    unsigned pfx24 = s_pfx & 0xFFFFFF00u;
    int* outp = candout + ((size_t)b*NPT + n)*NCAND;
    #pragma unroll
    for (int w = 0; w < 8; w++) {
        unsigned v = key[w];
        unsigned hi = v & 0xFFFFFF00u;
        int i = threadIdx.x + w*256;
        if (hi > pfx24) {
            int s = atomicAdd(&s_slot, 1);
            outp[s] = i;
        } else if (hi == pfx24) {
            int ti = atomicAdd(&s_tie, 1);
            if (ti < 256) tiel[ti] = ((unsigned long long)v << 32) | (unsigned)(NPT-1-i);
        }
    }
    __syncthreads();
    if (threadIdx.x == 0) {
        int A = s_slot, r = s_need, T = s_tie < 256 ? s_tie : 256;
        for (int kk = 0; kk < r; kk++) {
            unsigned long long best = 0ull; int bj = 0;
            for (int j2 = 0; j2 < T; j2++) if (tiel[j2] > best) { best = tiel[j2]; bj = j2; }
            tiel[bj] = 0ull;
            outp[A + kk] = NPT-1-(int)(best & 0xFFFFFFFFu);
        }
    }
}

// ---------------- exact f64 rescore -> final top-20 (wave-parallel selection) ----------------
__global__ __launch_bounds__(256) void k_rescore(const float* __restrict__ xT, const double* __restrict__ xxd,
                                                 const int* __restrict__ cand, int* __restrict__ idxout) {
    __shared__ float xn[CC];
    __shared__ double sc[NCAND];
    __shared__ int ci[NCAND];
    int t = blockIdx.x;             // b*N + n
    int b = t >> 11;
    const float* xrow = xT + (size_t)t*CC;
    for (int i = threadIdx.x; i < CC; i += 256) xn[i] = xrow[i];
    if (threadIdx.x < NCAND) ci[threadIdx.x] = cand[(size_t)t*NCAND + threadIdx.x];
    __syncthreads();
    int j = threadIdx.x >> 3, l = threadIdx.x & 7;
    int m = ci[j];
    const float* xm = xT + ((size_t)b*NPT + m)*CC;
    double acc = 0.0;
    int cbase = l*48;
    #pragma unroll 8
    for (int c = 0; c < 48; c++) acc += (double)xn[cbase+c] * (double)xm[cbase+c];
    acc += __shfl_down(acc, 4, 8);
    acc += __shfl_down(acc, 2, 8);
    acc += __shfl_down(acc, 1, 8);
    if (l == 0) sc[j] = 2.0*acc - xxd[t] - xxd[(size_t)b*NPT + m];
    __syncthreads();
    if (threadIdx.x < 64) {
        double v = (threadIdx.x < NCAND) ? sc[threadIdx.x] : -1e300;
        int oi = (threadIdx.x < NCAND) ? ci[threadIdx.x] : NPT;
        for (int kk = 0; kk < KNN; kk++) {
            double bv = v; int bo = oi;
            #pragma unroll
            for (int st = 16; st > 0; st >>= 1) {
                double ov = __shfl_xor(bv, st, 32);
                int    oo = __shfl_xor(bo, st, 32);
                if (ov > bv || (ov == bv && oo < bo)) { bv = ov; bo = oo; }
            }
            if (threadIdx.x == 0) idxout[(size_t)t*KNN + kk] = bo;
            if (oi == bo) v = -1e300;   // unique owner eliminates winner
        }
    }
}

// ---------------- P/Q precompute (f64), point-major out, LDS x + LDS transposed weights ----------------
__global__ __launch_bounds__(256) void k_pq_d(const float* __restrict__ xT,
                                              const float* __restrict__ wf, const float* __restrict__ wd,
                                              double* __restrict__ Pf, double* __restrict__ Qf,
                                              double* __restrict__ Pd, double* __restrict__ Qd) {
    __shared__ float xs[4][CC];             // 6144 B
    __shared__ float wfa[128*NCH];          // wf[o*256+c3]      -> [c3*21+o]
    __shared__ float wfb[128*NCH];          // wf[o*256+128+c3]  -> [c3*21+o]
    __shared__ float wda[128*NCH];
    __shared__ float wdb[128*NCH];
    int pt = threadIdx.x >> 6;                  // 0..3 local point
    int ov = threadIdx.x & 63;
    int row0 = blockIdx.x*4;                    // b*N+n base
    for (int i = threadIdx.x; i < 4*CC; i += 256)
        xs[i/CC][i%CC] = xT[(size_t)(row0 + i/CC)*CC + (i%CC)];
    for (int i = threadIdx.x; i < 128*NCH; i += 256) {
        int o2 = i >> 7, c3 = i & 127;          // o2=0..20, c3 coalesced
        wfa[c3*NCH+o2] = wf[o2*256 + c3];
        wfb[c3*NCH+o2] = wf[o2*256 + 128 + c3];
        wda[c3*NCH+o2] = wd[o2*256 + c3];
        wdb[c3*NCH+o2] = wd[o2*256 + 128 + c3];
    }
    __syncthreads();
    if (ov >= 63) return;
    int o = ov / 3, v = ov % 3;
    const float* xp = &xs[pt][v];
    double pf = 0.0, qf = 0.0, pd = 0.0, qd = 0.0;
    #pragma unroll 4
    for (int c3 = 0; c3 < 128; c3++) {
        double xv = (double)xp[c3*3];
        double waf = (double)wfa[c3*NCH+o], wbf = (double)wfb[c3*NCH+o];
        double wad = (double)wda[c3*NCH+o], wbd = (double)wdb[c3*NCH+o];
        pf += waf*xv; qf += (wbf-waf)*xv;
        pd += wad*xv; qd += (wbd-wad)*xv;
    }
    size_t off = (size_t)(row0 + pt)*64 + ov;
    Pf[off] = pf; Qf[off] = qf; Pd[off] = pd; Qd[off] = qd;
}

// ---------------- BN1 partial sums (f64, deterministic) ----------------
__global__ __launch_bounds__(256) void k_bn1_part(const double* __restrict__ Pf, const double* __restrict__ Qf,
                                                  const int* __restrict__ idx, double* __restrict__ part) {
    __shared__ double red[4][42];
    int t = blockIdx.x*256 + threadIdx.x;       // (b*N+n)*K+k
    int bn = t / KNN;
    int n = bn & (NPT-1); int b = bn >> 11;
    int m = idx[t];
    const double* PF = Pf + ((size_t)b*NPT + m)*64;
    const double* QF = Qf + ((size_t)b*NPT + n)*64;
    int wave = threadIdx.x >> 6;
    #pragma unroll
    for (int o = 0; o < NCH; o++) {
        double p0 = PF[o*3+0] + QF[o*3+0];
        double p1 = PF[o*3+1] + QF[o*3+1];
        double p2 = PF[o*3+2] + QF[o*3+2];
        double nr = sqrt(p0*p0 + p1*p1 + p2*p2) + EPSD;
        double a = nr, c2 = nr*nr;
        #pragma unroll
        for (int st = 32; st > 0; st >>= 1) { a += __shfl_down(a, st); c2 += __shfl_down(c2, st); }
        if ((threadIdx.x & 63) == 0) { red[wave][o] = a; red[wave][NCH+o] = c2; }
    }
    __syncthreads();
    if (threadIdx.x < 42)
        part[(size_t)blockIdx.x*42 + threadIdx.x] =
            red[0][threadIdx.x] + red[1][threadIdx.x] + red[2][threadIdx.x] + red[3][threadIdx.x];
}

// ---------------- finalize f64 stats (parallel: 21 blocks x 256 thr) ----------------
__global__ __launch_bounds__(256) void k_fin_d(const double* __restrict__ part, double* __restrict__ st,
                                               int nblk, double cnt) {
    __shared__ double r0[4], r1[4];
    int o = blockIdx.x;             // 0..NCH-1
    double s0 = 0.0, s1 = 0.0;
    for (int i = threadIdx.x; i < nblk; i += 256) {
        s0 += part[(size_t)i*42 + o];
        s1 += part[(size_t)i*42 + NCH + o];
    }
    #pragma unroll
    for (int stp = 32; stp > 0; stp >>= 1) { s0 += __shfl_down(s0, stp); s1 += __shfl_down(s1, stp); }
    int wv = threadIdx.x >> 6;
    if ((threadIdx.x & 63) == 0) { r0[wv] = s0; r1[wv] = s1; }
    __syncthreads();
    if (threadIdx.x == 0) {
        double sum = r0[0]+r0[1]+r0[2]+r0[3];
        double ssq = r1[0]+r1[1]+r1[2]+r1[3];
        double mean = sum / cnt;
        double var = ssq / cnt - mean*mean;
        if (var < 0.0) var = 0.0;
        st[o] = mean;
        st[NCH+o] = 1.0 / sqrt(var + BNEPSD);
    }
}

// ---------------- block1 (f64) -> BN2 partials; 8 threads/pair, 32 pairs/block ----------------
__global__ __launch_bounds__(256) void k_b1_bn2part(const double* __restrict__ Pf, const double* __restrict__ Qf,
                                                    const double* __restrict__ Pd, const double* __restrict__ Qd,
                                                    const int* __restrict__ idx, const double* __restrict__ st1,
                                                    const float* __restrict__ w2f_g, double* __restrict__ part) {
    __shared__ double h1L[32][65];
    __shared__ double w2s[NCH*NCH];
    __shared__ double s1[42];
    __shared__ double wred[4][42];
    int tid = threadIdx.x;
    int p = tid >> 3, j = tid & 7;
    int t = blockIdx.x*32 + p;
    for (int i = tid; i < NCH*NCH; i += 256) w2s[i] = (double)w2f_g[i];
    if (tid < 42) s1[tid] = st1[tid];
    int bn = t / KNN;
    int n = bn & (NPT-1), b = bn >> 11;
    int m = idx[t];
    const double* PF = Pf + ((size_t)b*NPT + m)*64;
    const double* QF = Qf + ((size_t)b*NPT + n)*64;
    const double* PD = Pd + ((size_t)b*NPT + m)*64;
    const double* QD = Qd + ((size_t)b*NPT + n)*64;
    __syncthreads();
    for (int o = j; o < NCH; o += 8) {
        double p0 = PF[o*3+0] + QF[o*3+0];
        double p1 = PF[o*3+1] + QF[o*3+1];
        double p2 = PF[o*3+2] + QF[o*3+2];
        double d0 = PD[o*3+0] + QD[o*3+0];
        double d1 = PD[o*3+1] + QD[o*3+1];
        double d2 = PD[o*3+2] + QD[o*3+2];
        double nr = sqrt(p0*p0 + p1*p1 + p2*p2) + EPSD;
        double fac = (nr - s1[o]) * s1[NCH+o] / nr;
        p0 *= fac; p1 *= fac; p2 *= fac;
        double dot = p0*d0 + p1*d1 + p2*d2;
        double dd  = d0*d0 + d1*d1 + d2*d2;
        double coef = dot / (dd + EPSD);
        double w0 = (dot >= 0.0) ? p0 : (p0 - coef*d0);
        double w1 = (dot >= 0.0) ? p1 : (p1 - coef*d1);
        double w2 = (dot >= 0.0) ? p2 : (p2 - coef*d2);
        h1L[p][o*3+0] = 0.2*p0 + 0.8*w0;
        h1L[p][o*3+1] = 0.2*p1 + 0.8*w1;
        h1L[p][o*3+2] = 0.2*p2 + 0.8*w2;
    }
    __syncthreads();
    double s[3] = {0.0,0.0,0.0}, q[3] = {0.0,0.0,0.0};
    {
        int oi = 0;
        for (int o = j; o < NCH; o += 8, oi++) {
            double a0 = 0.0, a1 = 0.0, a2 = 0.0;
            #pragma unroll
            for (int c = 0; c < NCH; c++) {
                double w = w2s[o*NCH+c];
                a0 += w*h1L[p][c*3+0]; a1 += w*h1L[p][c*3+1]; a2 += w*h1L[p][c*3+2];
            }
            double nr = sqrt(a0*a0 + a1*a1 + a2*a2) + EPSD;
            s[oi] = nr; q[oi] = nr*nr;
        }
    }
    #pragma unroll
    for (int st = 8; st < 64; st <<= 1) {
        #pragma unroll
        for (int u = 0; u < 3; u++) { s[u] += __shfl_down(s[u], st); q[u] += __shfl_down(q[u], st); }
    }
    if ((tid & 63) < 8) {           // lanes 0..7 hold per-wave sums for their j
        int wv = tid >> 6, oi = 0;
        for (int o = j; o < NCH; o += 8, oi++) { wred[wv][o] = s[oi]; wred[wv][NCH+o] = q[oi]; }
    }
    __syncthreads();
    if (tid < 42)
        part[(size_t)blockIdx.x*42 + tid] = wred[0][tid]+wred[1][tid]+wred[2][tid]+wred[3][tid];
}

// ---------------- block1+block2+pool fused (f64); 1 point/block, 12 thr/pair, 256 thr ----------------
__global__ __launch_bounds__(256) void k_apply_pool(const double* __restrict__ Pf, const double* __restrict__ Qf,
                                                    const double* __restrict__ Pd, const double* __restrict__ Qd,
                                                    const int* __restrict__ idx,
                                                    const double* __restrict__ st1, const double* __restrict__ st2,
                                                    const float* __restrict__ w2f_g, const float* __restrict__ w2d_g,
                                                    const float* __restrict__ wp_g,
                                                    float* __restrict__ pooled) {
    __shared__ double hL[KNN][65];          // h1, then reused for h2 (10,400 B)
    __shared__ double w2fs[NCH*NCH];
    __shared__ double w2ds[NCH*NCH];
    __shared__ double wps[NCH*NCH];
    __shared__ double s1[42], s2[42];
    __shared__ double dotsL[NCH][KNN+1];    // 3,528 B
    __shared__ int midx[KNN];
    int tid = threadIdx.x;
    int bn = blockIdx.x;                    // b*N+n
    int n = bn & (NPT-1), b = bn >> 11;
    for (int i = tid; i < NCH*NCH; i += 256) {
        w2fs[i] = (double)w2f_g[i]; w2ds[i] = (double)w2d_g[i]; wps[i] = (double)wp_g[i];
    }
    if (tid < 42) { s1[tid] = st1[tid]; s2[tid] = st2[tid]; }
    if (tid < KNN) midx[tid] = idx[(size_t)bn*KNN + tid];
    __syncthreads();
    int p = tid / 12, j = tid % 12;         // pair (=k) and channel lane
    bool act = (p < KNN);
    const double* QF = Qf + (size_t)bn*64;
    const double* QD = Qd + (size_t)bn*64;
    const double* PF = Pf;
    const double* PD = Pd;
    if (act) {
        int m = midx[p];
        PF = Pf + ((size_t)b*NPT + m)*64;
        PD = Pd + ((size_t)b*NPT + m)*64;
    }
    // block1 -> hL (h1)
    if (act) {
        for (int o = j; o < NCH; o += 12) {
            double p0 = PF[o*3+0] + QF[o*3+0];
            double p1 = PF[o*3+1] + QF[o*3+1];
            double p2 = PF[o*3+2] + QF[o*3+2];
            double d0 = PD[o*3+0] + QD[o*3+0];
            double d1 = PD[o*3+1] + QD[o*3+1];
            double d2 = PD[o*3+2] + QD[o*3+2];
            double nr = sqrt(p0*p0 + p1*p1 + p2*p2) + EPSD;
            double fac = (nr - s1[o]) * s1[NCH+o] / nr;
            p0 *= fac; p1 *= fac; p2 *= fac;
            double dot = p0*d0 + p1*d1 + p2*d2;
            double dd  = d0*d0 + d1*d1 + d2*d2;
            double coef = dot / (dd + EPSD);
            double w0 = (dot >= 0.0) ? p0 : (p0 - coef*d0);
            double w1 = (dot >= 0.0) ? p1 : (p1 - coef*d1);
            double w2 = (dot >= 0.0) ? p2 : (p2 - coef*d2);
            hL[p][o*3+0] = 0.2*p0 + 0.8*w0;
            hL[p][o*3+1] = 0.2*p1 + 0.8*w1;
            hL[p][o*3+2] = 0.2*p2 + 0.8*w2;
        }
    }
    __syncthreads();
    // block2 into named registers (static indexing)
    double h2a0=0, h2a1=0, h2a2=0, h2b0=0, h2b1=0, h2b2=0;
    int oA = j, oB = j + 12;
    if (act) {
        {   // oA always < 21 (j<=11)
            int o = oA;
            double p0 = 0.0, p1 = 0.0, p2 = 0.0, d0 = 0.0, d1 = 0.0, d2 = 0.0;
            #pragma unroll
            for (int c = 0; c < NCH; c++) {
                double wa = w2fs[o*NCH+c], wb = w2ds[o*NCH+c];
                double x0 = hL[p][c*3+0], x1 = hL[p][c*3+1], x2 = hL[p][c*3+2];
                p0 += wa*x0; p1 += wa*x1; p2 += wa*x2;
                d0 += wb*x0; d1 += wb*x1; d2 += wb*x2;
            }
            double nr = sqrt(p0*p0 + p1*p1 + p2*p2) + EPSD;
            double fac = (nr - s2[o]) * s2[NCH+o] / nr;
            p0 *= fac; p1 *= fac; p2 *= fac;
            double dot = p0*d0 + p1*d1 + p2*d2;
            double dd  = d0*d0 + d1*d1 + d2*d2;
            double coef = dot / (dd + EPSD);
            double w0 = (dot >= 0.0) ? p0 : (p0 - coef*d0);
            double w1 = (dot >= 0.0) ? p1 : (p1 - coef*d1);
            double w2 = (dot >= 0.0) ? p2 : (p2 - coef*d2);
            h2a0 = 0.2*p0 + 0.8*w0; h2a1 = 0.2*p1 + 0.8*w1; h2a2 = 0.2*p2 + 0.8*w2;
        }
        if (oB < NCH) {
            int o = oB;
            double p0 = 0.0, p1 = 0.0, p2 = 0.0, d0 = 0.0, d1 = 0.0, d2 = 0.0;
            #pragma unroll
            for (int c = 0; c < NCH; c++) {
                double wa = w2fs[o*NCH+c], wb = w2ds[o*NCH+c];
                double x0 = hL[p][c*3+0], x1 = hL[p][c*3+1], x2 = hL[p][c*3+2];
                p0 += wa*x0; p1 += wa*x1; p2 += wa*x2;
                d0 += wb*x0; d1 += wb*x1; d2 += wb*x2;
            }
            double nr = sqrt(p0*p0 + p1*p1 + p2*p2) + EPSD;
            double fac = (nr - s2[o]) * s2[NCH+o] / nr;
            p0 *= fac; p1 *= fac; p2 *= fac;
            double dot = p0*d0 + p1*d1 + p2*d2;
            double dd  = d0*d0 + d1*d1 + d2*d2;
            double coef = dot / (dd + EPSD);
            double w0 = (dot >= 0.0) ? p0 : (p0 - coef*d0);
            double w1 = (dot >= 0.0) ? p1 : (p1 - coef*d1);
            double w2 = (dot >= 0.0) ? p2 : (p2 - coef*d2);
            h2b0 = 0.2*p0 + 0.8*w0; h2b1 = 0.2*p1 + 0.8*w1; h2b2 = 0.2*p2 + 0.8*w2;
        }
    }
    __syncthreads();        // all reads of h1 done
    if (act) {
        hL[p][oA*3+0] = h2a0; hL[p][oA*3+1] = h2a1; hL[p][oA*3+2] = h2a2;
        if (oB < NCH) { hL[p][oB*3+0] = h2b0; hL[p][oB*3+1] = h2b1; hL[p][oB*3+2] = h2b2; }
    }
    __syncthreads();
    // pool dots from hL (= h2)
    if (act) {
        for (int o = j; o < NCH; o += 12) {
            double dv0 = 0.0, dv1 = 0.0, dv2 = 0.0;
            #pragma unroll
            for (int c = 0; c < NCH; c++) {
                double w = wps[o*NCH+c];
                dv0 += w*hL[p][c*3+0]; dv1 += w*hL[p][c*3+1]; dv2 += w*hL[p][c*3+2];
            }
            dotsL[o][p] = hL[p][o*3+0]*dv0 + hL[p][o*3+1]*dv1 + hL[p][o*3+2]*dv2;
        }
    }
    __syncthreads();
    // argmax per channel + gather winner values
    if (tid < NCH) {
        int o = tid;
        double best = dotsL[o][0]; int bk = 0;
        #pragma unroll
        for (int kk = 1; kk < KNN; kk++) { double v = dotsL[o][kk]; if (v > best) { best = v; bk = kk; } }
        #pragma unroll
        for (int u = 0; u < 3; u++)
            pooled[((size_t)b*63 + o*3+u)*NPT + n] = (float)hL[bk][o*3+u];
    }
}

// ---------------- conv1 (63->256) + stats ----------------
__global__ __launch_bounds__(256) void k_conv1(const float* __restrict__ pooled, const float* __restrict__ w1,
                                               float* __restrict__ y1, float* __restrict__ sums) {
    int n = blockIdx.x*256 + threadIdx.x;
    int o = blockIdx.y, b = blockIdx.z;
    const float* pb = pooled + (size_t)b*63*NPT + n;
    const float* wo = w1 + o*63;
    float acc = 0.f;
    #pragma unroll
    for (int c = 0; c < 63; c++) acc += wo[c]*pb[(size_t)c*NPT];
    y1[((size_t)b*256 + o)*NPT + n] = acc;
    float a = acc, c2 = acc*acc;
    #pragma unroll
    for (int st = 32; st > 0; st >>= 1) { a += __shfl_down(a, st); c2 += __shfl_down(c2, st); }
    __shared__ float ra[4], rc[4];
    int wv = threadIdx.x >> 6;
    if ((threadIdx.x & 63) == 0) { ra[wv] = a; rc[wv] = c2; }
    __syncthreads();
    if (threadIdx.x == 0) {
        atomicAdd(&sums[o], ra[0]+ra[1]+ra[2]+ra[3]);
        atomicAdd(&sums[256+o], rc[0]+rc[1]+rc[2]+rc[3]);
    }
}

// ---------------- finalize f32 stats ----------------
__global__ void k_finalize(const float* __restrict__ sums, float* __restrict__ stats, float invcnt, int nch) {
    int o = blockIdx.x*blockDim.x + threadIdx.x;
    if (o >= nch) return;
    float mean = sums[o]*invcnt;
    float var = sums[nch+o]*invcnt - mean*mean;
    if (var < 0.f) var = 0.f;
    stats[o] = mean;
    stats[nch+o] = 1.0f / sqrtf(var + BNEPS);
}

// ---------------- bn+lrelu in place ----------------
__global__ __launch_bounds__(256) void k_act(float* __restrict__ y, const float* __restrict__ stats, int nch) {
    int t = blockIdx.x*256 + threadIdx.x;
    int o = (t >> 11) % nch;
    float z = (y[t] - stats[o]) * stats[nch+o];
    y[t] = z >= 0.f ? z : NEGS*z;
}

// ---------------- conv2 (256->128) + stats ----------------
__global__ __launch_bounds__(256) void k_conv2(const float* __restrict__ z1, const float* __restrict__ w2,
                                               float* __restrict__ y2, float* __restrict__ sums) {
    int n = blockIdx.x*256 + threadIdx.x;
    int o = blockIdx.y, b = blockIdx.z;
    const float* pb = z1 + (size_t)b*256*NPT + n;
    const float* wo = w2 + o*256;
    float acc = 0.f;
    #pragma unroll 4
    for (int c = 0; c < 256; c++) acc += wo[c]*pb[(size_t)c*NPT];
    y2[((size_t)b*128 + o)*NPT + n] = acc;
    float a = acc, c2 = acc*acc;
    #pragma unroll
    for (int st = 32; st > 0; st >>= 1) { a += __shfl_down(a, st); c2 += __shfl_down(c2, st); }
    __shared__ float ra[4], rc[4];
    int wv = threadIdx.x >> 6;
    if ((threadIdx.x & 63) == 0) { ra[wv] = a; rc[wv] = c2; }
    __syncthreads();
    if (threadIdx.x == 0) {
        atomicAdd(&sums[o], ra[0]+ra[1]+ra[2]+ra[3]);
        atomicAdd(&sums[128+o], rc[0]+rc[1]+rc[2]+rc[3]);
    }
}

// ---------------- final: act(conv2) -> conv3 + bias ----------------
__global__ __launch_bounds__(256) void k_final(const float* __restrict__ y2, const float* __restrict__ w3,
                                               const float* __restrict__ b3, const float* __restrict__ stats,
                                               float* __restrict__ out) {
    int t = blockIdx.x*256 + threadIdx.x;       // B*N
    int n = t & (NPT-1); int b = t >> 11;
    const float* yb = y2 + (size_t)b*128*NPT + n;
    float acc = b3[0];
    #pragma unroll 4
    for (int c = 0; c < 128; c++) {
        float z = (yb[(size_t)c*NPT] - stats[c]) * stats[128+c];
        z = z >= 0.f ? z : NEGS*z;
        acc += w3[c]*z;
    }
    out[t] = acc;
}

extern "C" void kernel_launch(void* const* d_in, const int* in_sizes, int n_in,
                              void* d_out, int out_size, void* d_ws, size_t ws_size,
                              hipStream_t stream) {
    const float* x   = (const float*)d_in[0];
    const float* w1f = (const float*)d_in[1];
    const float* w1d = (const float*)d_in[2];
    const float* w2f = (const float*)d_in[3];
    const float* w2d = (const float*)d_in[4];
    const float* wp  = (const float*)d_in[5];
    const float* wc1 = (const float*)d_in[6];
    const float* wc2 = (const float*)d_in[7];
    const float* wc3 = (const float*)d_in[8];
    const float* bc3 = (const float*)d_in[9];
    float* out = (float*)d_out;

    float* ws = (float*)d_ws;
    float*  scores4 = ws;                          // 16,777,216 (4 x N x N)
    float*  xxf     = ws + 16777216;               // 8,192
    double* xxd     = (double*)(ws + 16785408);    // 8,192 d
    int*    cand    = (int*)(ws + 16801792);       // 262,144
    int*    idx     = (int*)(ws + 17063936);       // 163,840
    float*  xT      = ws + 17227776;               // 3,145,728
    double* Pfd     = (double*)(ws + 20373504);    // 524,288 d each (point-major [b*N+n][64])
    double* Qfd     = (double*)(ws + 21422080);
    double* Pdd     = (double*)(ws + 22470656);
    double* Qdd     = (double*)(ws + 23519232);
    double* part1   = (double*)(ws + 24567808);    // 640*42 d
    double* part2   = (double*)(ws + 24621568);    // 5120*42 d
    double* st1     = (double*)(ws + 25051648);    // 42 d
    double* st2     = (double*)(ws + 25051776);    // 42 d
    float*  sums_f  = ws + 25051904;               // 1024
    float*  stats_f = ws + 25052928;               // 1024
    float*  pooled  = ws + 25053952;               // 516,096
    float*  y1      = ws + 25570048;               // 2,097,152
    float*  y2      = ws + 27667200;               // 1,048,576 (end 28,715,776 f = 110 MB)

    k_zero<<<4, 256, 0, stream>>>(sums_f, 1024);
    k_xt<<<dim3(NPT/64, CC/64, BB), 256, 0, stream>>>(x, xT);
    k_xx<<<BB*NPT/4, 256, 0, stream>>>(xT, xxf, xxd);
    k_gram<<<dim3(528, BB), 256, 0, stream>>>(x, xxf, scores4);
    k_topk<<<dim3(NPT, BB), 256, 0, stream>>>(scores4, cand);
    k_rescore<<<BB*NPT, 256, 0, stream>>>(xT, xxd, cand, idx);
    k_pq_d<<<BB*NPT/4, 256, 0, stream>>>(xT, w1f, w1d, Pfd, Qfd, Pdd, Qdd);
    k_bn1_part<<<TOT/256, 256, 0, stream>>>(Pfd, Qfd, idx, part1);
    k_fin_d<<<NCH, 256, 0, stream>>>(part1, st1, TOT/256, (double)TOT);
    k_b1_bn2part<<<TOT/32, 256, 0, stream>>>(Pfd, Qfd, Pdd, Qdd, idx, st1, w2f, part2);
    k_fin_d<<<NCH, 256, 0, stream>>>(part2, st2, TOT/32, (double)TOT);
    k_apply_pool<<<BB*NPT, 256, 0, stream>>>(Pfd, Qfd, Pdd, Qdd, idx, st1, st2, w2f, w2d, wp, pooled);
    k_conv1<<<dim3(NPT/256, 256, BB), 256, 0, stream>>>(pooled, wc1, y1, sums_f);
    k_finalize<<<1, 256, 0, stream>>>(sums_f, stats_f, 1.f/(float)(BB*NPT), 256);
    k_act<<<BB*256*NPT/256, 256, 0, stream>>>(y1, stats_f, 256);
    k_conv2<<<dim3(NPT/256, 128, BB), 256, 0, stream>>>(y1, wc2, y2, sums_f+512);
    k_finalize<<<1, 128, 0, stream>>>(sums_f+512, stats_f+512, 1.f/(float)(BB*NPT), 128);
    k_final<<<BB*NPT/256, 256, 0, stream>>>(y2, wc3, bc3, stats_f+512, out);
}